// Round 14
// baseline (322.298 us; speedup 1.0000x reference)
//
#include <hip/hip_runtime.h>
#include <hip/hip_bf16.h>

#define B_ 4
#define T_ 1024
#define D_ 512
#define H_ 8
#define S_ 16
#define HD_ 64
#define ITS 8    // i-rows per WG (stats)
#define ITW 8    // i-rows per WG (attnw)
#define PVI 32   // i-rows per WG (pv)
#define PVJ 64   // j-chunk (pv)

typedef short bf16x8 __attribute__((ext_vector_type(8)));
typedef float f32x4m __attribute__((ext_vector_type(4)));

__device__ __forceinline__ unsigned short f2bf(float f) {
  unsigned u = __float_as_uint(f);
  unsigned r = (u + 0x7FFFu + ((u >> 16) & 1u)) >> 16;  // RNE
  return (unsigned short)r;
}
__device__ __forceinline__ float bf2f(unsigned short h) {
  return __uint_as_float((unsigned)h << 16);
}

__device__ __forceinline__ void split4(const float4 v, ushort4& h, ushort4& l) {
  h.x = f2bf(v.x); l.x = f2bf(v.x - bf2f(h.x));
  h.y = f2bf(v.y); l.y = f2bf(v.y - bf2f(h.y));
  h.z = f2bf(v.z); l.z = f2bf(v.z - bf2f(h.z));
  h.w = f2bf(v.w); l.w = f2bf(v.w - bf2f(h.w));
}

// ---------------- prep: params + 3 fp32->bf16hi/lo splits, fused ----------------
// grid 3104: [0,2048) x-split, [2048,2816) qkv_w, [2816,3072) out_w, [3072,3104) params
__global__ __launch_bounds__(256) void k_prep(const float* __restrict__ x,
                                              const float* __restrict__ qkv_w,
                                              const float* __restrict__ out_w,
                                              const float* __restrict__ base_centers,
                                              const float* __restrict__ center_deltas,
                                              const float* __restrict__ log_scales,
                                              const float* __restrict__ log_amps,
                                              const float* __restrict__ movement_param,
                                              const float* __restrict__ temperature,
                                              unsigned short* __restrict__ xh,
                                              unsigned short* __restrict__ xl,
                                              unsigned short* __restrict__ wh,
                                              unsigned short* __restrict__ wl,
                                              unsigned short* __restrict__ owh,
                                              unsigned short* __restrict__ owl,
                                              float* __restrict__ centers,
                                              float* __restrict__ inv_var,
                                              float* __restrict__ eff_amps,
                                              float* __restrict__ inv_temp) {
  const int bid = blockIdx.x;
  const int t = threadIdx.x;
  if (bid < 2048) {
    int i = bid * 256 + t;
    float4 v = ((const float4*)x)[i];
    ushort4 h, l; split4(v, h, l);
    ((ushort4*)xh)[i] = h; ((ushort4*)xl)[i] = l;
  } else if (bid < 2816) {
    int i = (bid - 2048) * 256 + t;
    float4 v = ((const float4*)qkv_w)[i];
    ushort4 h, l; split4(v, h, l);
    ((ushort4*)wh)[i] = h; ((ushort4*)wl)[i] = l;
  } else if (bid < 3072) {
    int i = (bid - 2816) * 256 + t;
    float4 v = ((const float4*)out_w)[i];
    ushort4 h, l; split4(v, h, l);
    ((ushort4*)owh)[i] = h; ((ushort4*)owl)[i] = l;
  } else {
    int tid = (bid - 3072) * 256 + t;  // 0..8191
    float move = (1.f / (1.f + __expf(-movement_param[0]))) * 0.2f;
    centers[tid] = base_centers[tid] + center_deltas[tid] * move;
    if (tid < H_ * S_) {
      float sc = __expf(log_scales[tid]);
      sc = fminf(fmaxf(sc, 1e-4f), 5.f);
      float am = __expf(log_amps[tid]);
      am = fminf(fmaxf(am, 1e-6f), 10.f);
      inv_var[tid] = 1.f / (sc * sc + 1e-8f);
      eff_amps[tid] = (am > 0.001f) ? am : 0.f;
    }
    if (tid == 0) {
      float tt = fminf(fmaxf(temperature[0], 0.01f), 10.f);
      inv_temp[0] = 1.f / tt;
    }
  }
}

// ---------------- split-bf16 MFMA GEMM (4-wave, 128-row tiles) ----------------
template <int BN>
__global__ __launch_bounds__(256) void gemm_mfma(const unsigned short* __restrict__ Ah,
                                                 const unsigned short* __restrict__ Al,
                                                 const unsigned short* __restrict__ Bh,
                                                 const unsigned short* __restrict__ Bl,
                                                 float* __restrict__ C,
                                                 int M, int N, int K) {
  constexpr int NF = BN / 16;
  const int t = threadIdx.x;
  const int lane = t & 63;
  const int wv = t >> 6;
  const int m0 = blockIdx.y * 128 + wv * 32;
  const int n0 = blockIdx.x * BN;
  const int lr = lane & 15;
  const int kg = lane >> 4;

  const unsigned short* a0h = Ah + (size_t)(m0 + lr) * K + kg * 8;
  const unsigned short* a1h = a0h + (size_t)16 * K;
  const unsigned short* a0l = Al + (size_t)(m0 + lr) * K + kg * 8;
  const unsigned short* a1l = a0l + (size_t)16 * K;
  const unsigned short* bph = Bh + (size_t)(n0 + lr) * K + kg * 8;
  const unsigned short* bpl = Bl + (size_t)(n0 + lr) * K + kg * 8;

  f32x4m acc[2][NF];
#pragma unroll
  for (int i = 0; i < 2; ++i)
#pragma unroll
    for (int f = 0; f < NF; ++f) {
      f32x4m z = {0.f, 0.f, 0.f, 0.f};
      acc[i][f] = z;
    }

  for (int k0 = 0; k0 < K; k0 += 32) {
    bf16x8 ah0 = *(const bf16x8*)(a0h + k0);
    bf16x8 ah1 = *(const bf16x8*)(a1h + k0);
    bf16x8 al0 = *(const bf16x8*)(a0l + k0);
    bf16x8 al1 = *(const bf16x8*)(a1l + k0);
#pragma unroll
    for (int f = 0; f < NF; ++f) {
      bf16x8 vbh = *(const bf16x8*)(bph + (size_t)f * 16 * K + k0);
      bf16x8 vbl = *(const bf16x8*)(bpl + (size_t)f * 16 * K + k0);
      acc[0][f] = __builtin_amdgcn_mfma_f32_16x16x32_bf16(al0, vbh, acc[0][f], 0, 0, 0);
      acc[0][f] = __builtin_amdgcn_mfma_f32_16x16x32_bf16(ah0, vbl, acc[0][f], 0, 0, 0);
      acc[0][f] = __builtin_amdgcn_mfma_f32_16x16x32_bf16(ah0, vbh, acc[0][f], 0, 0, 0);
      acc[1][f] = __builtin_amdgcn_mfma_f32_16x16x32_bf16(al1, vbh, acc[1][f], 0, 0, 0);
      acc[1][f] = __builtin_amdgcn_mfma_f32_16x16x32_bf16(ah1, vbl, acc[1][f], 0, 0, 0);
      acc[1][f] = __builtin_amdgcn_mfma_f32_16x16x32_bf16(ah1, vbh, acc[1][f], 0, 0, 0);
    }
  }
#pragma unroll
  for (int i = 0; i < 2; ++i)
#pragma unroll
    for (int f = 0; f < NF; ++f)
#pragma unroll
      for (int r = 0; r < 4; ++r)
        C[(size_t)(m0 + i * 16 + kg * 4 + r) * N + n0 + f * 16 + lr] = acc[i][f][r];
}

// ---------------- 2-wave variant (64-row tiles) for the out-proj ----------------
template <int BN>
__global__ __launch_bounds__(128) void gemm_mfma2(const unsigned short* __restrict__ Ah,
                                                  const unsigned short* __restrict__ Al,
                                                  const unsigned short* __restrict__ Bh,
                                                  const unsigned short* __restrict__ Bl,
                                                  float* __restrict__ C,
                                                  int M, int N, int K) {
  constexpr int NF = BN / 16;
  const int t = threadIdx.x;
  const int lane = t & 63;
  const int wv = t >> 6;  // 0..1
  const int m0 = blockIdx.y * 64 + wv * 32;
  const int n0 = blockIdx.x * BN;
  const int lr = lane & 15;
  const int kg = lane >> 4;

  const unsigned short* a0h = Ah + (size_t)(m0 + lr) * K + kg * 8;
  const unsigned short* a1h = a0h + (size_t)16 * K;
  const unsigned short* a0l = Al + (size_t)(m0 + lr) * K + kg * 8;
  const unsigned short* a1l = a0l + (size_t)16 * K;
  const unsigned short* bph = Bh + (size_t)(n0 + lr) * K + kg * 8;
  const unsigned short* bpl = Bl + (size_t)(n0 + lr) * K + kg * 8;

  f32x4m acc[2][NF];
#pragma unroll
  for (int i = 0; i < 2; ++i)
#pragma unroll
    for (int f = 0; f < NF; ++f) {
      f32x4m z = {0.f, 0.f, 0.f, 0.f};
      acc[i][f] = z;
    }

  for (int k0 = 0; k0 < K; k0 += 32) {
    bf16x8 ah0 = *(const bf16x8*)(a0h + k0);
    bf16x8 ah1 = *(const bf16x8*)(a1h + k0);
    bf16x8 al0 = *(const bf16x8*)(a0l + k0);
    bf16x8 al1 = *(const bf16x8*)(a1l + k0);
#pragma unroll
    for (int f = 0; f < NF; ++f) {
      bf16x8 vbh = *(const bf16x8*)(bph + (size_t)f * 16 * K + k0);
      bf16x8 vbl = *(const bf16x8*)(bpl + (size_t)f * 16 * K + k0);
      acc[0][f] = __builtin_amdgcn_mfma_f32_16x16x32_bf16(al0, vbh, acc[0][f], 0, 0, 0);
      acc[0][f] = __builtin_amdgcn_mfma_f32_16x16x32_bf16(ah0, vbl, acc[0][f], 0, 0, 0);
      acc[0][f] = __builtin_amdgcn_mfma_f32_16x16x32_bf16(ah0, vbh, acc[0][f], 0, 0, 0);
      acc[1][f] = __builtin_amdgcn_mfma_f32_16x16x32_bf16(al1, vbh, acc[1][f], 0, 0, 0);
      acc[1][f] = __builtin_amdgcn_mfma_f32_16x16x32_bf16(ah1, vbl, acc[1][f], 0, 0, 0);
      acc[1][f] = __builtin_amdgcn_mfma_f32_16x16x32_bf16(ah1, vbh, acc[1][f], 0, 0, 0);
    }
  }
#pragma unroll
  for (int i = 0; i < 2; ++i)
#pragma unroll
    for (int f = 0; f < NF; ++f)
#pragma unroll
      for (int r = 0; r < 4; ++r)
        C[(size_t)(m0 + i * 16 + kg * 4 + r) * N + n0 + f * 16 + lr] = acc[i][f][r];
}

// ---------------- gaussian kernel weights: q_w (× 1/temp), k_w ----------------
__global__ __launch_bounds__(256) void k_gauss(const float* __restrict__ qkv,
                                               const float* __restrict__ centers,
                                               const float* __restrict__ inv_var,
                                               const float* __restrict__ eff_amps,
                                               const float* __restrict__ inv_temp,
                                               float* __restrict__ qw,
                                               float* __restrict__ kw) {
  int gid = blockIdx.x * blockDim.x + threadIdx.x;
  if (gid >= B_ * T_ * H_ * S_) return;
  int s = gid & 15;
  int h = (gid >> 4) & 7;
  int bt = gid >> 7;  // b*T + t
  const float* qrow = qkv + (size_t)bt * 1536 + h * 64;
  const float* krow = qrow + 512;
  const float* c = centers + (h * 16 + s) * 64;
  float qd = 0.f, kd = 0.f;
#pragma unroll
  for (int d = 0; d < 64; d += 4) {
    float4 cv = *(const float4*)(c + d);
    float4 qv = *(const float4*)(qrow + d);
    float4 kv = *(const float4*)(krow + d);
    float t;
    t = qv.x - cv.x; qd += t * t;
    t = qv.y - cv.y; qd += t * t;
    t = qv.z - cv.z; qd += t * t;
    t = qv.w - cv.w; qd += t * t;
    t = kv.x - cv.x; kd += t * t;
    t = kv.y - cv.y; kd += t * t;
    t = kv.z - cv.z; kd += t * t;
    t = kv.w - cv.w; kd += t * t;
  }
  qd = fminf(qd, 100.f);
  kd = fminf(kd, 100.f);
  float iv = inv_var[h * 16 + s];
  float ea = eff_amps[h * 16 + s];
  qw[gid] = __expf(-0.5f * qd * iv) * ea * inv_temp[0];
  kw[gid] = __expf(-0.5f * kd * iv) * ea;
}

__device__ __forceinline__ float dot16(const float4 q[4], const float4 k[4]) {
  return q[0].x * k[0].x + q[0].y * k[0].y + q[0].z * k[0].z + q[0].w * k[0].w +
         q[1].x * k[1].x + q[1].y * k[1].y + q[1].z * k[1].z + q[1].w * k[1].w +
         q[2].x * k[2].x + q[2].y * k[2].y + q[2].z * k[2].z + q[2].w * k[2].w +
         q[3].x * k[3].x + q[3].y * k[3].y + q[3].z * k[3].z + q[3].w * k[3].w;
}

// ---------------- fused stats + vtr (8:1 WG interleave) ----------------
__global__ __launch_bounds__(256, 4) void k_sv(const float* __restrict__ qw_g,
                                               const float* __restrict__ kw_g,
                                               const float* __restrict__ qkv,
                                               float* __restrict__ m_g,
                                               float* __restrict__ is_g,
                                               unsigned short* __restrict__ vth,
                                               unsigned short* __restrict__ vtl) {
  union Sm {
    float red[4][4][2][2];
    float Vl[64][68];
  };
  __shared__ Sm sm;
  const int bid = blockIdx.x;
  const int g = bid / 9;
  const int r = bid - g * 9;
  const int t = threadIdx.x;

  if (r < 8) {
    // ---- stats: register-qw, zero-LDS hot loop ----
    const int x = g * 8 + r;  // 0..4095
    const int ic = x & 127;
    const int h = (x >> 7) & 7;
    const int b = x >> 10;
    const int i0 = ic * ITS;
    const int rp = t & 3;
    const int jl = t >> 2;

    float qwr[2][16], mr[2], sr[2];
#pragma unroll
    for (int e = 0; e < 2; ++e) {
      const float* qp = qw_g + (((size_t)(b * T_ + i0 + rp * 2 + e) * H_ + h) * S_);
#pragma unroll
      for (int s4 = 0; s4 < 4; ++s4) {
        float4 v = *(const float4*)(qp + s4 * 4);
        qwr[e][s4 * 4 + 0] = v.x; qwr[e][s4 * 4 + 1] = v.y;
        qwr[e][s4 * 4 + 2] = v.z; qwr[e][s4 * 4 + 3] = v.w;
      }
      mr[e] = -1e30f; sr[e] = 0.f;
    }
    for (int c = 0; c < T_ / 64; ++c) {
      int j = c * 64 + jl;
      const float* kp = kw_g + ((size_t)(b * T_ + j) * H_ + h) * S_;
      float4 k0 = *(const float4*)(kp);
      float4 k1 = *(const float4*)(kp + 4);
      float4 k2 = *(const float4*)(kp + 8);
      float4 k3 = *(const float4*)(kp + 12);
#pragma unroll
      for (int e = 0; e < 2; ++e) {
        float d = qwr[e][0] * k0.x + qwr[e][1] * k0.y + qwr[e][2] * k0.z + qwr[e][3] * k0.w +
                  qwr[e][4] * k1.x + qwr[e][5] * k1.y + qwr[e][6] * k1.z + qwr[e][7] * k1.w +
                  qwr[e][8] * k2.x + qwr[e][9] * k2.y + qwr[e][10] * k2.z + qwr[e][11] * k2.w +
                  qwr[e][12] * k3.x + qwr[e][13] * k3.y + qwr[e][14] * k3.z + qwr[e][15] * k3.w;
        float mn = fmaxf(mr[e], d);
        sr[e] = sr[e] * __expf(mr[e] - mn) + __expf(d - mn);
        mr[e] = mn;
      }
    }
#pragma unroll
    for (int o = 4; o < 64; o <<= 1) {
#pragma unroll
      for (int e = 0; e < 2; ++e) {
        float m2 = __shfl_xor(mr[e], o);
        float s2 = __shfl_xor(sr[e], o);
        float mn = fmaxf(mr[e], m2);
        sr[e] = sr[e] * __expf(mr[e] - mn) + s2 * __expf(m2 - mn);
        mr[e] = mn;
      }
    }
    int wv = t >> 6;
    if ((t & 63) < 4) {
      sm.red[wv][rp][0][0] = mr[0]; sm.red[wv][rp][0][1] = sr[0];
      sm.red[wv][rp][1][0] = mr[1]; sm.red[wv][rp][1][1] = sr[1];
    }
    __syncthreads();
    if (t < ITS) {
      int rpp = t >> 1, e = t & 1;
      float mf = sm.red[0][rpp][e][0], sf = sm.red[0][rpp][e][1];
#pragma unroll
      for (int w = 1; w < 4; ++w) {
        float m2 = sm.red[w][rpp][e][0], s2 = sm.red[w][rpp][e][1];
        float mn = fmaxf(mf, m2);
        sf = sf * __expf(mf - mn) + s2 * __expf(m2 - mn);
        mf = mn;
      }
      size_t o = (size_t)(b * H_ + h) * T_ + i0 + t;
      m_g[o] = mf;
      is_g[o] = 1.f / sf;
    }
  } else {
    // ---- vtr: V transpose to bf16 hi/lo panels Vt[b][h][d][j] ----
    const int id = g;  // 0..511
    const int jc = id & 15;
    const int h = (id >> 4) & 7;
    const int b = id >> 7;
    const int j0 = jc * 64;
    {
      int jj = t >> 2, dqg = t & 3;
      const float* vp = qkv + (size_t)(b * T_ + j0 + jj) * 1536 + 1024 + h * 64 + dqg * 16;
#pragma unroll
      for (int q = 0; q < 4; ++q) {
        float4 v = *(const float4*)(vp + q * 4);
        *(float4*)&sm.Vl[jj][dqg * 16 + q * 4] = v;
      }
    }
    __syncthreads();
    {
      int d = t >> 2, jg = t & 3;
      ushort4 hs[4], ls[4];
#pragma unroll
      for (int q = 0; q < 4; ++q) {
        float f0 = sm.Vl[jg * 16 + q * 4 + 0][d];
        float f1 = sm.Vl[jg * 16 + q * 4 + 1][d];
        float f2 = sm.Vl[jg * 16 + q * 4 + 2][d];
        float f3 = sm.Vl[jg * 16 + q * 4 + 3][d];
        hs[q].x = f2bf(f0); ls[q].x = f2bf(f0 - bf2f(hs[q].x));
        hs[q].y = f2bf(f1); ls[q].y = f2bf(f1 - bf2f(hs[q].y));
        hs[q].z = f2bf(f2); ls[q].z = f2bf(f2 - bf2f(hs[q].z));
        hs[q].w = f2bf(f3); ls[q].w = f2bf(f3 - bf2f(hs[q].w));
      }
      size_t off = ((size_t)(b * H_ + h) * 64 + d) * 1024 + j0 + jg * 16;
#pragma unroll
      for (int q = 0; q < 4; ++q) {
        *(ushort4*)(vth + off + q * 4) = hs[q];
        *(ushort4*)(vtl + off + q * 4) = ls[q];
      }
    }
  }
}

// ---------------- fused attnw + pv fat kernel (2:1 WG interleave) ----------------
// attnw WGs are write-bound, pv WGs MFMA/VALU-bound -> co-scheduling fills both
// pipes per CU. pv's XCD-panel locality preserved: (3g+2)&7 is a bijection on
// g mod 8, so panel assignment is derived from the PHYSICAL bid&7.
__global__ __launch_bounds__(256, 4) void k_ap(const float* __restrict__ qw_g,
                                               const float* __restrict__ kw_g,
                                               const float* __restrict__ m_g,
                                               const float* __restrict__ is_g,
                                               const unsigned short* __restrict__ vth,
                                               const unsigned short* __restrict__ vtl,
                                               float* __restrict__ attn,
                                               unsigned short* __restrict__ oph,
                                               unsigned short* __restrict__ opl) {
  union Sm {
    struct {
      float qw_l[ITW][H_ * S_];
      float msl[ITW][H_];
      float isl[ITW][H_];
      float tile[ITW][H_][68];
    } aw;
    struct {
      float kw_sw[PVJ][16];
      float mgs[128][17];
    } pv;
  };
  __shared__ Sm sm;
  const int bid = blockIdx.x;
  const int g = bid / 3;
  const int r3 = bid - g * 3;
  const int t = threadIdx.x;

  if (r3 < 2) {
    // ================= attnw body (v1) =================
    const int a = g * 2 + r3;  // 0..2047
    const int jt = a & 3;
    const int it = (a >> 2) & 127;
    const int b = a >> 9;
    const int i0 = it * ITW;
    const int jbase = jt * 256;

    {
      int f = t * 4;
      int rr = f >> 7, c = f & 127;
      *(float4*)&sm.aw.qw_l[rr][c] =
          *(const float4*)(qw_g + ((size_t)(b * T_ + i0 + rr) * 128 + c));
    }
    if (t < 64) {
      int rr = t >> 3, hh = t & 7;
      size_t o = (size_t)(b * H_ + hh) * T_ + i0 + rr;
      sm.aw.msl[rr][hh] = m_g[o];
      sm.aw.isl[rr][hh] = is_g[o];
    }
    __syncthreads();

    const int h = t >> 5;
    const int jq = t & 31;
    const float* kw_b = kw_g + (size_t)b * T_ * (H_ * S_);
    float* attn_b = attn + (size_t)(b * T_ + i0) * (T_ * H_);

    for (int st = 0; st < 4; ++st) {
      const int j0 = jbase + st * 64;
      const float* kp = kw_b + ((size_t)(j0 + jq * 2) * H_ + h) * S_;
      float4 ka[4], kb[4];
      ka[0] = *(const float4*)(kp);       ka[1] = *(const float4*)(kp + 4);
      ka[2] = *(const float4*)(kp + 8);   ka[3] = *(const float4*)(kp + 12);
      kb[0] = *(const float4*)(kp + 128); kb[1] = *(const float4*)(kp + 132);
      kb[2] = *(const float4*)(kp + 136); kb[3] = *(const float4*)(kp + 140);
#pragma unroll
      for (int rr = 0; rr < ITW; ++rr) {
        float4 q4[4];
        q4[0] = *(const float4*)&sm.aw.qw_l[rr][h * 16 + 0];
        q4[1] = *(const float4*)&sm.aw.qw_l[rr][h * 16 + 4];
        q4[2] = *(const float4*)&sm.aw.qw_l[rr][h * 16 + 8];
        q4[3] = *(const float4*)&sm.aw.qw_l[rr][h * 16 + 12];
        float la = dot16(q4, ka);
        float lb = dot16(q4, kb);
        float mm = sm.aw.msl[rr][h], ii = sm.aw.isl[rr][h];
        *(float2*)&sm.aw.tile[rr][h][jq * 2] =
            make_float2(__expf(la - mm) * ii, __expf(lb - mm) * ii);
      }
      __syncthreads();
#pragma unroll
      for (int l = 0; l < 4; ++l) {
        int f = (l * 256 + t) * 4;
        int rr = f >> 9;
        int rem = f & 511;
        int jl = rem >> 3;
        int h0 = rem & 7;  // 0 or 4
        float4 v;
        v.x = sm.aw.tile[rr][h0 + 0][jl];
        v.y = sm.aw.tile[rr][h0 + 1][jl];
        v.z = sm.aw.tile[rr][h0 + 2][jl];
        v.w = sm.aw.tile[rr][h0 + 3][jl];
        *(float4*)(attn_b + (size_t)rr * (T_ * H_) + (size_t)(j0 + jl) * H_ + h0) = v;
      }
      __syncthreads();
    }
  } else {
    // ================= pv body (v5) =================
    const int xcd = bid & 7;       // physical XCD (round-robin heuristic)
    const int t8 = g >> 3;         // 0..127 (bijective with (xcd, t8) over pv WGs)
    const int p = xcd * 4 + (t8 & 3);
    const int ib = t8 >> 2;        // 0..31
    const int b = p >> 3;
    const int h = p & 7;
    const int i0 = ib * PVI;
    const int lane = t & 63;
    const int w = t >> 6;
    const int I = w >> 1;
    const int S = w & 1;
    const int lr = lane & 15;
    const int kg = lane >> 4;

    const int irow = I * 16 + lr;
    float qwr[16];
    {
      const float* qp = qw_g + (((size_t)(b * T_ + i0 + irow) * H_ + h) * S_);
#pragma unroll
      for (int s4 = 0; s4 < 4; ++s4) {
        float4 v = *(const float4*)(qp + s4 * 4);
        qwr[s4 * 4 + 0] = v.x; qwr[s4 * 4 + 1] = v.y;
        qwr[s4 * 4 + 2] = v.z; qwr[s4 * 4 + 3] = v.w;
      }
    }
    float mr = m_g[(size_t)(b * H_ + h) * T_ + i0 + irow];
    float isr = is_g[(size_t)(b * H_ + h) * T_ + i0 + irow];
#pragma unroll
    for (int s = 0; s < 16; ++s) asm volatile("" : "+v"(qwr[s]));
    asm volatile("" : "+v"(mr));
    asm volatile("" : "+v"(isr));

    const unsigned short* vhp = vth + ((size_t)(b * H_ + h) * 64) * 1024;
    const unsigned short* vlp = vtl + ((size_t)(b * H_ + h) * 64) * 1024;

    f32x4m acc[4];
#pragma unroll
    for (int f = 0; f < 4; ++f) { f32x4m z = {0.f, 0.f, 0.f, 0.f}; acc[f] = z; }

    for (int jc = 0; jc < T_ / PVJ; ++jc) {
      const int j0 = jc * PVJ;
      __syncthreads();
      {
        int j = t >> 2, s4g = t & 3;
        float4 v = *(const float4*)(kw_g +
            (((size_t)(b * T_ + j0 + j) * H_ + h) * S_ + s4g * 4));
        int blk = s4g ^ ((j >> 3) & 3);
        *(float4*)&sm.pv.kw_sw[j][blk * 4] = v;
      }
      __syncthreads();
      union UA { unsigned short s[8]; bf16x8 v; } AH, AL;
#pragma unroll
      for (int u = 0; u < 8; ++u) {
        int jr = S * 32 + kg * 8 + u;
        int gg = (jr >> 3) & 3;
        float d = 0.f;
#pragma unroll
        for (int s4 = 0; s4 < 4; ++s4) {
          float4 kv = *(const float4*)&sm.pv.kw_sw[jr][(s4 ^ gg) * 4];
          d += qwr[s4 * 4 + 0] * kv.x + qwr[s4 * 4 + 1] * kv.y +
               qwr[s4 * 4 + 2] * kv.z + qwr[s4 * 4 + 3] * kv.w;
        }
        float pv = __expf(d - mr) * isr;
        unsigned short hh = f2bf(pv);
        AH.s[u] = hh;
        AL.s[u] = f2bf(pv - bf2f(hh));
      }
#pragma unroll
      for (int f = 0; f < 4; ++f) {
        size_t voff = (size_t)(f * 16 + lr) * 1024 + j0 + S * 32 + kg * 8;
        bf16x8 BHv = *(const bf16x8*)(vhp + voff);
        bf16x8 BLv = *(const bf16x8*)(vlp + voff);
        acc[f] = __builtin_amdgcn_mfma_f32_16x16x32_bf16(AL.v, BHv, acc[f], 0, 0, 0);
        acc[f] = __builtin_amdgcn_mfma_f32_16x16x32_bf16(AH.v, BLv, acc[f], 0, 0, 0);
        acc[f] = __builtin_amdgcn_mfma_f32_16x16x32_bf16(AH.v, BHv, acc[f], 0, 0, 0);
      }
    }
    __syncthreads();
    if (S == 1) {
      float* dst = &sm.pv.mgs[I * 64 + lane][0];
#pragma unroll
      for (int f = 0; f < 4; ++f)
#pragma unroll
        for (int rr = 0; rr < 4; ++rr) dst[f * 4 + rr] = acc[f][rr];
    }
    __syncthreads();
    if (S == 0) {
      const float* src = &sm.pv.mgs[I * 64 + lane][0];
#pragma unroll
      for (int f = 0; f < 4; ++f) {
#pragma unroll
        for (int rr = 0; rr < 4; ++rr) {
          float o = acc[f][rr] + src[f * 4 + rr];
          unsigned short hh = f2bf(o);
          unsigned short ll = f2bf(o - bf2f(hh));
          size_t idx = (size_t)(b * T_ + i0 + I * 16 + kg * 4 + rr) * D_ +
                       h * HD_ + f * 16 + lr;
          oph[idx] = hh;
          opl[idx] = ll;
        }
      }
    }
  }
}

extern "C" void kernel_launch(void* const* d_in, const int* in_sizes, int n_in,
                              void* d_out, int out_size, void* d_ws, size_t ws_size,
                              hipStream_t stream) {
  const float* x = (const float*)d_in[0];
  const float* qkv_w = (const float*)d_in[1];
  const float* out_w = (const float*)d_in[2];
  const float* base_c = (const float*)d_in[3];
  const float* deltas = (const float*)d_in[4];
  const float* log_sc = (const float*)d_in[5];
  const float* log_am = (const float*)d_in[6];
  const float* move_p = (const float*)d_in[7];
  const float* temp = (const float*)d_in[8];

  float* out = (float*)d_out;                    // B*T*D
  float* attn = out + (size_t)B_ * T_ * D_;      // B*T*T*H

  float* ws = (float*)d_ws;
  float* qkv = ws;                                          // 6,291,456 f
  float* qw = qkv + 6291456;                                // 524,288
  float* kw = qw + 524288;                                  // 524,288
  float* centers = kw + 524288;                             // 8,192
  float* inv_var = centers + 8192;                          // 128
  float* eff_amps = inv_var + 128;                          // 128
  float* inv_temp = eff_amps + 128;                         // 4
  float* m_g = inv_temp + 4;                                // 32,768
  float* is_g = m_g + 32768;                                // 32,768
  unsigned short* xh = (unsigned short*)(is_g + 32768);     // 2,097,152 us
  unsigned short* xl = xh + 2097152;                        // 2,097,152
  unsigned short* wh = xl + 2097152;                        // 786,432
  unsigned short* wl = wh + 786432;                         // 786,432
  unsigned short* owh = wl + 786432;                        // 262,144
  unsigned short* owl = owh + 262144;                       // 262,144
  unsigned short* oph = owl + 262144;                       // 2,097,152
  unsigned short* opl = oph + 2097152;                      // 2,097,152
  unsigned short* vth = opl + 2097152;                      // 2,097,152
  unsigned short* vtl = vth + 2097152;                      // 2,097,152

  k_prep<<<3104, 256, 0, stream>>>(x, qkv_w, out_w, base_c, deltas, log_sc, log_am,
                                   move_p, temp, xh, xl, wh, wl, owh, owl,
                                   centers, inv_var, eff_amps, inv_temp);

  dim3 g1(1536 / 64, 4096 / 128);   // 24 x 32 = 768 WGs
  gemm_mfma<64><<<g1, 256, 0, stream>>>(xh, xl, wh, wl, qkv, B_ * T_, 3 * D_, D_);

  k_gauss<<<(B_ * T_ * H_ * S_) / 256, 256, 0, stream>>>(qkv, centers, inv_var,
                                                         eff_amps, inv_temp, qw, kw);
  k_sv<<<4608, 256, 0, stream>>>(qw, kw, qkv, m_g, is_g, vth, vtl);
  k_ap<<<3072, 256, 0, stream>>>(qw, kw, m_g, is_g, vth, vtl, attn, oph, opl);

  dim3 g2(512 / 32, 4096 / 64);     // 16 x 64 = 1024 WGs
  gemm_mfma2<32><<<g2, 128, 0, stream>>>(oph, opl, owh, owl, out, B_ * T_, D_, D_);
}

// Round 15
// 306.624 us; speedup vs baseline: 1.0511x; 1.0511x over previous
//
#include <hip/hip_runtime.h>
#include <hip/hip_bf16.h>

#define B_ 4
#define T_ 1024
#define D_ 512
#define H_ 8
#define S_ 16
#define HD_ 64
#define ITS 8    // i-rows per WG (stats)
#define ITW 8    // i-rows per WG (attnw)
#define PVI 32   // i-rows per WG (pv)
#define PVJ 64   // j-chunk (pv)

typedef short bf16x8 __attribute__((ext_vector_type(8)));
typedef float f32x4m __attribute__((ext_vector_type(4)));

__device__ __forceinline__ unsigned short f2bf(float f) {
  unsigned u = __float_as_uint(f);
  unsigned r = (u + 0x7FFFu + ((u >> 16) & 1u)) >> 16;  // RNE
  return (unsigned short)r;
}
__device__ __forceinline__ float bf2f(unsigned short h) {
  return __uint_as_float((unsigned)h << 16);
}

__device__ __forceinline__ void split4(const float4 v, ushort4& h, ushort4& l) {
  h.x = f2bf(v.x); l.x = f2bf(v.x - bf2f(h.x));
  h.y = f2bf(v.y); l.y = f2bf(v.y - bf2f(h.y));
  h.z = f2bf(v.z); l.z = f2bf(v.z - bf2f(h.z));
  h.w = f2bf(v.w); l.w = f2bf(v.w - bf2f(h.w));
}

// ---------------- prep: params + 3 fp32->bf16hi/lo splits, fused ----------------
__global__ __launch_bounds__(256) void k_prep(const float* __restrict__ x,
                                              const float* __restrict__ qkv_w,
                                              const float* __restrict__ out_w,
                                              const float* __restrict__ base_centers,
                                              const float* __restrict__ center_deltas,
                                              const float* __restrict__ log_scales,
                                              const float* __restrict__ log_amps,
                                              const float* __restrict__ movement_param,
                                              const float* __restrict__ temperature,
                                              unsigned short* __restrict__ xh,
                                              unsigned short* __restrict__ xl,
                                              unsigned short* __restrict__ wh,
                                              unsigned short* __restrict__ wl,
                                              unsigned short* __restrict__ owh,
                                              unsigned short* __restrict__ owl,
                                              float* __restrict__ centers,
                                              float* __restrict__ inv_var,
                                              float* __restrict__ eff_amps,
                                              float* __restrict__ inv_temp) {
  const int bid = blockIdx.x;
  const int t = threadIdx.x;
  if (bid < 2048) {
    int i = bid * 256 + t;
    float4 v = ((const float4*)x)[i];
    ushort4 h, l; split4(v, h, l);
    ((ushort4*)xh)[i] = h; ((ushort4*)xl)[i] = l;
  } else if (bid < 2816) {
    int i = (bid - 2048) * 256 + t;
    float4 v = ((const float4*)qkv_w)[i];
    ushort4 h, l; split4(v, h, l);
    ((ushort4*)wh)[i] = h; ((ushort4*)wl)[i] = l;
  } else if (bid < 3072) {
    int i = (bid - 2816) * 256 + t;
    float4 v = ((const float4*)out_w)[i];
    ushort4 h, l; split4(v, h, l);
    ((ushort4*)owh)[i] = h; ((ushort4*)owl)[i] = l;
  } else {
    int tid = (bid - 3072) * 256 + t;  // 0..8191
    float move = (1.f / (1.f + __expf(-movement_param[0]))) * 0.2f;
    centers[tid] = base_centers[tid] + center_deltas[tid] * move;
    if (tid < H_ * S_) {
      float sc = __expf(log_scales[tid]);
      sc = fminf(fmaxf(sc, 1e-4f), 5.f);
      float am = __expf(log_amps[tid]);
      am = fminf(fmaxf(am, 1e-6f), 10.f);
      inv_var[tid] = 1.f / (sc * sc + 1e-8f);
      eff_amps[tid] = (am > 0.001f) ? am : 0.f;
    }
    if (tid == 0) {
      float tt = fminf(fmaxf(temperature[0], 0.01f), 10.f);
      inv_temp[0] = 1.f / tt;
    }
  }
}

// ---------------- split-bf16 MFMA GEMM (4-wave, 128-row tiles) ----------------
template <int BN>
__global__ __launch_bounds__(256) void gemm_mfma(const unsigned short* __restrict__ Ah,
                                                 const unsigned short* __restrict__ Al,
                                                 const unsigned short* __restrict__ Bh,
                                                 const unsigned short* __restrict__ Bl,
                                                 float* __restrict__ C,
                                                 int M, int N, int K) {
  constexpr int NF = BN / 16;
  const int t = threadIdx.x;
  const int lane = t & 63;
  const int wv = t >> 6;
  const int m0 = blockIdx.y * 128 + wv * 32;
  const int n0 = blockIdx.x * BN;
  const int lr = lane & 15;
  const int kg = lane >> 4;

  const unsigned short* a0h = Ah + (size_t)(m0 + lr) * K + kg * 8;
  const unsigned short* a1h = a0h + (size_t)16 * K;
  const unsigned short* a0l = Al + (size_t)(m0 + lr) * K + kg * 8;
  const unsigned short* a1l = a0l + (size_t)16 * K;
  const unsigned short* bph = Bh + (size_t)(n0 + lr) * K + kg * 8;
  const unsigned short* bpl = Bl + (size_t)(n0 + lr) * K + kg * 8;

  f32x4m acc[2][NF];
#pragma unroll
  for (int i = 0; i < 2; ++i)
#pragma unroll
    for (int f = 0; f < NF; ++f) {
      f32x4m z = {0.f, 0.f, 0.f, 0.f};
      acc[i][f] = z;
    }

  for (int k0 = 0; k0 < K; k0 += 32) {
    bf16x8 ah0 = *(const bf16x8*)(a0h + k0);
    bf16x8 ah1 = *(const bf16x8*)(a1h + k0);
    bf16x8 al0 = *(const bf16x8*)(a0l + k0);
    bf16x8 al1 = *(const bf16x8*)(a1l + k0);
#pragma unroll
    for (int f = 0; f < NF; ++f) {
      bf16x8 vbh = *(const bf16x8*)(bph + (size_t)f * 16 * K + k0);
      bf16x8 vbl = *(const bf16x8*)(bpl + (size_t)f * 16 * K + k0);
      acc[0][f] = __builtin_amdgcn_mfma_f32_16x16x32_bf16(al0, vbh, acc[0][f], 0, 0, 0);
      acc[0][f] = __builtin_amdgcn_mfma_f32_16x16x32_bf16(ah0, vbl, acc[0][f], 0, 0, 0);
      acc[0][f] = __builtin_amdgcn_mfma_f32_16x16x32_bf16(ah0, vbh, acc[0][f], 0, 0, 0);
      acc[1][f] = __builtin_amdgcn_mfma_f32_16x16x32_bf16(al1, vbh, acc[1][f], 0, 0, 0);
      acc[1][f] = __builtin_amdgcn_mfma_f32_16x16x32_bf16(ah1, vbl, acc[1][f], 0, 0, 0);
      acc[1][f] = __builtin_amdgcn_mfma_f32_16x16x32_bf16(ah1, vbh, acc[1][f], 0, 0, 0);
    }
  }
#pragma unroll
  for (int i = 0; i < 2; ++i)
#pragma unroll
    for (int f = 0; f < NF; ++f)
#pragma unroll
      for (int r = 0; r < 4; ++r)
        C[(size_t)(m0 + i * 16 + kg * 4 + r) * N + n0 + f * 16 + lr] = acc[i][f][r];
}

// ---------------- 2-wave variant (64-row tiles) for the out-proj ----------------
template <int BN>
__global__ __launch_bounds__(128) void gemm_mfma2(const unsigned short* __restrict__ Ah,
                                                  const unsigned short* __restrict__ Al,
                                                  const unsigned short* __restrict__ Bh,
                                                  const unsigned short* __restrict__ Bl,
                                                  float* __restrict__ C,
                                                  int M, int N, int K) {
  constexpr int NF = BN / 16;
  const int t = threadIdx.x;
  const int lane = t & 63;
  const int wv = t >> 6;  // 0..1
  const int m0 = blockIdx.y * 64 + wv * 32;
  const int n0 = blockIdx.x * BN;
  const int lr = lane & 15;
  const int kg = lane >> 4;

  const unsigned short* a0h = Ah + (size_t)(m0 + lr) * K + kg * 8;
  const unsigned short* a1h = a0h + (size_t)16 * K;
  const unsigned short* a0l = Al + (size_t)(m0 + lr) * K + kg * 8;
  const unsigned short* a1l = a0l + (size_t)16 * K;
  const unsigned short* bph = Bh + (size_t)(n0 + lr) * K + kg * 8;
  const unsigned short* bpl = Bl + (size_t)(n0 + lr) * K + kg * 8;

  f32x4m acc[2][NF];
#pragma unroll
  for (int i = 0; i < 2; ++i)
#pragma unroll
    for (int f = 0; f < NF; ++f) {
      f32x4m z = {0.f, 0.f, 0.f, 0.f};
      acc[i][f] = z;
    }

  for (int k0 = 0; k0 < K; k0 += 32) {
    bf16x8 ah0 = *(const bf16x8*)(a0h + k0);
    bf16x8 ah1 = *(const bf16x8*)(a1h + k0);
    bf16x8 al0 = *(const bf16x8*)(a0l + k0);
    bf16x8 al1 = *(const bf16x8*)(a1l + k0);
#pragma unroll
    for (int f = 0; f < NF; ++f) {
      bf16x8 vbh = *(const bf16x8*)(bph + (size_t)f * 16 * K + k0);
      bf16x8 vbl = *(const bf16x8*)(bpl + (size_t)f * 16 * K + k0);
      acc[0][f] = __builtin_amdgcn_mfma_f32_16x16x32_bf16(al0, vbh, acc[0][f], 0, 0, 0);
      acc[0][f] = __builtin_amdgcn_mfma_f32_16x16x32_bf16(ah0, vbl, acc[0][f], 0, 0, 0);
      acc[0][f] = __builtin_amdgcn_mfma_f32_16x16x32_bf16(ah0, vbh, acc[0][f], 0, 0, 0);
      acc[1][f] = __builtin_amdgcn_mfma_f32_16x16x32_bf16(al1, vbh, acc[1][f], 0, 0, 0);
      acc[1][f] = __builtin_amdgcn_mfma_f32_16x16x32_bf16(ah1, vbl, acc[1][f], 0, 0, 0);
      acc[1][f] = __builtin_amdgcn_mfma_f32_16x16x32_bf16(ah1, vbh, acc[1][f], 0, 0, 0);
    }
  }
#pragma unroll
  for (int i = 0; i < 2; ++i)
#pragma unroll
    for (int f = 0; f < NF; ++f)
#pragma unroll
      for (int r = 0; r < 4; ++r)
        C[(size_t)(m0 + i * 16 + kg * 4 + r) * N + n0 + f * 16 + lr] = acc[i][f][r];
}

// ---------------- gaussian kernel weights: q_w (× 1/temp), k_w ----------------
__global__ __launch_bounds__(256) void k_gauss(const float* __restrict__ qkv,
                                               const float* __restrict__ centers,
                                               const float* __restrict__ inv_var,
                                               const float* __restrict__ eff_amps,
                                               const float* __restrict__ inv_temp,
                                               float* __restrict__ qw,
                                               float* __restrict__ kw) {
  int gid = blockIdx.x * blockDim.x + threadIdx.x;
  if (gid >= B_ * T_ * H_ * S_) return;
  int s = gid & 15;
  int h = (gid >> 4) & 7;
  int bt = gid >> 7;  // b*T + t
  const float* qrow = qkv + (size_t)bt * 1536 + h * 64;
  const float* krow = qrow + 512;
  const float* c = centers + (h * 16 + s) * 64;
  float qd = 0.f, kd = 0.f;
#pragma unroll
  for (int d = 0; d < 64; d += 4) {
    float4 cv = *(const float4*)(c + d);
    float4 qv = *(const float4*)(qrow + d);
    float4 kv = *(const float4*)(krow + d);
    float t;
    t = qv.x - cv.x; qd += t * t;
    t = qv.y - cv.y; qd += t * t;
    t = qv.z - cv.z; qd += t * t;
    t = qv.w - cv.w; qd += t * t;
    t = kv.x - cv.x; kd += t * t;
    t = kv.y - cv.y; kd += t * t;
    t = kv.z - cv.z; kd += t * t;
    t = kv.w - cv.w; kd += t * t;
  }
  qd = fminf(qd, 100.f);
  kd = fminf(kd, 100.f);
  float iv = inv_var[h * 16 + s];
  float ea = eff_amps[h * 16 + s];
  qw[gid] = __expf(-0.5f * qd * iv) * ea * inv_temp[0];
  kw[gid] = __expf(-0.5f * kd * iv) * ea;
}

__device__ __forceinline__ float dot16(const float4 q[4], const float4 k[4]) {
  return q[0].x * k[0].x + q[0].y * k[0].y + q[0].z * k[0].z + q[0].w * k[0].w +
         q[1].x * k[1].x + q[1].y * k[1].y + q[1].z * k[1].z + q[1].w * k[1].w +
         q[2].x * k[2].x + q[2].y * k[2].y + q[2].z * k[2].z + q[2].w * k[2].w +
         q[3].x * k[3].x + q[3].y * k[3].y + q[3].z * k[3].z + q[3].w * k[3].w;
}

// ---------------- fused stats + vtr (8:1 WG interleave) ----------------
__global__ __launch_bounds__(256, 4) void k_sv(const float* __restrict__ qw_g,
                                               const float* __restrict__ kw_g,
                                               const float* __restrict__ qkv,
                                               float* __restrict__ m_g,
                                               float* __restrict__ is_g,
                                               unsigned short* __restrict__ vth,
                                               unsigned short* __restrict__ vtl) {
  union Sm {
    float red[4][4][2][2];
    float Vl[64][68];
  };
  __shared__ Sm sm;
  const int bid = blockIdx.x;
  const int g = bid / 9;
  const int r = bid - g * 9;
  const int t = threadIdx.x;

  if (r < 8) {
    const int x = g * 8 + r;  // 0..4095
    const int ic = x & 127;
    const int h = (x >> 7) & 7;
    const int b = x >> 10;
    const int i0 = ic * ITS;
    const int rp = t & 3;
    const int jl = t >> 2;

    float qwr[2][16], mr[2], sr[2];
#pragma unroll
    for (int e = 0; e < 2; ++e) {
      const float* qp = qw_g + (((size_t)(b * T_ + i0 + rp * 2 + e) * H_ + h) * S_);
#pragma unroll
      for (int s4 = 0; s4 < 4; ++s4) {
        float4 v = *(const float4*)(qp + s4 * 4);
        qwr[e][s4 * 4 + 0] = v.x; qwr[e][s4 * 4 + 1] = v.y;
        qwr[e][s4 * 4 + 2] = v.z; qwr[e][s4 * 4 + 3] = v.w;
      }
      mr[e] = -1e30f; sr[e] = 0.f;
    }
    for (int c = 0; c < T_ / 64; ++c) {
      int j = c * 64 + jl;
      const float* kp = kw_g + ((size_t)(b * T_ + j) * H_ + h) * S_;
      float4 k0 = *(const float4*)(kp);
      float4 k1 = *(const float4*)(kp + 4);
      float4 k2 = *(const float4*)(kp + 8);
      float4 k3 = *(const float4*)(kp + 12);
#pragma unroll
      for (int e = 0; e < 2; ++e) {
        float d = qwr[e][0] * k0.x + qwr[e][1] * k0.y + qwr[e][2] * k0.z + qwr[e][3] * k0.w +
                  qwr[e][4] * k1.x + qwr[e][5] * k1.y + qwr[e][6] * k1.z + qwr[e][7] * k1.w +
                  qwr[e][8] * k2.x + qwr[e][9] * k2.y + qwr[e][10] * k2.z + qwr[e][11] * k2.w +
                  qwr[e][12] * k3.x + qwr[e][13] * k3.y + qwr[e][14] * k3.z + qwr[e][15] * k3.w;
        float mn = fmaxf(mr[e], d);
        sr[e] = sr[e] * __expf(mr[e] - mn) + __expf(d - mn);
        mr[e] = mn;
      }
    }
#pragma unroll
    for (int o = 4; o < 64; o <<= 1) {
#pragma unroll
      for (int e = 0; e < 2; ++e) {
        float m2 = __shfl_xor(mr[e], o);
        float s2 = __shfl_xor(sr[e], o);
        float mn = fmaxf(mr[e], m2);
        sr[e] = sr[e] * __expf(mr[e] - mn) + s2 * __expf(m2 - mn);
        mr[e] = mn;
      }
    }
    int wv = t >> 6;
    if ((t & 63) < 4) {
      sm.red[wv][rp][0][0] = mr[0]; sm.red[wv][rp][0][1] = sr[0];
      sm.red[wv][rp][1][0] = mr[1]; sm.red[wv][rp][1][1] = sr[1];
    }
    __syncthreads();
    if (t < ITS) {
      int rpp = t >> 1, e = t & 1;
      float mf = sm.red[0][rpp][e][0], sf = sm.red[0][rpp][e][1];
#pragma unroll
      for (int w = 1; w < 4; ++w) {
        float m2 = sm.red[w][rpp][e][0], s2 = sm.red[w][rpp][e][1];
        float mn = fmaxf(mf, m2);
        sf = sf * __expf(mf - mn) + s2 * __expf(m2 - mn);
        mf = mn;
      }
      size_t o = (size_t)(b * H_ + h) * T_ + i0 + t;
      m_g[o] = mf;
      is_g[o] = 1.f / sf;
    }
  } else {
    const int id = g;  // 0..511
    const int jc = id & 15;
    const int h = (id >> 4) & 7;
    const int b = id >> 7;
    const int j0 = jc * 64;
    {
      int jj = t >> 2, dqg = t & 3;
      const float* vp = qkv + (size_t)(b * T_ + j0 + jj) * 1536 + 1024 + h * 64 + dqg * 16;
#pragma unroll
      for (int q = 0; q < 4; ++q) {
        float4 v = *(const float4*)(vp + q * 4);
        *(float4*)&sm.Vl[jj][dqg * 16 + q * 4] = v;
      }
    }
    __syncthreads();
    {
      int d = t >> 2, jg = t & 3;
      ushort4 hs[4], ls[4];
#pragma unroll
      for (int q = 0; q < 4; ++q) {
        float f0 = sm.Vl[jg * 16 + q * 4 + 0][d];
        float f1 = sm.Vl[jg * 16 + q * 4 + 1][d];
        float f2 = sm.Vl[jg * 16 + q * 4 + 2][d];
        float f3 = sm.Vl[jg * 16 + q * 4 + 3][d];
        hs[q].x = f2bf(f0); ls[q].x = f2bf(f0 - bf2f(hs[q].x));
        hs[q].y = f2bf(f1); ls[q].y = f2bf(f1 - bf2f(hs[q].y));
        hs[q].z = f2bf(f2); ls[q].z = f2bf(f2 - bf2f(hs[q].z));
        hs[q].w = f2bf(f3); ls[q].w = f2bf(f3 - bf2f(hs[q].w));
      }
      size_t off = ((size_t)(b * H_ + h) * 64 + d) * 1024 + j0 + jg * 16;
#pragma unroll
      for (int q = 0; q < 4; ++q) {
        *(ushort4*)(vth + off + q * 4) = hs[q];
        *(ushort4*)(vtl + off + q * 4) = ls[q];
      }
    }
  }
}

// ---------------- attn writer (v1 body, jt-split 8) ----------------
// grid 4096: per WG 8 i-rows x 128 j x 8 h (2 subtiles). Halved serial chain
// vs jt=4 doubles independent WGs for latency hiding; access patterns identical.
__global__ __launch_bounds__(256, 4) void k_attnw(const float* __restrict__ qw_g,
                                                  const float* __restrict__ kw_g,
                                                  const float* __restrict__ m_g,
                                                  const float* __restrict__ is_g,
                                                  float* __restrict__ attn) {
  const int x = blockIdx.x;
  const int jt = x & 7;
  const int it = (x >> 3) & 127;
  const int b = x >> 10;
  const int i0 = it * ITW;
  const int jbase = jt * 128;
  const int tid = threadIdx.x;

  __shared__ float qw_l[ITW][H_ * S_];     // 4 KB
  __shared__ float msl[ITW][H_];
  __shared__ float isl[ITW][H_];
  __shared__ float tile[ITW][H_][68];      // 17.4 KB

  {
    int f = tid * 4;
    int r = f >> 7, c = f & 127;
    *(float4*)&qw_l[r][c] = *(const float4*)(qw_g + ((size_t)(b * T_ + i0 + r) * 128 + c));
  }
  if (tid < 64) {
    int r = tid >> 3, hh = tid & 7;
    size_t o = (size_t)(b * H_ + hh) * T_ + i0 + r;
    msl[r][hh] = m_g[o];
    isl[r][hh] = is_g[o];
  }
  __syncthreads();

  const int h = tid >> 5;
  const int jq = tid & 31;
  const float* kw_b = kw_g + (size_t)b * T_ * (H_ * S_);
  float* attn_b = attn + (size_t)(b * T_ + i0) * (T_ * H_);

  for (int st = 0; st < 2; ++st) {
    const int j0 = jbase + st * 64;
    const float* kp = kw_b + ((size_t)(j0 + jq * 2) * H_ + h) * S_;
    float4 ka[4], kb[4];
    ka[0] = *(const float4*)(kp);       ka[1] = *(const float4*)(kp + 4);
    ka[2] = *(const float4*)(kp + 8);   ka[3] = *(const float4*)(kp + 12);
    kb[0] = *(const float4*)(kp + 128); kb[1] = *(const float4*)(kp + 132);
    kb[2] = *(const float4*)(kp + 136); kb[3] = *(const float4*)(kp + 140);
#pragma unroll
    for (int r = 0; r < ITW; ++r) {
      float4 q4[4];
      q4[0] = *(const float4*)&qw_l[r][h * 16 + 0];
      q4[1] = *(const float4*)&qw_l[r][h * 16 + 4];
      q4[2] = *(const float4*)&qw_l[r][h * 16 + 8];
      q4[3] = *(const float4*)&qw_l[r][h * 16 + 12];
      float la = dot16(q4, ka);
      float lb = dot16(q4, kb);
      float mm = msl[r][h], ii = isl[r][h];
      *(float2*)&tile[r][h][jq * 2] =
          make_float2(__expf(la - mm) * ii, __expf(lb - mm) * ii);
    }
    __syncthreads();
#pragma unroll
    for (int l = 0; l < 4; ++l) {
      int f = (l * 256 + tid) * 4;
      int r = f >> 9;
      int rem = f & 511;
      int jl = rem >> 3;
      int h0 = rem & 7;  // 0 or 4
      float4 v;
      v.x = tile[r][h0 + 0][jl];
      v.y = tile[r][h0 + 1][jl];
      v.z = tile[r][h0 + 2][jl];
      v.w = tile[r][h0 + 3][jl];
      *(float4*)(attn_b + (size_t)r * (T_ * H_) + (size_t)(j0 + jl) * H_ + h0) = v;
    }
    __syncthreads();
  }
}

// ---------------- PV via MFMA, V from transposed bf16 panels (v5) ----------------
__global__ __launch_bounds__(256, 4) void k_pv(const float* __restrict__ qw_g,
                                               const float* __restrict__ kw_g,
                                               const float* __restrict__ m_g,
                                               const float* __restrict__ is_g,
                                               const unsigned short* __restrict__ vth,
                                               const unsigned short* __restrict__ vtl,
                                               unsigned short* __restrict__ oph,
                                               unsigned short* __restrict__ opl) {
  const int bid = blockIdx.x;
  const int xcd = bid & 7;
  const int qq = bid >> 3;             // 0..127
  const int p = xcd * 4 + (qq & 3);    // panel 0..31
  const int ib = qq >> 2;              // 0..31
  const int b = p >> 3;
  const int h = p & 7;
  const int i0 = ib * PVI;
  const int t = threadIdx.x;
  const int lane = t & 63;
  const int w = t >> 6;
  const int I = w >> 1;                // i-frag
  const int S = w & 1;                 // k-step (32-j half of chunk)
  const int lr = lane & 15;
  const int kg = lane >> 4;

  __shared__ float kw_sw[PVJ][16];     // 4 KB; s4-block ^= (j>>3)&3
  __shared__ float mgs[128][17];       // 8.7 KB merge scratch

  const int irow = I * 16 + lr;
  float qwr[16];
  {
    const float* qp = qw_g + (((size_t)(b * T_ + i0 + irow) * H_ + h) * S_);
#pragma unroll
    for (int s4 = 0; s4 < 4; ++s4) {
      float4 v = *(const float4*)(qp + s4 * 4);
      qwr[s4 * 4 + 0] = v.x; qwr[s4 * 4 + 1] = v.y;
      qwr[s4 * 4 + 2] = v.z; qwr[s4 * 4 + 3] = v.w;
    }
  }
  float mr = m_g[(size_t)(b * H_ + h) * T_ + i0 + irow];
  float isr = is_g[(size_t)(b * H_ + h) * T_ + i0 + irow];
#pragma unroll
  for (int s = 0; s < 16; ++s) asm volatile("" : "+v"(qwr[s]));
  asm volatile("" : "+v"(mr));
  asm volatile("" : "+v"(isr));

  const unsigned short* vhp = vth + ((size_t)(b * H_ + h) * 64) * 1024;
  const unsigned short* vlp = vtl + ((size_t)(b * H_ + h) * 64) * 1024;

  f32x4m acc[4];
#pragma unroll
  for (int f = 0; f < 4; ++f) { f32x4m z = {0.f, 0.f, 0.f, 0.f}; acc[f] = z; }

  for (int jc = 0; jc < T_ / PVJ; ++jc) {
    const int j0 = jc * PVJ;
    __syncthreads();
    {
      int j = t >> 2, s4g = t & 3;
      float4 v = *(const float4*)(kw_g + (((size_t)(b * T_ + j0 + j) * H_ + h) * S_ + s4g * 4));
      int blk = s4g ^ ((j >> 3) & 3);
      *(float4*)&kw_sw[j][blk * 4] = v;
    }
    __syncthreads();
    union UA { unsigned short s[8]; bf16x8 v; } AH, AL;
#pragma unroll
    for (int u = 0; u < 8; ++u) {
      int jr = S * 32 + kg * 8 + u;
      int g = (jr >> 3) & 3;
      float d = 0.f;
#pragma unroll
      for (int s4 = 0; s4 < 4; ++s4) {
        float4 kv = *(const float4*)&kw_sw[jr][(s4 ^ g) * 4];
        d += qwr[s4 * 4 + 0] * kv.x + qwr[s4 * 4 + 1] * kv.y +
             qwr[s4 * 4 + 2] * kv.z + qwr[s4 * 4 + 3] * kv.w;
      }
      float pv = __expf(d - mr) * isr;
      unsigned short hh = f2bf(pv);
      AH.s[u] = hh;
      AL.s[u] = f2bf(pv - bf2f(hh));
    }
#pragma unroll
    for (int f = 0; f < 4; ++f) {
      size_t voff = (size_t)(f * 16 + lr) * 1024 + j0 + S * 32 + kg * 8;
      bf16x8 BHv = *(const bf16x8*)(vhp + voff);
      bf16x8 BLv = *(const bf16x8*)(vlp + voff);
      acc[f] = __builtin_amdgcn_mfma_f32_16x16x32_bf16(AL.v, BHv, acc[f], 0, 0, 0);
      acc[f] = __builtin_amdgcn_mfma_f32_16x16x32_bf16(AH.v, BLv, acc[f], 0, 0, 0);
      acc[f] = __builtin_amdgcn_mfma_f32_16x16x32_bf16(AH.v, BHv, acc[f], 0, 0, 0);
    }
  }
  __syncthreads();
  if (S == 1) {
    float* dst = &mgs[I * 64 + lane][0];
#pragma unroll
    for (int f = 0; f < 4; ++f)
#pragma unroll
      for (int r = 0; r < 4; ++r) dst[f * 4 + r] = acc[f][r];
  }
  __syncthreads();
  if (S == 0) {
    const float* src = &mgs[I * 64 + lane][0];
#pragma unroll
    for (int f = 0; f < 4; ++f) {
#pragma unroll
      for (int r = 0; r < 4; ++r) {
        float o = acc[f][r] + src[f * 4 + r];
        unsigned short hh = f2bf(o);
        unsigned short ll = f2bf(o - bf2f(hh));
        size_t idx = (size_t)(b * T_ + i0 + I * 16 + kg * 4 + r) * D_ + h * HD_ + f * 16 + lr;
        oph[idx] = hh;
        opl[idx] = ll;
      }
    }
  }
}

extern "C" void kernel_launch(void* const* d_in, const int* in_sizes, int n_in,
                              void* d_out, int out_size, void* d_ws, size_t ws_size,
                              hipStream_t stream) {
  const float* x = (const float*)d_in[0];
  const float* qkv_w = (const float*)d_in[1];
  const float* out_w = (const float*)d_in[2];
  const float* base_c = (const float*)d_in[3];
  const float* deltas = (const float*)d_in[4];
  const float* log_sc = (const float*)d_in[5];
  const float* log_am = (const float*)d_in[6];
  const float* move_p = (const float*)d_in[7];
  const float* temp = (const float*)d_in[8];

  float* out = (float*)d_out;                    // B*T*D
  float* attn = out + (size_t)B_ * T_ * D_;      // B*T*T*H

  float* ws = (float*)d_ws;
  float* qkv = ws;                                          // 6,291,456 f
  float* qw = qkv + 6291456;                                // 524,288
  float* kw = qw + 524288;                                  // 524,288
  float* centers = kw + 524288;                             // 8,192
  float* inv_var = centers + 8192;                          // 128
  float* eff_amps = inv_var + 128;                          // 128
  float* inv_temp = eff_amps + 128;                         // 4
  float* m_g = inv_temp + 4;                                // 32,768
  float* is_g = m_g + 32768;                                // 32,768
  unsigned short* xh = (unsigned short*)(is_g + 32768);     // 2,097,152 us
  unsigned short* xl = xh + 2097152;                        // 2,097,152
  unsigned short* wh = xl + 2097152;                        // 786,432
  unsigned short* wl = wh + 786432;                         // 786,432
  unsigned short* owh = wl + 786432;                        // 262,144
  unsigned short* owl = owh + 262144;                       // 262,144
  unsigned short* oph = owl + 262144;                       // 2,097,152
  unsigned short* opl = oph + 2097152;                      // 2,097,152
  unsigned short* vth = opl + 2097152;                      // 2,097,152
  unsigned short* vtl = vth + 2097152;                      // 2,097,152

  k_prep<<<3104, 256, 0, stream>>>(x, qkv_w, out_w, base_c, deltas, log_sc, log_am,
                                   move_p, temp, xh, xl, wh, wl, owh, owl,
                                   centers, inv_var, eff_amps, inv_temp);

  dim3 g1(1536 / 64, 4096 / 128);   // 24 x 32 = 768 WGs
  gemm_mfma<64><<<g1, 256, 0, stream>>>(xh, xl, wh, wl, qkv, B_ * T_, 3 * D_, D_);

  k_gauss<<<(B_ * T_ * H_ * S_) / 256, 256, 0, stream>>>(qkv, centers, inv_var,
                                                         eff_amps, inv_temp, qw, kw);
  k_sv<<<4608, 256, 0, stream>>>(qw, kw, qkv, m_g, is_g, vth, vtl);
  k_attnw<<<B_ * (T_ / ITW) * 8, 256, 0, stream>>>(qw, kw, m_g, is_g, attn);
  k_pv<<<B_ * H_ * (T_ / PVI), 256, 0, stream>>>(qw, kw, m_g, is_g, vth, vtl, oph, opl);

  dim3 g2(512 / 32, 4096 / 64);     // 16 x 64 = 1024 WGs
  gemm_mfma2<32><<<g2, 128, 0, stream>>>(oph, opl, owh, owl, out, B_ * T_, D_, D_);
}

// Round 16
// 270.147 us; speedup vs baseline: 1.1930x; 1.1350x over previous
//
#include <hip/hip_runtime.h>
#include <hip/hip_bf16.h>

#define B_ 4
#define T_ 1024
#define D_ 512
#define H_ 8
#define S_ 16
#define HD_ 64
#define ITS 8    // i-rows per WG (stats)
#define ITW 8    // i-rows per WG (attnw)
#define PVI 32   // i-rows per WG (pv)
#define PVJ 64   // j-chunk (pv)

typedef short bf16x8 __attribute__((ext_vector_type(8)));
typedef float f32x4m __attribute__((ext_vector_type(4)));

__device__ __forceinline__ unsigned short f2bf(float f) {
  unsigned u = __float_as_uint(f);
  unsigned r = (u + 0x7FFFu + ((u >> 16) & 1u)) >> 16;  // RNE
  return (unsigned short)r;
}
__device__ __forceinline__ float bf2f(unsigned short h) {
  return __uint_as_float((unsigned)h << 16);
}

__device__ __forceinline__ void split4(const float4 v, ushort4& h, ushort4& l) {
  h.x = f2bf(v.x); l.x = f2bf(v.x - bf2f(h.x));
  h.y = f2bf(v.y); l.y = f2bf(v.y - bf2f(h.y));
  h.z = f2bf(v.z); l.z = f2bf(v.z - bf2f(h.z));
  h.w = f2bf(v.w); l.w = f2bf(v.w - bf2f(h.w));
}

// ---------------- prep: params + 3 fp32->bf16hi/lo splits, fused ----------------
__global__ __launch_bounds__(256) void k_prep(const float* __restrict__ x,
                                              const float* __restrict__ qkv_w,
                                              const float* __restrict__ out_w,
                                              const float* __restrict__ base_centers,
                                              const float* __restrict__ center_deltas,
                                              const float* __restrict__ log_scales,
                                              const float* __restrict__ log_amps,
                                              const float* __restrict__ movement_param,
                                              const float* __restrict__ temperature,
                                              unsigned short* __restrict__ xh,
                                              unsigned short* __restrict__ xl,
                                              unsigned short* __restrict__ wh,
                                              unsigned short* __restrict__ wl,
                                              unsigned short* __restrict__ owh,
                                              unsigned short* __restrict__ owl,
                                              float* __restrict__ centers,
                                              float* __restrict__ inv_var,
                                              float* __restrict__ eff_amps,
                                              float* __restrict__ inv_temp) {
  const int bid = blockIdx.x;
  const int t = threadIdx.x;
  if (bid < 2048) {
    int i = bid * 256 + t;
    float4 v = ((const float4*)x)[i];
    ushort4 h, l; split4(v, h, l);
    ((ushort4*)xh)[i] = h; ((ushort4*)xl)[i] = l;
  } else if (bid < 2816) {
    int i = (bid - 2048) * 256 + t;
    float4 v = ((const float4*)qkv_w)[i];
    ushort4 h, l; split4(v, h, l);
    ((ushort4*)wh)[i] = h; ((ushort4*)wl)[i] = l;
  } else if (bid < 3072) {
    int i = (bid - 2816) * 256 + t;
    float4 v = ((const float4*)out_w)[i];
    ushort4 h, l; split4(v, h, l);
    ((ushort4*)owh)[i] = h; ((ushort4*)owl)[i] = l;
  } else {
    int tid = (bid - 3072) * 256 + t;  // 0..8191
    float move = (1.f / (1.f + __expf(-movement_param[0]))) * 0.2f;
    centers[tid] = base_centers[tid] + center_deltas[tid] * move;
    if (tid < H_ * S_) {
      float sc = __expf(log_scales[tid]);
      sc = fminf(fmaxf(sc, 1e-4f), 5.f);
      float am = __expf(log_amps[tid]);
      am = fminf(fmaxf(am, 1e-6f), 10.f);
      inv_var[tid] = 1.f / (sc * sc + 1e-8f);
      eff_amps[tid] = (am > 0.001f) ? am : 0.f;
    }
    if (tid == 0) {
      float tt = fminf(fmaxf(temperature[0], 0.01f), 10.f);
      inv_temp[0] = 1.f / tt;
    }
  }
}

// ---------------- split-bf16 MFMA GEMM, B staged in swizzled LDS ----------------
// 4 waves share one 64x64 B hi/lo chunk (16KB LDS). Old version: each wave
// flat-loaded identical B frags (4x redundant, 16-row-scattered). Stage write
// and ds_read both conflict-free via 16B-slot XOR swizzle (slot ^= row&7).
template <int BN>
__global__ __launch_bounds__(256) void gemm_mfma(const unsigned short* __restrict__ Ah,
                                                 const unsigned short* __restrict__ Al,
                                                 const unsigned short* __restrict__ Bh,
                                                 const unsigned short* __restrict__ Bl,
                                                 float* __restrict__ C,
                                                 int M, int N, int K) {
  static_assert(BN == 64, "staging sized for BN=64");
  constexpr int NF = BN / 16;
  const int t = threadIdx.x;
  const int lane = t & 63;
  const int wv = t >> 6;
  const int m0 = blockIdx.y * 128 + wv * 32;
  const int n0 = blockIdx.x * BN;
  const int lr = lane & 15;
  const int kg = lane >> 4;

  __shared__ unsigned short Bsh[64][64];  // 8 KB
  __shared__ unsigned short Bsl[64][64];  // 8 KB

  const unsigned short* a0h = Ah + (size_t)(m0 + lr) * K + kg * 8;
  const unsigned short* a1h = a0h + (size_t)16 * K;
  const unsigned short* a0l = Al + (size_t)(m0 + lr) * K + kg * 8;
  const unsigned short* a1l = a0l + (size_t)16 * K;

  f32x4m acc[2][NF];
#pragma unroll
  for (int i = 0; i < 2; ++i)
#pragma unroll
    for (int f = 0; f < NF; ++f) {
      f32x4m z = {0.f, 0.f, 0.f, 0.f};
      acc[i][f] = z;
    }

  for (int k0 = 0; k0 < K; k0 += 64) {
    if (k0) __syncthreads();  // previous chunk's readers done
    // stage B hi/lo chunk: 64 rows x 64 cols, swizzled 16B slots
#pragma unroll
    for (int r2 = 0; r2 < 2; ++r2) {
      int idx = t + r2 * 256;
      int row = idx >> 3, c8 = idx & 7;
      int c8s = c8 ^ (row & 7);
      float4 vh = *(const float4*)(Bh + (size_t)(n0 + row) * K + k0 + c8 * 8);
      float4 vl = *(const float4*)(Bl + (size_t)(n0 + row) * K + k0 + c8 * 8);
      *(float4*)&Bsh[row][c8s * 8] = vh;
      *(float4*)&Bsl[row][c8s * 8] = vl;
    }
    __syncthreads();
#pragma unroll
    for (int S2 = 0; S2 < 2; ++S2) {
      const int kk = k0 + S2 * 32;
      bf16x8 ah0 = *(const bf16x8*)(a0h + kk);
      bf16x8 ah1 = *(const bf16x8*)(a1h + kk);
      bf16x8 al0 = *(const bf16x8*)(a0l + kk);
      bf16x8 al1 = *(const bf16x8*)(a1l + kk);
#pragma unroll
      for (int f = 0; f < NF; ++f) {
        int row = f * 16 + lr;
        int sl = (S2 * 4 + kg) ^ (row & 7);
        bf16x8 vbh = *(const bf16x8*)&Bsh[row][sl * 8];
        bf16x8 vbl = *(const bf16x8*)&Bsl[row][sl * 8];
        acc[0][f] = __builtin_amdgcn_mfma_f32_16x16x32_bf16(al0, vbh, acc[0][f], 0, 0, 0);
        acc[0][f] = __builtin_amdgcn_mfma_f32_16x16x32_bf16(ah0, vbl, acc[0][f], 0, 0, 0);
        acc[0][f] = __builtin_amdgcn_mfma_f32_16x16x32_bf16(ah0, vbh, acc[0][f], 0, 0, 0);
        acc[1][f] = __builtin_amdgcn_mfma_f32_16x16x32_bf16(al1, vbh, acc[1][f], 0, 0, 0);
        acc[1][f] = __builtin_amdgcn_mfma_f32_16x16x32_bf16(ah1, vbl, acc[1][f], 0, 0, 0);
        acc[1][f] = __builtin_amdgcn_mfma_f32_16x16x32_bf16(ah1, vbh, acc[1][f], 0, 0, 0);
      }
    }
  }
#pragma unroll
  for (int i = 0; i < 2; ++i)
#pragma unroll
    for (int f = 0; f < NF; ++f)
#pragma unroll
      for (int r = 0; r < 4; ++r)
        C[(size_t)(m0 + i * 16 + kg * 4 + r) * N + n0 + f * 16 + lr] = acc[i][f][r];
}

// ---------------- 2-wave variant (64-row tiles) for the out-proj ----------------
template <int BN>
__global__ __launch_bounds__(128) void gemm_mfma2(const unsigned short* __restrict__ Ah,
                                                  const unsigned short* __restrict__ Al,
                                                  const unsigned short* __restrict__ Bh,
                                                  const unsigned short* __restrict__ Bl,
                                                  float* __restrict__ C,
                                                  int M, int N, int K) {
  constexpr int NF = BN / 16;
  const int t = threadIdx.x;
  const int lane = t & 63;
  const int wv = t >> 6;  // 0..1
  const int m0 = blockIdx.y * 64 + wv * 32;
  const int n0 = blockIdx.x * BN;
  const int lr = lane & 15;
  const int kg = lane >> 4;

  const unsigned short* a0h = Ah + (size_t)(m0 + lr) * K + kg * 8;
  const unsigned short* a1h = a0h + (size_t)16 * K;
  const unsigned short* a0l = Al + (size_t)(m0 + lr) * K + kg * 8;
  const unsigned short* a1l = a0l + (size_t)16 * K;
  const unsigned short* bph = Bh + (size_t)(n0 + lr) * K + kg * 8;
  const unsigned short* bpl = Bl + (size_t)(n0 + lr) * K + kg * 8;

  f32x4m acc[2][NF];
#pragma unroll
  for (int i = 0; i < 2; ++i)
#pragma unroll
    for (int f = 0; f < NF; ++f) {
      f32x4m z = {0.f, 0.f, 0.f, 0.f};
      acc[i][f] = z;
    }

  for (int k0 = 0; k0 < K; k0 += 32) {
    bf16x8 ah0 = *(const bf16x8*)(a0h + k0);
    bf16x8 ah1 = *(const bf16x8*)(a1h + k0);
    bf16x8 al0 = *(const bf16x8*)(a0l + k0);
    bf16x8 al1 = *(const bf16x8*)(a1l + k0);
#pragma unroll
    for (int f = 0; f < NF; ++f) {
      bf16x8 vbh = *(const bf16x8*)(bph + (size_t)f * 16 * K + k0);
      bf16x8 vbl = *(const bf16x8*)(bpl + (size_t)f * 16 * K + k0);
      acc[0][f] = __builtin_amdgcn_mfma_f32_16x16x32_bf16(al0, vbh, acc[0][f], 0, 0, 0);
      acc[0][f] = __builtin_amdgcn_mfma_f32_16x16x32_bf16(ah0, vbl, acc[0][f], 0, 0, 0);
      acc[0][f] = __builtin_amdgcn_mfma_f32_16x16x32_bf16(ah0, vbh, acc[0][f], 0, 0, 0);
      acc[1][f] = __builtin_amdgcn_mfma_f32_16x16x32_bf16(al1, vbh, acc[1][f], 0, 0, 0);
      acc[1][f] = __builtin_amdgcn_mfma_f32_16x16x32_bf16(ah1, vbl, acc[1][f], 0, 0, 0);
      acc[1][f] = __builtin_amdgcn_mfma_f32_16x16x32_bf16(ah1, vbh, acc[1][f], 0, 0, 0);
    }
  }
#pragma unroll
  for (int i = 0; i < 2; ++i)
#pragma unroll
    for (int f = 0; f < NF; ++f)
#pragma unroll
      for (int r = 0; r < 4; ++r)
        C[(size_t)(m0 + i * 16 + kg * 4 + r) * N + n0 + f * 16 + lr] = acc[i][f][r];
}

// ---------------- gaussian kernel weights: q_w (× 1/temp), k_w ----------------
__global__ __launch_bounds__(256) void k_gauss(const float* __restrict__ qkv,
                                               const float* __restrict__ centers,
                                               const float* __restrict__ inv_var,
                                               const float* __restrict__ eff_amps,
                                               const float* __restrict__ inv_temp,
                                               float* __restrict__ qw,
                                               float* __restrict__ kw) {
  int gid = blockIdx.x * blockDim.x + threadIdx.x;
  if (gid >= B_ * T_ * H_ * S_) return;
  int s = gid & 15;
  int h = (gid >> 4) & 7;
  int bt = gid >> 7;  // b*T + t
  const float* qrow = qkv + (size_t)bt * 1536 + h * 64;
  const float* krow = qrow + 512;
  const float* c = centers + (h * 16 + s) * 64;
  float qd = 0.f, kd = 0.f;
#pragma unroll
  for (int d = 0; d < 64; d += 4) {
    float4 cv = *(const float4*)(c + d);
    float4 qv = *(const float4*)(qrow + d);
    float4 kv = *(const float4*)(krow + d);
    float t;
    t = qv.x - cv.x; qd += t * t;
    t = qv.y - cv.y; qd += t * t;
    t = qv.z - cv.z; qd += t * t;
    t = qv.w - cv.w; qd += t * t;
    t = kv.x - cv.x; kd += t * t;
    t = kv.y - cv.y; kd += t * t;
    t = kv.z - cv.z; kd += t * t;
    t = kv.w - cv.w; kd += t * t;
  }
  qd = fminf(qd, 100.f);
  kd = fminf(kd, 100.f);
  float iv = inv_var[h * 16 + s];
  float ea = eff_amps[h * 16 + s];
  qw[gid] = __expf(-0.5f * qd * iv) * ea * inv_temp[0];
  kw[gid] = __expf(-0.5f * kd * iv) * ea;
}

__device__ __forceinline__ float dot16(const float4 q[4], const float4 k[4]) {
  return q[0].x * k[0].x + q[0].y * k[0].y + q[0].z * k[0].z + q[0].w * k[0].w +
         q[1].x * k[1].x + q[1].y * k[1].y + q[1].z * k[1].z + q[1].w * k[1].w +
         q[2].x * k[2].x + q[2].y * k[2].y + q[2].z * k[2].z + q[2].w * k[2].w +
         q[3].x * k[3].x + q[3].y * k[3].y + q[3].z * k[3].z + q[3].w * k[3].w;
}

// ---------------- fused stats + vtr (8:1 WG interleave) ----------------
__global__ __launch_bounds__(256, 4) void k_sv(const float* __restrict__ qw_g,
                                               const float* __restrict__ kw_g,
                                               const float* __restrict__ qkv,
                                               float* __restrict__ m_g,
                                               float* __restrict__ is_g,
                                               unsigned short* __restrict__ vth,
                                               unsigned short* __restrict__ vtl) {
  union Sm {
    float red[4][4][2][2];
    float Vl[64][68];
  };
  __shared__ Sm sm;
  const int bid = blockIdx.x;
  const int g = bid / 9;
  const int r = bid - g * 9;
  const int t = threadIdx.x;

  if (r < 8) {
    const int x = g * 8 + r;  // 0..4095
    const int ic = x & 127;
    const int h = (x >> 7) & 7;
    const int b = x >> 10;
    const int i0 = ic * ITS;
    const int rp = t & 3;
    const int jl = t >> 2;

    float qwr[2][16], mr[2], sr[2];
#pragma unroll
    for (int e = 0; e < 2; ++e) {
      const float* qp = qw_g + (((size_t)(b * T_ + i0 + rp * 2 + e) * H_ + h) * S_);
#pragma unroll
      for (int s4 = 0; s4 < 4; ++s4) {
        float4 v = *(const float4*)(qp + s4 * 4);
        qwr[e][s4 * 4 + 0] = v.x; qwr[e][s4 * 4 + 1] = v.y;
        qwr[e][s4 * 4 + 2] = v.z; qwr[e][s4 * 4 + 3] = v.w;
      }
      mr[e] = -1e30f; sr[e] = 0.f;
    }
    for (int c = 0; c < T_ / 64; ++c) {
      int j = c * 64 + jl;
      const float* kp = kw_g + ((size_t)(b * T_ + j) * H_ + h) * S_;
      float4 k0 = *(const float4*)(kp);
      float4 k1 = *(const float4*)(kp + 4);
      float4 k2 = *(const float4*)(kp + 8);
      float4 k3 = *(const float4*)(kp + 12);
#pragma unroll
      for (int e = 0; e < 2; ++e) {
        float d = qwr[e][0] * k0.x + qwr[e][1] * k0.y + qwr[e][2] * k0.z + qwr[e][3] * k0.w +
                  qwr[e][4] * k1.x + qwr[e][5] * k1.y + qwr[e][6] * k1.z + qwr[e][7] * k1.w +
                  qwr[e][8] * k2.x + qwr[e][9] * k2.y + qwr[e][10] * k2.z + qwr[e][11] * k2.w +
                  qwr[e][12] * k3.x + qwr[e][13] * k3.y + qwr[e][14] * k3.z + qwr[e][15] * k3.w;
        float mn = fmaxf(mr[e], d);
        sr[e] = sr[e] * __expf(mr[e] - mn) + __expf(d - mn);
        mr[e] = mn;
      }
    }
#pragma unroll
    for (int o = 4; o < 64; o <<= 1) {
#pragma unroll
      for (int e = 0; e < 2; ++e) {
        float m2 = __shfl_xor(mr[e], o);
        float s2 = __shfl_xor(sr[e], o);
        float mn = fmaxf(mr[e], m2);
        sr[e] = sr[e] * __expf(mr[e] - mn) + s2 * __expf(m2 - mn);
        mr[e] = mn;
      }
    }
    int wv = t >> 6;
    if ((t & 63) < 4) {
      sm.red[wv][rp][0][0] = mr[0]; sm.red[wv][rp][0][1] = sr[0];
      sm.red[wv][rp][1][0] = mr[1]; sm.red[wv][rp][1][1] = sr[1];
    }
    __syncthreads();
    if (t < ITS) {
      int rpp = t >> 1, e = t & 1;
      float mf = sm.red[0][rpp][e][0], sf = sm.red[0][rpp][e][1];
#pragma unroll
      for (int w = 1; w < 4; ++w) {
        float m2 = sm.red[w][rpp][e][0], s2 = sm.red[w][rpp][e][1];
        float mn = fmaxf(mf, m2);
        sf = sf * __expf(mf - mn) + s2 * __expf(m2 - mn);
        mf = mn;
      }
      size_t o = (size_t)(b * H_ + h) * T_ + i0 + t;
      m_g[o] = mf;
      is_g[o] = 1.f / sf;
    }
  } else {
    const int id = g;  // 0..511
    const int jc = id & 15;
    const int h = (id >> 4) & 7;
    const int b = id >> 7;
    const int j0 = jc * 64;
    {
      int jj = t >> 2, dqg = t & 3;
      const float* vp = qkv + (size_t)(b * T_ + j0 + jj) * 1536 + 1024 + h * 64 + dqg * 16;
#pragma unroll
      for (int q = 0; q < 4; ++q) {
        float4 v = *(const float4*)(vp + q * 4);
        *(float4*)&sm.Vl[jj][dqg * 16 + q * 4] = v;
      }
    }
    __syncthreads();
    {
      int d = t >> 2, jg = t & 3;
      ushort4 hs[4], ls[4];
#pragma unroll
      for (int q = 0; q < 4; ++q) {
        float f0 = sm.Vl[jg * 16 + q * 4 + 0][d];
        float f1 = sm.Vl[jg * 16 + q * 4 + 1][d];
        float f2 = sm.Vl[jg * 16 + q * 4 + 2][d];
        float f3 = sm.Vl[jg * 16 + q * 4 + 3][d];
        hs[q].x = f2bf(f0); ls[q].x = f2bf(f0 - bf2f(hs[q].x));
        hs[q].y = f2bf(f1); ls[q].y = f2bf(f1 - bf2f(hs[q].y));
        hs[q].z = f2bf(f2); ls[q].z = f2bf(f2 - bf2f(hs[q].z));
        hs[q].w = f2bf(f3); ls[q].w = f2bf(f3 - bf2f(hs[q].w));
      }
      size_t off = ((size_t)(b * H_ + h) * 64 + d) * 1024 + j0 + jg * 16;
#pragma unroll
      for (int q = 0; q < 4; ++q) {
        *(ushort4*)(vth + off + q * 4) = hs[q];
        *(ushort4*)(vtl + off + q * 4) = ls[q];
      }
    }
  }
}

// ---------------- attn writer (v1 body, jt-split 8) ----------------
__global__ __launch_bounds__(256, 4) void k_attnw(const float* __restrict__ qw_g,
                                                  const float* __restrict__ kw_g,
                                                  const float* __restrict__ m_g,
                                                  const float* __restrict__ is_g,
                                                  float* __restrict__ attn) {
  const int x = blockIdx.x;
  const int jt = x & 7;
  const int it = (x >> 3) & 127;
  const int b = x >> 10;
  const int i0 = it * ITW;
  const int jbase = jt * 128;
  const int tid = threadIdx.x;

  __shared__ float qw_l[ITW][H_ * S_];     // 4 KB
  __shared__ float msl[ITW][H_];
  __shared__ float isl[ITW][H_];
  __shared__ float tile[ITW][H_][68];      // 17.4 KB

  {
    int f = tid * 4;
    int r = f >> 7, c = f & 127;
    *(float4*)&qw_l[r][c] = *(const float4*)(qw_g + ((size_t)(b * T_ + i0 + r) * 128 + c));
  }
  if (tid < 64) {
    int r = tid >> 3, hh = tid & 7;
    size_t o = (size_t)(b * H_ + hh) * T_ + i0 + r;
    msl[r][hh] = m_g[o];
    isl[r][hh] = is_g[o];
  }
  __syncthreads();

  const int h = tid >> 5;
  const int jq = tid & 31;
  const float* kw_b = kw_g + (size_t)b * T_ * (H_ * S_);
  float* attn_b = attn + (size_t)(b * T_ + i0) * (T_ * H_);

  for (int st = 0; st < 2; ++st) {
    const int j0 = jbase + st * 64;
    const float* kp = kw_b + ((size_t)(j0 + jq * 2) * H_ + h) * S_;
    float4 ka[4], kb[4];
    ka[0] = *(const float4*)(kp);       ka[1] = *(const float4*)(kp + 4);
    ka[2] = *(const float4*)(kp + 8);   ka[3] = *(const float4*)(kp + 12);
    kb[0] = *(const float4*)(kp + 128); kb[1] = *(const float4*)(kp + 132);
    kb[2] = *(const float4*)(kp + 136); kb[3] = *(const float4*)(kp + 140);
#pragma unroll
    for (int r = 0; r < ITW; ++r) {
      float4 q4[4];
      q4[0] = *(const float4*)&qw_l[r][h * 16 + 0];
      q4[1] = *(const float4*)&qw_l[r][h * 16 + 4];
      q4[2] = *(const float4*)&qw_l[r][h * 16 + 8];
      q4[3] = *(const float4*)&qw_l[r][h * 16 + 12];
      float la = dot16(q4, ka);
      float lb = dot16(q4, kb);
      float mm = msl[r][h], ii = isl[r][h];
      *(float2*)&tile[r][h][jq * 2] =
          make_float2(__expf(la - mm) * ii, __expf(lb - mm) * ii);
    }
    __syncthreads();
#pragma unroll
    for (int l = 0; l < 4; ++l) {
      int f = (l * 256 + tid) * 4;
      int r = f >> 9;
      int rem = f & 511;
      int jl = rem >> 3;
      int h0 = rem & 7;  // 0 or 4
      float4 v;
      v.x = tile[r][h0 + 0][jl];
      v.y = tile[r][h0 + 1][jl];
      v.z = tile[r][h0 + 2][jl];
      v.w = tile[r][h0 + 3][jl];
      *(float4*)(attn_b + (size_t)r * (T_ * H_) + (size_t)(j0 + jl) * H_ + h0) = v;
    }
    __syncthreads();
  }
}

// ---------------- PV via MFMA, V from transposed bf16 panels (v5) ----------------
__global__ __launch_bounds__(256, 4) void k_pv(const float* __restrict__ qw_g,
                                               const float* __restrict__ kw_g,
                                               const float* __restrict__ m_g,
                                               const float* __restrict__ is_g,
                                               const unsigned short* __restrict__ vth,
                                               const unsigned short* __restrict__ vtl,
                                               unsigned short* __restrict__ oph,
                                               unsigned short* __restrict__ opl) {
  const int bid = blockIdx.x;
  const int xcd = bid & 7;
  const int qq = bid >> 3;             // 0..127
  const int p = xcd * 4 + (qq & 3);    // panel 0..31
  const int ib = qq >> 2;              // 0..31
  const int b = p >> 3;
  const int h = p & 7;
  const int i0 = ib * PVI;
  const int t = threadIdx.x;
  const int lane = t & 63;
  const int w = t >> 6;
  const int I = w >> 1;                // i-frag
  const int S = w & 1;                 // k-step (32-j half of chunk)
  const int lr = lane & 15;
  const int kg = lane >> 4;

  __shared__ float kw_sw[PVJ][16];     // 4 KB; s4-block ^= (j>>3)&3
  __shared__ float mgs[128][17];       // 8.7 KB merge scratch

  const int irow = I * 16 + lr;
  float qwr[16];
  {
    const float* qp = qw_g + (((size_t)(b * T_ + i0 + irow) * H_ + h) * S_);
#pragma unroll
    for (int s4 = 0; s4 < 4; ++s4) {
      float4 v = *(const float4*)(qp + s4 * 4);
      qwr[s4 * 4 + 0] = v.x; qwr[s4 * 4 + 1] = v.y;
      qwr[s4 * 4 + 2] = v.z; qwr[s4 * 4 + 3] = v.w;
    }
  }
  float mr = m_g[(size_t)(b * H_ + h) * T_ + i0 + irow];
  float isr = is_g[(size_t)(b * H_ + h) * T_ + i0 + irow];
#pragma unroll
  for (int s = 0; s < 16; ++s) asm volatile("" : "+v"(qwr[s]));
  asm volatile("" : "+v"(mr));
  asm volatile("" : "+v"(isr));

  const unsigned short* vhp = vth + ((size_t)(b * H_ + h) * 64) * 1024;
  const unsigned short* vlp = vtl + ((size_t)(b * H_ + h) * 64) * 1024;

  f32x4m acc[4];
#pragma unroll
  for (int f = 0; f < 4; ++f) { f32x4m z = {0.f, 0.f, 0.f, 0.f}; acc[f] = z; }

  for (int jc = 0; jc < T_ / PVJ; ++jc) {
    const int j0 = jc * PVJ;
    __syncthreads();
    {
      int j = t >> 2, s4g = t & 3;
      float4 v = *(const float4*)(kw_g + (((size_t)(b * T_ + j0 + j) * H_ + h) * S_ + s4g * 4));
      int blk = s4g ^ ((j >> 3) & 3);
      *(float4*)&kw_sw[j][blk * 4] = v;
    }
    __syncthreads();
    union UA { unsigned short s[8]; bf16x8 v; } AH, AL;
#pragma unroll
    for (int u = 0; u < 8; ++u) {
      int jr = S * 32 + kg * 8 + u;
      int g = (jr >> 3) & 3;
      float d = 0.f;
#pragma unroll
      for (int s4 = 0; s4 < 4; ++s4) {
        float4 kv = *(const float4*)&kw_sw[jr][(s4 ^ g) * 4];
        d += qwr[s4 * 4 + 0] * kv.x + qwr[s4 * 4 + 1] * kv.y +
             qwr[s4 * 4 + 2] * kv.z + qwr[s4 * 4 + 3] * kv.w;
      }
      float pv = __expf(d - mr) * isr;
      unsigned short hh = f2bf(pv);
      AH.s[u] = hh;
      AL.s[u] = f2bf(pv - bf2f(hh));
    }
#pragma unroll
    for (int f = 0; f < 4; ++f) {
      size_t voff = (size_t)(f * 16 + lr) * 1024 + j0 + S * 32 + kg * 8;
      bf16x8 BHv = *(const bf16x8*)(vhp + voff);
      bf16x8 BLv = *(const bf16x8*)(vlp + voff);
      acc[f] = __builtin_amdgcn_mfma_f32_16x16x32_bf16(AL.v, BHv, acc[f], 0, 0, 0);
      acc[f] = __builtin_amdgcn_mfma_f32_16x16x32_bf16(AH.v, BLv, acc[f], 0, 0, 0);
      acc[f] = __builtin_amdgcn_mfma_f32_16x16x32_bf16(AH.v, BHv, acc[f], 0, 0, 0);
    }
  }
  __syncthreads();
  if (S == 1) {
    float* dst = &mgs[I * 64 + lane][0];
#pragma unroll
    for (int f = 0; f < 4; ++f)
#pragma unroll
      for (int r = 0; r < 4; ++r) dst[f * 4 + r] = acc[f][r];
  }
  __syncthreads();
  if (S == 0) {
    const float* src = &mgs[I * 64 + lane][0];
#pragma unroll
    for (int f = 0; f < 4; ++f) {
#pragma unroll
      for (int r = 0; r < 4; ++r) {
        float o = acc[f][r] + src[f * 4 + r];
        unsigned short hh = f2bf(o);
        unsigned short ll = f2bf(o - bf2f(hh));
        size_t idx = (size_t)(b * T_ + i0 + I * 16 + kg * 4 + r) * D_ + h * HD_ + f * 16 + lr;
        oph[idx] = hh;
        opl[idx] = ll;
      }
    }
  }
}

extern "C" void kernel_launch(void* const* d_in, const int* in_sizes, int n_in,
                              void* d_out, int out_size, void* d_ws, size_t ws_size,
                              hipStream_t stream) {
  const float* x = (const float*)d_in[0];
  const float* qkv_w = (const float*)d_in[1];
  const float* out_w = (const float*)d_in[2];
  const float* base_c = (const float*)d_in[3];
  const float* deltas = (const float*)d_in[4];
  const float* log_sc = (const float*)d_in[5];
  const float* log_am = (const float*)d_in[6];
  const float* move_p = (const float*)d_in[7];
  const float* temp = (const float*)d_in[8];

  float* out = (float*)d_out;                    // B*T*D
  float* attn = out + (size_t)B_ * T_ * D_;      // B*T*T*H

  float* ws = (float*)d_ws;
  float* qkv = ws;                                          // 6,291,456 f
  float* qw = qkv + 6291456;                                // 524,288
  float* kw = qw + 524288;                                  // 524,288
  float* centers = kw + 524288;                             // 8,192
  float* inv_var = centers + 8192;                          // 128
  float* eff_amps = inv_var + 128;                          // 128
  float* inv_temp = eff_amps + 128;                         // 4
  float* m_g = inv_temp + 4;                                // 32,768
  float* is_g = m_g + 32768;                                // 32,768
  unsigned short* xh = (unsigned short*)(is_g + 32768);     // 2,097,152 us
  unsigned short* xl = xh + 2097152;                        // 2,097,152
  unsigned short* wh = xl + 2097152;                        // 786,432
  unsigned short* wl = wh + 786432;                         // 786,432
  unsigned short* owh = wl + 786432;                        // 262,144
  unsigned short* owl = owh + 262144;                       // 262,144
  unsigned short* oph = owl + 262144;                       // 2,097,152
  unsigned short* opl = oph + 2097152;                      // 2,097,152
  unsigned short* vth = opl + 2097152;                      // 2,097,152
  unsigned short* vtl = vth + 2097152;                      // 2,097,152

  k_prep<<<3104, 256, 0, stream>>>(x, qkv_w, out_w, base_c, deltas, log_sc, log_am,
                                   move_p, temp, xh, xl, wh, wl, owh, owl,
                                   centers, inv_var, eff_amps, inv_temp);

  dim3 g1(1536 / 64, 4096 / 128);   // 24 x 32 = 768 WGs
  gemm_mfma<64><<<g1, 256, 0, stream>>>(xh, xl, wh, wl, qkv, B_ * T_, 3 * D_, D_);

  k_gauss<<<(B_ * T_ * H_ * S_) / 256, 256, 0, stream>>>(qkv, centers, inv_var,
                                                         eff_amps, inv_temp, qw, kw);
  k_sv<<<4608, 256, 0, stream>>>(qw, kw, qkv, m_g, is_g, vth, vtl);
  k_attnw<<<B_ * (T_ / ITW) * 8, 256, 0, stream>>>(qw, kw, m_g, is_g, attn);
  k_pv<<<B_ * H_ * (T_ / PVI), 256, 0, stream>>>(qw, kw, m_g, is_g, vth, vtl, oph, opl);

  dim3 g2(512 / 32, 4096 / 64);     // 16 x 64 = 1024 WGs
  gemm_mfma2<32><<<g2, 128, 0, stream>>>(oph, opl, owh, owl, out, B_ * T_, D_, D_);
}

// Round 17
// 253.418 us; speedup vs baseline: 1.2718x; 1.0660x over previous
//
#include <hip/hip_runtime.h>
#include <hip/hip_bf16.h>

#define B_ 4
#define T_ 1024
#define D_ 512
#define H_ 8
#define S_ 16
#define HD_ 64
#define ITS 8    // i-rows per WG (stats)
#define ITW 8    // i-rows per WG (attnw)
#define PVI 32   // i-rows per WG (pv)
#define PVJ 64   // j-chunk (pv)

typedef short bf16x8 __attribute__((ext_vector_type(8)));
typedef float f32x4m __attribute__((ext_vector_type(4)));

__device__ __forceinline__ unsigned short f2bf(float f) {
  unsigned u = __float_as_uint(f);
  unsigned r = (u + 0x7FFFu + ((u >> 16) & 1u)) >> 16;  // RNE
  return (unsigned short)r;
}
__device__ __forceinline__ float bf2f(unsigned short h) {
  return __uint_as_float((unsigned)h << 16);
}

__device__ __forceinline__ void split4(const float4 v, ushort4& h, ushort4& l) {
  h.x = f2bf(v.x); l.x = f2bf(v.x - bf2f(h.x));
  h.y = f2bf(v.y); l.y = f2bf(v.y - bf2f(h.y));
  h.z = f2bf(v.z); l.z = f2bf(v.z - bf2f(h.z));
  h.w = f2bf(v.w); l.w = f2bf(v.w - bf2f(h.w));
}

// ---------------- prep: params + 3 fp32->bf16hi/lo splits, fused ----------------
__global__ __launch_bounds__(256) void k_prep(const float* __restrict__ x,
                                              const float* __restrict__ qkv_w,
                                              const float* __restrict__ out_w,
                                              const float* __restrict__ base_centers,
                                              const float* __restrict__ center_deltas,
                                              const float* __restrict__ log_scales,
                                              const float* __restrict__ log_amps,
                                              const float* __restrict__ movement_param,
                                              const float* __restrict__ temperature,
                                              unsigned short* __restrict__ xh,
                                              unsigned short* __restrict__ xl,
                                              unsigned short* __restrict__ wh,
                                              unsigned short* __restrict__ wl,
                                              unsigned short* __restrict__ owh,
                                              unsigned short* __restrict__ owl,
                                              float* __restrict__ centers,
                                              float* __restrict__ inv_var,
                                              float* __restrict__ eff_amps,
                                              float* __restrict__ inv_temp) {
  const int bid = blockIdx.x;
  const int t = threadIdx.x;
  if (bid < 2048) {
    int i = bid * 256 + t;
    float4 v = ((const float4*)x)[i];
    ushort4 h, l; split4(v, h, l);
    ((ushort4*)xh)[i] = h; ((ushort4*)xl)[i] = l;
  } else if (bid < 2816) {
    int i = (bid - 2048) * 256 + t;
    float4 v = ((const float4*)qkv_w)[i];
    ushort4 h, l; split4(v, h, l);
    ((ushort4*)wh)[i] = h; ((ushort4*)wl)[i] = l;
  } else if (bid < 3072) {
    int i = (bid - 2816) * 256 + t;
    float4 v = ((const float4*)out_w)[i];
    ushort4 h, l; split4(v, h, l);
    ((ushort4*)owh)[i] = h; ((ushort4*)owl)[i] = l;
  } else {
    int tid = (bid - 3072) * 256 + t;  // 0..8191
    float move = (1.f / (1.f + __expf(-movement_param[0]))) * 0.2f;
    centers[tid] = base_centers[tid] + center_deltas[tid] * move;
    if (tid < H_ * S_) {
      float sc = __expf(log_scales[tid]);
      sc = fminf(fmaxf(sc, 1e-4f), 5.f);
      float am = __expf(log_amps[tid]);
      am = fminf(fmaxf(am, 1e-6f), 10.f);
      inv_var[tid] = 1.f / (sc * sc + 1e-8f);
      eff_amps[tid] = (am > 0.001f) ? am : 0.f;
    }
    if (tid == 0) {
      float tt = fminf(fmaxf(temperature[0], 0.01f), 10.f);
      inv_temp[0] = 1.f / tt;
    }
  }
}

// ---------------- split-bf16 MFMA GEMM, B staged in swizzled LDS (4-wave) ----------------
template <int BN>
__global__ __launch_bounds__(256) void gemm_mfma(const unsigned short* __restrict__ Ah,
                                                 const unsigned short* __restrict__ Al,
                                                 const unsigned short* __restrict__ Bh,
                                                 const unsigned short* __restrict__ Bl,
                                                 float* __restrict__ C,
                                                 int M, int N, int K) {
  static_assert(BN == 64, "staging sized for BN=64");
  constexpr int NF = BN / 16;
  const int t = threadIdx.x;
  const int lane = t & 63;
  const int wv = t >> 6;
  const int m0 = blockIdx.y * 128 + wv * 32;
  const int n0 = blockIdx.x * BN;
  const int lr = lane & 15;
  const int kg = lane >> 4;

  __shared__ unsigned short Bsh[64][64];  // 8 KB
  __shared__ unsigned short Bsl[64][64];  // 8 KB

  const unsigned short* a0h = Ah + (size_t)(m0 + lr) * K + kg * 8;
  const unsigned short* a1h = a0h + (size_t)16 * K;
  const unsigned short* a0l = Al + (size_t)(m0 + lr) * K + kg * 8;
  const unsigned short* a1l = a0l + (size_t)16 * K;

  f32x4m acc[2][NF];
#pragma unroll
  for (int i = 0; i < 2; ++i)
#pragma unroll
    for (int f = 0; f < NF; ++f) {
      f32x4m z = {0.f, 0.f, 0.f, 0.f};
      acc[i][f] = z;
    }

  for (int k0 = 0; k0 < K; k0 += 64) {
    if (k0) __syncthreads();  // previous chunk's readers done
#pragma unroll
    for (int r2 = 0; r2 < 2; ++r2) {
      int idx = t + r2 * 256;
      int row = idx >> 3, c8 = idx & 7;
      int c8s = c8 ^ (row & 7);
      float4 vh = *(const float4*)(Bh + (size_t)(n0 + row) * K + k0 + c8 * 8);
      float4 vl = *(const float4*)(Bl + (size_t)(n0 + row) * K + k0 + c8 * 8);
      *(float4*)&Bsh[row][c8s * 8] = vh;
      *(float4*)&Bsl[row][c8s * 8] = vl;
    }
    __syncthreads();
#pragma unroll
    for (int S2 = 0; S2 < 2; ++S2) {
      const int kk = k0 + S2 * 32;
      bf16x8 ah0 = *(const bf16x8*)(a0h + kk);
      bf16x8 ah1 = *(const bf16x8*)(a1h + kk);
      bf16x8 al0 = *(const bf16x8*)(a0l + kk);
      bf16x8 al1 = *(const bf16x8*)(a1l + kk);
#pragma unroll
      for (int f = 0; f < NF; ++f) {
        int row = f * 16 + lr;
        int sl = (S2 * 4 + kg) ^ (row & 7);
        bf16x8 vbh = *(const bf16x8*)&Bsh[row][sl * 8];
        bf16x8 vbl = *(const bf16x8*)&Bsl[row][sl * 8];
        acc[0][f] = __builtin_amdgcn_mfma_f32_16x16x32_bf16(al0, vbh, acc[0][f], 0, 0, 0);
        acc[0][f] = __builtin_amdgcn_mfma_f32_16x16x32_bf16(ah0, vbl, acc[0][f], 0, 0, 0);
        acc[0][f] = __builtin_amdgcn_mfma_f32_16x16x32_bf16(ah0, vbh, acc[0][f], 0, 0, 0);
        acc[1][f] = __builtin_amdgcn_mfma_f32_16x16x32_bf16(al1, vbh, acc[1][f], 0, 0, 0);
        acc[1][f] = __builtin_amdgcn_mfma_f32_16x16x32_bf16(ah1, vbl, acc[1][f], 0, 0, 0);
        acc[1][f] = __builtin_amdgcn_mfma_f32_16x16x32_bf16(ah1, vbh, acc[1][f], 0, 0, 0);
      }
    }
  }
#pragma unroll
  for (int i = 0; i < 2; ++i)
#pragma unroll
    for (int f = 0; f < NF; ++f)
#pragma unroll
      for (int r = 0; r < 4; ++r)
        C[(size_t)(m0 + i * 16 + kg * 4 + r) * N + n0 + f * 16 + lr] = acc[i][f][r];
}

// ---------------- 2-wave out-proj GEMM, B staged in swizzled LDS ----------------
// Same staging pattern that won 36us on the QKV GEMM: 64 m-blocks re-read the
// same B panel; stage the 32x64 hi/lo chunk once per WG (8 KB LDS).
template <int BN>
__global__ __launch_bounds__(128) void gemm_mfma2(const unsigned short* __restrict__ Ah,
                                                  const unsigned short* __restrict__ Al,
                                                  const unsigned short* __restrict__ Bh,
                                                  const unsigned short* __restrict__ Bl,
                                                  float* __restrict__ C,
                                                  int M, int N, int K) {
  static_assert(BN == 32, "staging sized for BN=32");
  constexpr int NF = BN / 16;
  const int t = threadIdx.x;
  const int lane = t & 63;
  const int wv = t >> 6;  // 0..1
  const int m0 = blockIdx.y * 64 + wv * 32;
  const int n0 = blockIdx.x * BN;
  const int lr = lane & 15;
  const int kg = lane >> 4;

  __shared__ unsigned short Bsh[32][64];  // 4 KB
  __shared__ unsigned short Bsl[32][64];  // 4 KB

  const unsigned short* a0h = Ah + (size_t)(m0 + lr) * K + kg * 8;
  const unsigned short* a1h = a0h + (size_t)16 * K;
  const unsigned short* a0l = Al + (size_t)(m0 + lr) * K + kg * 8;
  const unsigned short* a1l = a0l + (size_t)16 * K;

  f32x4m acc[2][NF];
#pragma unroll
  for (int i = 0; i < 2; ++i)
#pragma unroll
    for (int f = 0; f < NF; ++f) {
      f32x4m z = {0.f, 0.f, 0.f, 0.f};
      acc[i][f] = z;
    }

  for (int k0 = 0; k0 < K; k0 += 64) {
    if (k0) __syncthreads();
#pragma unroll
    for (int r2 = 0; r2 < 2; ++r2) {
      int idx = t + r2 * 128;
      int row = idx >> 3, c8 = idx & 7;
      int c8s = c8 ^ (row & 7);
      float4 vh = *(const float4*)(Bh + (size_t)(n0 + row) * K + k0 + c8 * 8);
      float4 vl = *(const float4*)(Bl + (size_t)(n0 + row) * K + k0 + c8 * 8);
      *(float4*)&Bsh[row][c8s * 8] = vh;
      *(float4*)&Bsl[row][c8s * 8] = vl;
    }
    __syncthreads();
#pragma unroll
    for (int S2 = 0; S2 < 2; ++S2) {
      const int kk = k0 + S2 * 32;
      bf16x8 ah0 = *(const bf16x8*)(a0h + kk);
      bf16x8 ah1 = *(const bf16x8*)(a1h + kk);
      bf16x8 al0 = *(const bf16x8*)(a0l + kk);
      bf16x8 al1 = *(const bf16x8*)(a1l + kk);
#pragma unroll
      for (int f = 0; f < NF; ++f) {
        int row = f * 16 + lr;
        int sl = (S2 * 4 + kg) ^ (row & 7);
        bf16x8 vbh = *(const bf16x8*)&Bsh[row][sl * 8];
        bf16x8 vbl = *(const bf16x8*)&Bsl[row][sl * 8];
        acc[0][f] = __builtin_amdgcn_mfma_f32_16x16x32_bf16(al0, vbh, acc[0][f], 0, 0, 0);
        acc[0][f] = __builtin_amdgcn_mfma_f32_16x16x32_bf16(ah0, vbl, acc[0][f], 0, 0, 0);
        acc[0][f] = __builtin_amdgcn_mfma_f32_16x16x32_bf16(ah0, vbh, acc[0][f], 0, 0, 0);
        acc[1][f] = __builtin_amdgcn_mfma_f32_16x16x32_bf16(al1, vbh, acc[1][f], 0, 0, 0);
        acc[1][f] = __builtin_amdgcn_mfma_f32_16x16x32_bf16(ah1, vbl, acc[1][f], 0, 0, 0);
        acc[1][f] = __builtin_amdgcn_mfma_f32_16x16x32_bf16(ah1, vbh, acc[1][f], 0, 0, 0);
      }
    }
  }
#pragma unroll
  for (int i = 0; i < 2; ++i)
#pragma unroll
    for (int f = 0; f < NF; ++f)
#pragma unroll
      for (int r = 0; r < 4; ++r)
        C[(size_t)(m0 + i * 16 + kg * 4 + r) * N + n0 + f * 16 + lr] = acc[i][f][r];
}

// ---------------- gaussian kernel weights v2: 2 s-values share q/k rows ----------------
__global__ __launch_bounds__(256) void k_gauss(const float* __restrict__ qkv,
                                               const float* __restrict__ centers,
                                               const float* __restrict__ inv_var,
                                               const float* __restrict__ eff_amps,
                                               const float* __restrict__ inv_temp,
                                               float* __restrict__ qw,
                                               float* __restrict__ kw) {
  int gid = blockIdx.x * blockDim.x + threadIdx.x;  // 0..B*T*H*8-1
  int s = gid & 7;
  int h = (gid >> 3) & 7;
  int bt = gid >> 6;
  const float* qrow = qkv + (size_t)bt * 1536 + h * 64;
  const float* krow = qrow + 512;
  const float* c0 = centers + (h * 16 + s) * 64;
  const float* c1 = c0 + 8 * 64;  // s+8
  float qd0 = 0.f, kd0 = 0.f, qd1 = 0.f, kd1 = 0.f;
#pragma unroll
  for (int d = 0; d < 64; d += 4) {
    float4 qv = *(const float4*)(qrow + d);
    float4 kv = *(const float4*)(krow + d);
    float4 ca = *(const float4*)(c0 + d);
    float4 cb = *(const float4*)(c1 + d);
    float t;
    t = qv.x - ca.x; qd0 += t * t;  t = qv.y - ca.y; qd0 += t * t;
    t = qv.z - ca.z; qd0 += t * t;  t = qv.w - ca.w; qd0 += t * t;
    t = kv.x - ca.x; kd0 += t * t;  t = kv.y - ca.y; kd0 += t * t;
    t = kv.z - ca.z; kd0 += t * t;  t = kv.w - ca.w; kd0 += t * t;
    t = qv.x - cb.x; qd1 += t * t;  t = qv.y - cb.y; qd1 += t * t;
    t = qv.z - cb.z; qd1 += t * t;  t = qv.w - cb.w; qd1 += t * t;
    t = kv.x - cb.x; kd1 += t * t;  t = kv.y - cb.y; kd1 += t * t;
    t = kv.z - cb.z; kd1 += t * t;  t = kv.w - cb.w; kd1 += t * t;
  }
  qd0 = fminf(qd0, 100.f); kd0 = fminf(kd0, 100.f);
  qd1 = fminf(qd1, 100.f); kd1 = fminf(kd1, 100.f);
  float it = inv_temp[0];
  float iv0 = inv_var[h * 16 + s],     ea0 = eff_amps[h * 16 + s];
  float iv1 = inv_var[h * 16 + s + 8], ea1 = eff_amps[h * 16 + s + 8];
  size_t base = (size_t)(bt * H_ + h) * S_ + s;
  qw[base]     = __expf(-0.5f * qd0 * iv0) * ea0 * it;
  kw[base]     = __expf(-0.5f * kd0 * iv0) * ea0;
  qw[base + 8] = __expf(-0.5f * qd1 * iv1) * ea1 * it;
  kw[base + 8] = __expf(-0.5f * kd1 * iv1) * ea1;
}

__device__ __forceinline__ float dot16(const float4 q[4], const float4 k[4]) {
  return q[0].x * k[0].x + q[0].y * k[0].y + q[0].z * k[0].z + q[0].w * k[0].w +
         q[1].x * k[1].x + q[1].y * k[1].y + q[1].z * k[1].z + q[1].w * k[1].w +
         q[2].x * k[2].x + q[2].y * k[2].y + q[2].z * k[2].z + q[2].w * k[2].w +
         q[3].x * k[3].x + q[3].y * k[3].y + q[3].z * k[3].z + q[3].w * k[3].w;
}

// ---------------- fused stats + vtr (8:1 WG interleave) ----------------
__global__ __launch_bounds__(256, 4) void k_sv(const float* __restrict__ qw_g,
                                               const float* __restrict__ kw_g,
                                               const float* __restrict__ qkv,
                                               float* __restrict__ m_g,
                                               float* __restrict__ is_g,
                                               unsigned short* __restrict__ vth,
                                               unsigned short* __restrict__ vtl) {
  union Sm {
    float red[4][4][2][2];
    float Vl[64][68];
  };
  __shared__ Sm sm;
  const int bid = blockIdx.x;
  const int g = bid / 9;
  const int r = bid - g * 9;
  const int t = threadIdx.x;

  if (r < 8) {
    const int x = g * 8 + r;  // 0..4095
    const int ic = x & 127;
    const int h = (x >> 7) & 7;
    const int b = x >> 10;
    const int i0 = ic * ITS;
    const int rp = t & 3;
    const int jl = t >> 2;

    float qwr[2][16], mr[2], sr[2];
#pragma unroll
    for (int e = 0; e < 2; ++e) {
      const float* qp = qw_g + (((size_t)(b * T_ + i0 + rp * 2 + e) * H_ + h) * S_);
#pragma unroll
      for (int s4 = 0; s4 < 4; ++s4) {
        float4 v = *(const float4*)(qp + s4 * 4);
        qwr[e][s4 * 4 + 0] = v.x; qwr[e][s4 * 4 + 1] = v.y;
        qwr[e][s4 * 4 + 2] = v.z; qwr[e][s4 * 4 + 3] = v.w;
      }
      mr[e] = -1e30f; sr[e] = 0.f;
    }
    for (int c = 0; c < T_ / 64; ++c) {
      int j = c * 64 + jl;
      const float* kp = kw_g + ((size_t)(b * T_ + j) * H_ + h) * S_;
      float4 k0 = *(const float4*)(kp);
      float4 k1 = *(const float4*)(kp + 4);
      float4 k2 = *(const float4*)(kp + 8);
      float4 k3 = *(const float4*)(kp + 12);
#pragma unroll
      for (int e = 0; e < 2; ++e) {
        float d = qwr[e][0] * k0.x + qwr[e][1] * k0.y + qwr[e][2] * k0.z + qwr[e][3] * k0.w +
                  qwr[e][4] * k1.x + qwr[e][5] * k1.y + qwr[e][6] * k1.z + qwr[e][7] * k1.w +
                  qwr[e][8] * k2.x + qwr[e][9] * k2.y + qwr[e][10] * k2.z + qwr[e][11] * k2.w +
                  qwr[e][12] * k3.x + qwr[e][13] * k3.y + qwr[e][14] * k3.z + qwr[e][15] * k3.w;
        float mn = fmaxf(mr[e], d);
        sr[e] = sr[e] * __expf(mr[e] - mn) + __expf(d - mn);
        mr[e] = mn;
      }
    }
#pragma unroll
    for (int o = 4; o < 64; o <<= 1) {
#pragma unroll
      for (int e = 0; e < 2; ++e) {
        float m2 = __shfl_xor(mr[e], o);
        float s2 = __shfl_xor(sr[e], o);
        float mn = fmaxf(mr[e], m2);
        sr[e] = sr[e] * __expf(mr[e] - mn) + s2 * __expf(m2 - mn);
        mr[e] = mn;
      }
    }
    int wv = t >> 6;
    if ((t & 63) < 4) {
      sm.red[wv][rp][0][0] = mr[0]; sm.red[wv][rp][0][1] = sr[0];
      sm.red[wv][rp][1][0] = mr[1]; sm.red[wv][rp][1][1] = sr[1];
    }
    __syncthreads();
    if (t < ITS) {
      int rpp = t >> 1, e = t & 1;
      float mf = sm.red[0][rpp][e][0], sf = sm.red[0][rpp][e][1];
#pragma unroll
      for (int w = 1; w < 4; ++w) {
        float m2 = sm.red[w][rpp][e][0], s2 = sm.red[w][rpp][e][1];
        float mn = fmaxf(mf, m2);
        sf = sf * __expf(mf - mn) + s2 * __expf(m2 - mn);
        mf = mn;
      }
      size_t o = (size_t)(b * H_ + h) * T_ + i0 + t;
      m_g[o] = mf;
      is_g[o] = 1.f / sf;
    }
  } else {
    const int id = g;  // 0..511
    const int jc = id & 15;
    const int h = (id >> 4) & 7;
    const int b = id >> 7;
    const int j0 = jc * 64;
    {
      int jj = t >> 2, dqg = t & 3;
      const float* vp = qkv + (size_t)(b * T_ + j0 + jj) * 1536 + 1024 + h * 64 + dqg * 16;
#pragma unroll
      for (int q = 0; q < 4; ++q) {
        float4 v = *(const float4*)(vp + q * 4);
        *(float4*)&sm.Vl[jj][dqg * 16 + q * 4] = v;
      }
    }
    __syncthreads();
    {
      int d = t >> 2, jg = t & 3;
      ushort4 hs[4], ls[4];
#pragma unroll
      for (int q = 0; q < 4; ++q) {
        float f0 = sm.Vl[jg * 16 + q * 4 + 0][d];
        float f1 = sm.Vl[jg * 16 + q * 4 + 1][d];
        float f2 = sm.Vl[jg * 16 + q * 4 + 2][d];
        float f3 = sm.Vl[jg * 16 + q * 4 + 3][d];
        hs[q].x = f2bf(f0); ls[q].x = f2bf(f0 - bf2f(hs[q].x));
        hs[q].y = f2bf(f1); ls[q].y = f2bf(f1 - bf2f(hs[q].y));
        hs[q].z = f2bf(f2); ls[q].z = f2bf(f2 - bf2f(hs[q].z));
        hs[q].w = f2bf(f3); ls[q].w = f2bf(f3 - bf2f(hs[q].w));
      }
      size_t off = ((size_t)(b * H_ + h) * 64 + d) * 1024 + j0 + jg * 16;
#pragma unroll
      for (int q = 0; q < 4; ++q) {
        *(ushort4*)(vth + off + q * 4) = hs[q];
        *(ushort4*)(vtl + off + q * 4) = ls[q];
      }
    }
  }
}

// ---------------- attn writer (v1 body, jt-split 16: one subtile per WG) ----------------
__global__ __launch_bounds__(256, 4) void k_attnw(const float* __restrict__ qw_g,
                                                  const float* __restrict__ kw_g,
                                                  const float* __restrict__ m_g,
                                                  const float* __restrict__ is_g,
                                                  float* __restrict__ attn) {
  const int x = blockIdx.x;
  const int jt = x & 15;
  const int it = (x >> 4) & 127;
  const int b = x >> 11;
  const int i0 = it * ITW;
  const int j0 = jt * 64;
  const int tid = threadIdx.x;

  __shared__ float qw_l[ITW][H_ * S_];     // 4 KB
  __shared__ float msl[ITW][H_];
  __shared__ float isl[ITW][H_];
  __shared__ float tile[ITW][H_][68];      // 17.4 KB

  {
    int f = tid * 4;
    int r = f >> 7, c = f & 127;
    *(float4*)&qw_l[r][c] = *(const float4*)(qw_g + ((size_t)(b * T_ + i0 + r) * 128 + c));
  }
  if (tid < 64) {
    int r = tid >> 3, hh = tid & 7;
    size_t o = (size_t)(b * H_ + hh) * T_ + i0 + r;
    msl[r][hh] = m_g[o];
    isl[r][hh] = is_g[o];
  }
  __syncthreads();

  const int h = tid >> 5;
  const int jq = tid & 31;
  const float* kw_b = kw_g + (size_t)b * T_ * (H_ * S_);
  float* attn_b = attn + (size_t)(b * T_ + i0) * (T_ * H_);

  const float* kp = kw_b + ((size_t)(j0 + jq * 2) * H_ + h) * S_;
  float4 ka[4], kb[4];
  ka[0] = *(const float4*)(kp);       ka[1] = *(const float4*)(kp + 4);
  ka[2] = *(const float4*)(kp + 8);   ka[3] = *(const float4*)(kp + 12);
  kb[0] = *(const float4*)(kp + 128); kb[1] = *(const float4*)(kp + 132);
  kb[2] = *(const float4*)(kp + 136); kb[3] = *(const float4*)(kp + 140);
#pragma unroll
  for (int r = 0; r < ITW; ++r) {
    float4 q4[4];
    q4[0] = *(const float4*)&qw_l[r][h * 16 + 0];
    q4[1] = *(const float4*)&qw_l[r][h * 16 + 4];
    q4[2] = *(const float4*)&qw_l[r][h * 16 + 8];
    q4[3] = *(const float4*)&qw_l[r][h * 16 + 12];
    float la = dot16(q4, ka);
    float lb = dot16(q4, kb);
    float mm = msl[r][h], ii = isl[r][h];
    *(float2*)&tile[r][h][jq * 2] =
        make_float2(__expf(la - mm) * ii, __expf(lb - mm) * ii);
  }
  __syncthreads();
#pragma unroll
  for (int l = 0; l < 4; ++l) {
    int f = (l * 256 + tid) * 4;
    int r = f >> 9;
    int rem = f & 511;
    int jl = rem >> 3;
    int h0 = rem & 7;  // 0 or 4
    float4 v;
    v.x = tile[r][h0 + 0][jl];
    v.y = tile[r][h0 + 1][jl];
    v.z = tile[r][h0 + 2][jl];
    v.w = tile[r][h0 + 3][jl];
    *(float4*)(attn_b + (size_t)r * (T_ * H_) + (size_t)(j0 + jl) * H_ + h0) = v;
  }
}

// ---------------- PV via MFMA, V from transposed bf16 panels (v5) ----------------
__global__ __launch_bounds__(256, 4) void k_pv(const float* __restrict__ qw_g,
                                               const float* __restrict__ kw_g,
                                               const float* __restrict__ m_g,
                                               const float* __restrict__ is_g,
                                               const unsigned short* __restrict__ vth,
                                               const unsigned short* __restrict__ vtl,
                                               unsigned short* __restrict__ oph,
                                               unsigned short* __restrict__ opl) {
  const int bid = blockIdx.x;
  const int xcd = bid & 7;
  const int qq = bid >> 3;             // 0..127
  const int p = xcd * 4 + (qq & 3);    // panel 0..31
  const int ib = qq >> 2;              // 0..31
  const int b = p >> 3;
  const int h = p & 7;
  const int i0 = ib * PVI;
  const int t = threadIdx.x;
  const int lane = t & 63;
  const int w = t >> 6;
  const int I = w >> 1;                // i-frag
  const int S = w & 1;                 // k-step (32-j half of chunk)
  const int lr = lane & 15;
  const int kg = lane >> 4;

  __shared__ float kw_sw[PVJ][16];     // 4 KB; s4-block ^= (j>>3)&3
  __shared__ float mgs[128][17];       // 8.7 KB merge scratch

  const int irow = I * 16 + lr;
  float qwr[16];
  {
    const float* qp = qw_g + (((size_t)(b * T_ + i0 + irow) * H_ + h) * S_);
#pragma unroll
    for (int s4 = 0; s4 < 4; ++s4) {
      float4 v = *(const float4*)(qp + s4 * 4);
      qwr[s4 * 4 + 0] = v.x; qwr[s4 * 4 + 1] = v.y;
      qwr[s4 * 4 + 2] = v.z; qwr[s4 * 4 + 3] = v.w;
    }
  }
  float mr = m_g[(size_t)(b * H_ + h) * T_ + i0 + irow];
  float isr = is_g[(size_t)(b * H_ + h) * T_ + i0 + irow];
#pragma unroll
  for (int s = 0; s < 16; ++s) asm volatile("" : "+v"(qwr[s]));
  asm volatile("" : "+v"(mr));
  asm volatile("" : "+v"(isr));

  const unsigned short* vhp = vth + ((size_t)(b * H_ + h) * 64) * 1024;
  const unsigned short* vlp = vtl + ((size_t)(b * H_ + h) * 64) * 1024;

  f32x4m acc[4];
#pragma unroll
  for (int f = 0; f < 4; ++f) { f32x4m z = {0.f, 0.f, 0.f, 0.f}; acc[f] = z; }

  for (int jc = 0; jc < T_ / PVJ; ++jc) {
    const int j0 = jc * PVJ;
    __syncthreads();
    {
      int j = t >> 2, s4g = t & 3;
      float4 v = *(const float4*)(kw_g + (((size_t)(b * T_ + j0 + j) * H_ + h) * S_ + s4g * 4));
      int blk = s4g ^ ((j >> 3) & 3);
      *(float4*)&kw_sw[j][blk * 4] = v;
    }
    __syncthreads();
    union UA { unsigned short s[8]; bf16x8 v; } AH, AL;
#pragma unroll
    for (int u = 0; u < 8; ++u) {
      int jr = S * 32 + kg * 8 + u;
      int g = (jr >> 3) & 3;
      float d = 0.f;
#pragma unroll
      for (int s4 = 0; s4 < 4; ++s4) {
        float4 kv = *(const float4*)&kw_sw[jr][(s4 ^ g) * 4];
        d += qwr[s4 * 4 + 0] * kv.x + qwr[s4 * 4 + 1] * kv.y +
             qwr[s4 * 4 + 2] * kv.z + qwr[s4 * 4 + 3] * kv.w;
      }
      float pv = __expf(d - mr) * isr;
      unsigned short hh = f2bf(pv);
      AH.s[u] = hh;
      AL.s[u] = f2bf(pv - bf2f(hh));
    }
#pragma unroll
    for (int f = 0; f < 4; ++f) {
      size_t voff = (size_t)(f * 16 + lr) * 1024 + j0 + S * 32 + kg * 8;
      bf16x8 BHv = *(const bf16x8*)(vhp + voff);
      bf16x8 BLv = *(const bf16x8*)(vlp + voff);
      acc[f] = __builtin_amdgcn_mfma_f32_16x16x32_bf16(AL.v, BHv, acc[f], 0, 0, 0);
      acc[f] = __builtin_amdgcn_mfma_f32_16x16x32_bf16(AH.v, BLv, acc[f], 0, 0, 0);
      acc[f] = __builtin_amdgcn_mfma_f32_16x16x32_bf16(AH.v, BHv, acc[f], 0, 0, 0);
    }
  }
  __syncthreads();
  if (S == 1) {
    float* dst = &mgs[I * 64 + lane][0];
#pragma unroll
    for (int f = 0; f < 4; ++f)
#pragma unroll
      for (int r = 0; r < 4; ++r) dst[f * 4 + r] = acc[f][r];
  }
  __syncthreads();
  if (S == 0) {
    const float* src = &mgs[I * 64 + lane][0];
#pragma unroll
    for (int f = 0; f < 4; ++f) {
#pragma unroll
      for (int r = 0; r < 4; ++r) {
        float o = acc[f][r] + src[f * 4 + r];
        unsigned short hh = f2bf(o);
        unsigned short ll = f2bf(o - bf2f(hh));
        size_t idx = (size_t)(b * T_ + i0 + I * 16 + kg * 4 + r) * D_ + h * HD_ + f * 16 + lr;
        oph[idx] = hh;
        opl[idx] = ll;
      }
    }
  }
}

extern "C" void kernel_launch(void* const* d_in, const int* in_sizes, int n_in,
                              void* d_out, int out_size, void* d_ws, size_t ws_size,
                              hipStream_t stream) {
  const float* x = (const float*)d_in[0];
  const float* qkv_w = (const float*)d_in[1];
  const float* out_w = (const float*)d_in[2];
  const float* base_c = (const float*)d_in[3];
  const float* deltas = (const float*)d_in[4];
  const float* log_sc = (const float*)d_in[5];
  const float* log_am = (const float*)d_in[6];
  const float* move_p = (const float*)d_in[7];
  const float* temp = (const float*)d_in[8];

  float* out = (float*)d_out;                    // B*T*D
  float* attn = out + (size_t)B_ * T_ * D_;      // B*T*T*H

  float* ws = (float*)d_ws;
  float* qkv = ws;                                          // 6,291,456 f
  float* qw = qkv + 6291456;                                // 524,288
  float* kw = qw + 524288;                                  // 524,288
  float* centers = kw + 524288;                             // 8,192
  float* inv_var = centers + 8192;                          // 128
  float* eff_amps = inv_var + 128;                          // 128
  float* inv_temp = eff_amps + 128;                         // 4
  float* m_g = inv_temp + 4;                                // 32,768
  float* is_g = m_g + 32768;                                // 32,768
  unsigned short* xh = (unsigned short*)(is_g + 32768);     // 2,097,152 us
  unsigned short* xl = xh + 2097152;                        // 2,097,152
  unsigned short* wh = xl + 2097152;                        // 786,432
  unsigned short* wl = wh + 786432;                         // 786,432
  unsigned short* owh = wl + 786432;                        // 262,144
  unsigned short* owl = owh + 262144;                       // 262,144
  unsigned short* oph = owl + 262144;                       // 2,097,152
  unsigned short* opl = oph + 2097152;                      // 2,097,152
  unsigned short* vth = opl + 2097152;                      // 2,097,152
  unsigned short* vtl = vth + 2097152;                      // 2,097,152

  k_prep<<<3104, 256, 0, stream>>>(x, qkv_w, out_w, base_c, deltas, log_sc, log_am,
                                   move_p, temp, xh, xl, wh, wl, owh, owl,
                                   centers, inv_var, eff_amps, inv_temp);

  dim3 g1(1536 / 64, 4096 / 128);   // 24 x 32 = 768 WGs
  gemm_mfma<64><<<g1, 256, 0, stream>>>(xh, xl, wh, wl, qkv, B_ * T_, 3 * D_, D_);

  k_gauss<<<(B_ * T_ * H_ * 8) / 256, 256, 0, stream>>>(qkv, centers, inv_var,
                                                        eff_amps, inv_temp, qw, kw);
  k_sv<<<4608, 256, 0, stream>>>(qw, kw, qkv, m_g, is_g, vth, vtl);
  k_attnw<<<B_ * (T_ / ITW) * 16, 256, 0, stream>>>(qw, kw, m_g, is_g, attn);
  k_pv<<<B_ * H_ * (T_ / PVI), 256, 0, stream>>>(qw, kw, m_g, is_g, vth, vtl, oph, opl);

  dim3 g2(512 / 32, 4096 / 64);     // 16 x 64 = 1024 WGs
  gemm_mfma2<32><<<g2, 128, 0, stream>>>(oph, opl, owh, owl, out, B_ * T_, D_, D_);
}

// Round 18
// 252.655 us; speedup vs baseline: 1.2756x; 1.0030x over previous
//
#include <hip/hip_runtime.h>
#include <hip/hip_bf16.h>

#define B_ 4
#define T_ 1024
#define D_ 512
#define H_ 8
#define S_ 16
#define HD_ 64
#define ITS 8    // i-rows per WG (stats)
#define ITW 8    // i-rows per WG (attnw)
#define PVI 32   // i-rows per WG (pv)
#define PVJ 64   // j-chunk (pv)

typedef short bf16x8 __attribute__((ext_vector_type(8)));
typedef float f32x4m __attribute__((ext_vector_type(4)));

__device__ __forceinline__ unsigned short f2bf(float f) {
  unsigned u = __float_as_uint(f);
  unsigned r = (u + 0x7FFFu + ((u >> 16) & 1u)) >> 16;  // RNE
  return (unsigned short)r;
}
__device__ __forceinline__ float bf2f(unsigned short h) {
  return __uint_as_float((unsigned)h << 16);
}

__device__ __forceinline__ void split4(const float4 v, ushort4& h, ushort4& l) {
  h.x = f2bf(v.x); l.x = f2bf(v.x - bf2f(h.x));
  h.y = f2bf(v.y); l.y = f2bf(v.y - bf2f(h.y));
  h.z = f2bf(v.z); l.z = f2bf(v.z - bf2f(h.z));
  h.w = f2bf(v.w); l.w = f2bf(v.w - bf2f(h.w));
}

// ---------------- prep: params + 3 fp32->bf16hi/lo splits, fused ----------------
__global__ __launch_bounds__(256) void k_prep(const float* __restrict__ x,
                                              const float* __restrict__ qkv_w,
                                              const float* __restrict__ out_w,
                                              const float* __restrict__ base_centers,
                                              const float* __restrict__ center_deltas,
                                              const float* __restrict__ log_scales,
                                              const float* __restrict__ log_amps,
                                              const float* __restrict__ movement_param,
                                              const float* __restrict__ temperature,
                                              unsigned short* __restrict__ xh,
                                              unsigned short* __restrict__ xl,
                                              unsigned short* __restrict__ wh,
                                              unsigned short* __restrict__ wl,
                                              unsigned short* __restrict__ owh,
                                              unsigned short* __restrict__ owl,
                                              float* __restrict__ centers,
                                              float* __restrict__ inv_var,
                                              float* __restrict__ eff_amps,
                                              float* __restrict__ inv_temp) {
  const int bid = blockIdx.x;
  const int t = threadIdx.x;
  if (bid < 2048) {
    int i = bid * 256 + t;
    float4 v = ((const float4*)x)[i];
    ushort4 h, l; split4(v, h, l);
    ((ushort4*)xh)[i] = h; ((ushort4*)xl)[i] = l;
  } else if (bid < 2816) {
    int i = (bid - 2048) * 256 + t;
    float4 v = ((const float4*)qkv_w)[i];
    ushort4 h, l; split4(v, h, l);
    ((ushort4*)wh)[i] = h; ((ushort4*)wl)[i] = l;
  } else if (bid < 3072) {
    int i = (bid - 2816) * 256 + t;
    float4 v = ((const float4*)out_w)[i];
    ushort4 h, l; split4(v, h, l);
    ((ushort4*)owh)[i] = h; ((ushort4*)owl)[i] = l;
  } else {
    int tid = (bid - 3072) * 256 + t;  // 0..8191
    float move = (1.f / (1.f + __expf(-movement_param[0]))) * 0.2f;
    centers[tid] = base_centers[tid] + center_deltas[tid] * move;
    if (tid < H_ * S_) {
      float sc = __expf(log_scales[tid]);
      sc = fminf(fmaxf(sc, 1e-4f), 5.f);
      float am = __expf(log_amps[tid]);
      am = fminf(fmaxf(am, 1e-6f), 10.f);
      inv_var[tid] = 1.f / (sc * sc + 1e-8f);
      eff_amps[tid] = (am > 0.001f) ? am : 0.f;
    }
    if (tid == 0) {
      float tt = fminf(fmaxf(temperature[0], 0.01f), 10.f);
      inv_temp[0] = 1.f / tt;
    }
  }
}

// ---------------- split-bf16 MFMA GEMM, B staged in swizzled LDS (4-wave) ----------------
template <int BN>
__global__ __launch_bounds__(256) void gemm_mfma(const unsigned short* __restrict__ Ah,
                                                 const unsigned short* __restrict__ Al,
                                                 const unsigned short* __restrict__ Bh,
                                                 const unsigned short* __restrict__ Bl,
                                                 float* __restrict__ C,
                                                 int M, int N, int K) {
  static_assert(BN == 64, "staging sized for BN=64");
  constexpr int NF = BN / 16;
  const int t = threadIdx.x;
  const int lane = t & 63;
  const int wv = t >> 6;
  const int m0 = blockIdx.y * 128 + wv * 32;
  const int n0 = blockIdx.x * BN;
  const int lr = lane & 15;
  const int kg = lane >> 4;

  __shared__ unsigned short Bsh[64][64];  // 8 KB
  __shared__ unsigned short Bsl[64][64];  // 8 KB

  const unsigned short* a0h = Ah + (size_t)(m0 + lr) * K + kg * 8;
  const unsigned short* a1h = a0h + (size_t)16 * K;
  const unsigned short* a0l = Al + (size_t)(m0 + lr) * K + kg * 8;
  const unsigned short* a1l = a0l + (size_t)16 * K;

  f32x4m acc[2][NF];
#pragma unroll
  for (int i = 0; i < 2; ++i)
#pragma unroll
    for (int f = 0; f < NF; ++f) {
      f32x4m z = {0.f, 0.f, 0.f, 0.f};
      acc[i][f] = z;
    }

  for (int k0 = 0; k0 < K; k0 += 64) {
    if (k0) __syncthreads();  // previous chunk's readers done
#pragma unroll
    for (int r2 = 0; r2 < 2; ++r2) {
      int idx = t + r2 * 256;
      int row = idx >> 3, c8 = idx & 7;
      int c8s = c8 ^ (row & 7);
      float4 vh = *(const float4*)(Bh + (size_t)(n0 + row) * K + k0 + c8 * 8);
      float4 vl = *(const float4*)(Bl + (size_t)(n0 + row) * K + k0 + c8 * 8);
      *(float4*)&Bsh[row][c8s * 8] = vh;
      *(float4*)&Bsl[row][c8s * 8] = vl;
    }
    __syncthreads();
#pragma unroll
    for (int S2 = 0; S2 < 2; ++S2) {
      const int kk = k0 + S2 * 32;
      bf16x8 ah0 = *(const bf16x8*)(a0h + kk);
      bf16x8 ah1 = *(const bf16x8*)(a1h + kk);
      bf16x8 al0 = *(const bf16x8*)(a0l + kk);
      bf16x8 al1 = *(const bf16x8*)(a1l + kk);
#pragma unroll
      for (int f = 0; f < NF; ++f) {
        int row = f * 16 + lr;
        int sl = (S2 * 4 + kg) ^ (row & 7);
        bf16x8 vbh = *(const bf16x8*)&Bsh[row][sl * 8];
        bf16x8 vbl = *(const bf16x8*)&Bsl[row][sl * 8];
        acc[0][f] = __builtin_amdgcn_mfma_f32_16x16x32_bf16(al0, vbh, acc[0][f], 0, 0, 0);
        acc[0][f] = __builtin_amdgcn_mfma_f32_16x16x32_bf16(ah0, vbl, acc[0][f], 0, 0, 0);
        acc[0][f] = __builtin_amdgcn_mfma_f32_16x16x32_bf16(ah0, vbh, acc[0][f], 0, 0, 0);
        acc[1][f] = __builtin_amdgcn_mfma_f32_16x16x32_bf16(al1, vbh, acc[1][f], 0, 0, 0);
        acc[1][f] = __builtin_amdgcn_mfma_f32_16x16x32_bf16(ah1, vbl, acc[1][f], 0, 0, 0);
        acc[1][f] = __builtin_amdgcn_mfma_f32_16x16x32_bf16(ah1, vbh, acc[1][f], 0, 0, 0);
      }
    }
  }
#pragma unroll
  for (int i = 0; i < 2; ++i)
#pragma unroll
    for (int f = 0; f < NF; ++f)
#pragma unroll
      for (int r = 0; r < 4; ++r)
        C[(size_t)(m0 + i * 16 + kg * 4 + r) * N + n0 + f * 16 + lr] = acc[i][f][r];
}

// ---------------- 2-wave out-proj GEMM, B staged in swizzled LDS ----------------
template <int BN>
__global__ __launch_bounds__(128) void gemm_mfma2(const unsigned short* __restrict__ Ah,
                                                  const unsigned short* __restrict__ Al,
                                                  const unsigned short* __restrict__ Bh,
                                                  const unsigned short* __restrict__ Bl,
                                                  float* __restrict__ C,
                                                  int M, int N, int K) {
  static_assert(BN == 32, "staging sized for BN=32");
  constexpr int NF = BN / 16;
  const int t = threadIdx.x;
  const int lane = t & 63;
  const int wv = t >> 6;  // 0..1
  const int m0 = blockIdx.y * 64 + wv * 32;
  const int n0 = blockIdx.x * BN;
  const int lr = lane & 15;
  const int kg = lane >> 4;

  __shared__ unsigned short Bsh[32][64];  // 4 KB
  __shared__ unsigned short Bsl[32][64];  // 4 KB

  const unsigned short* a0h = Ah + (size_t)(m0 + lr) * K + kg * 8;
  const unsigned short* a1h = a0h + (size_t)16 * K;
  const unsigned short* a0l = Al + (size_t)(m0 + lr) * K + kg * 8;
  const unsigned short* a1l = a0l + (size_t)16 * K;

  f32x4m acc[2][NF];
#pragma unroll
  for (int i = 0; i < 2; ++i)
#pragma unroll
    for (int f = 0; f < NF; ++f) {
      f32x4m z = {0.f, 0.f, 0.f, 0.f};
      acc[i][f] = z;
    }

  for (int k0 = 0; k0 < K; k0 += 64) {
    if (k0) __syncthreads();
#pragma unroll
    for (int r2 = 0; r2 < 2; ++r2) {
      int idx = t + r2 * 128;
      int row = idx >> 3, c8 = idx & 7;
      int c8s = c8 ^ (row & 7);
      float4 vh = *(const float4*)(Bh + (size_t)(n0 + row) * K + k0 + c8 * 8);
      float4 vl = *(const float4*)(Bl + (size_t)(n0 + row) * K + k0 + c8 * 8);
      *(float4*)&Bsh[row][c8s * 8] = vh;
      *(float4*)&Bsl[row][c8s * 8] = vl;
    }
    __syncthreads();
#pragma unroll
    for (int S2 = 0; S2 < 2; ++S2) {
      const int kk = k0 + S2 * 32;
      bf16x8 ah0 = *(const bf16x8*)(a0h + kk);
      bf16x8 ah1 = *(const bf16x8*)(a1h + kk);
      bf16x8 al0 = *(const bf16x8*)(a0l + kk);
      bf16x8 al1 = *(const bf16x8*)(a1l + kk);
#pragma unroll
      for (int f = 0; f < NF; ++f) {
        int row = f * 16 + lr;
        int sl = (S2 * 4 + kg) ^ (row & 7);
        bf16x8 vbh = *(const bf16x8*)&Bsh[row][sl * 8];
        bf16x8 vbl = *(const bf16x8*)&Bsl[row][sl * 8];
        acc[0][f] = __builtin_amdgcn_mfma_f32_16x16x32_bf16(al0, vbh, acc[0][f], 0, 0, 0);
        acc[0][f] = __builtin_amdgcn_mfma_f32_16x16x32_bf16(ah0, vbl, acc[0][f], 0, 0, 0);
        acc[0][f] = __builtin_amdgcn_mfma_f32_16x16x32_bf16(ah0, vbh, acc[0][f], 0, 0, 0);
        acc[1][f] = __builtin_amdgcn_mfma_f32_16x16x32_bf16(al1, vbh, acc[1][f], 0, 0, 0);
        acc[1][f] = __builtin_amdgcn_mfma_f32_16x16x32_bf16(ah1, vbl, acc[1][f], 0, 0, 0);
        acc[1][f] = __builtin_amdgcn_mfma_f32_16x16x32_bf16(ah1, vbh, acc[1][f], 0, 0, 0);
      }
    }
  }
#pragma unroll
  for (int i = 0; i < 2; ++i)
#pragma unroll
    for (int f = 0; f < NF; ++f)
#pragma unroll
      for (int r = 0; r < 4; ++r)
        C[(size_t)(m0 + i * 16 + kg * 4 + r) * N + n0 + f * 16 + lr] = acc[i][f][r];
}

// ---------------- gaussian kernel weights v2: 2 s-values share q/k rows ----------------
__global__ __launch_bounds__(256) void k_gauss(const float* __restrict__ qkv,
                                               const float* __restrict__ centers,
                                               const float* __restrict__ inv_var,
                                               const float* __restrict__ eff_amps,
                                               const float* __restrict__ inv_temp,
                                               float* __restrict__ qw,
                                               float* __restrict__ kw) {
  int gid = blockIdx.x * blockDim.x + threadIdx.x;  // 0..B*T*H*8-1
  int s = gid & 7;
  int h = (gid >> 3) & 7;
  int bt = gid >> 6;
  const float* qrow = qkv + (size_t)bt * 1536 + h * 64;
  const float* krow = qrow + 512;
  const float* c0 = centers + (h * 16 + s) * 64;
  const float* c1 = c0 + 8 * 64;  // s+8
  float qd0 = 0.f, kd0 = 0.f, qd1 = 0.f, kd1 = 0.f;
#pragma unroll
  for (int d = 0; d < 64; d += 4) {
    float4 qv = *(const float4*)(qrow + d);
    float4 kv = *(const float4*)(krow + d);
    float4 ca = *(const float4*)(c0 + d);
    float4 cb = *(const float4*)(c1 + d);
    float t;
    t = qv.x - ca.x; qd0 += t * t;  t = qv.y - ca.y; qd0 += t * t;
    t = qv.z - ca.z; qd0 += t * t;  t = qv.w - ca.w; qd0 += t * t;
    t = kv.x - ca.x; kd0 += t * t;  t = kv.y - ca.y; kd0 += t * t;
    t = kv.z - ca.z; kd0 += t * t;  t = kv.w - ca.w; kd0 += t * t;
    t = qv.x - cb.x; qd1 += t * t;  t = qv.y - cb.y; qd1 += t * t;
    t = qv.z - cb.z; qd1 += t * t;  t = qv.w - cb.w; qd1 += t * t;
    t = kv.x - cb.x; kd1 += t * t;  t = kv.y - cb.y; kd1 += t * t;
    t = kv.z - cb.z; kd1 += t * t;  t = kv.w - cb.w; kd1 += t * t;
  }
  qd0 = fminf(qd0, 100.f); kd0 = fminf(kd0, 100.f);
  qd1 = fminf(qd1, 100.f); kd1 = fminf(kd1, 100.f);
  float it = inv_temp[0];
  float iv0 = inv_var[h * 16 + s],     ea0 = eff_amps[h * 16 + s];
  float iv1 = inv_var[h * 16 + s + 8], ea1 = eff_amps[h * 16 + s + 8];
  size_t base = (size_t)(bt * H_ + h) * S_ + s;
  qw[base]     = __expf(-0.5f * qd0 * iv0) * ea0 * it;
  kw[base]     = __expf(-0.5f * kd0 * iv0) * ea0;
  qw[base + 8] = __expf(-0.5f * qd1 * iv1) * ea1 * it;
  kw[base + 8] = __expf(-0.5f * kd1 * iv1) * ea1;
}

__device__ __forceinline__ float dot16(const float4 q[4], const float4 k[4]) {
  return q[0].x * k[0].x + q[0].y * k[0].y + q[0].z * k[0].z + q[0].w * k[0].w +
         q[1].x * k[1].x + q[1].y * k[1].y + q[1].z * k[1].z + q[1].w * k[1].w +
         q[2].x * k[2].x + q[2].y * k[2].y + q[2].z * k[2].z + q[2].w * k[2].w +
         q[3].x * k[3].x + q[3].y * k[3].y + q[3].z * k[3].z + q[3].w * k[3].w;
}

// ---------------- fused stats + vtr (8:1 WG interleave) ----------------
__global__ __launch_bounds__(256, 4) void k_sv(const float* __restrict__ qw_g,
                                               const float* __restrict__ kw_g,
                                               const float* __restrict__ qkv,
                                               float* __restrict__ m_g,
                                               float* __restrict__ is_g,
                                               unsigned short* __restrict__ vth,
                                               unsigned short* __restrict__ vtl) {
  union Sm {
    float red[4][4][2][2];
    float Vl[64][68];
  };
  __shared__ Sm sm;
  const int bid = blockIdx.x;
  const int g = bid / 9;
  const int r = bid - g * 9;
  const int t = threadIdx.x;

  if (r < 8) {
    const int x = g * 8 + r;  // 0..4095
    const int ic = x & 127;
    const int h = (x >> 7) & 7;
    const int b = x >> 10;
    const int i0 = ic * ITS;
    const int rp = t & 3;
    const int jl = t >> 2;

    float qwr[2][16], mr[2], sr[2];
#pragma unroll
    for (int e = 0; e < 2; ++e) {
      const float* qp = qw_g + (((size_t)(b * T_ + i0 + rp * 2 + e) * H_ + h) * S_);
#pragma unroll
      for (int s4 = 0; s4 < 4; ++s4) {
        float4 v = *(const float4*)(qp + s4 * 4);
        qwr[e][s4 * 4 + 0] = v.x; qwr[e][s4 * 4 + 1] = v.y;
        qwr[e][s4 * 4 + 2] = v.z; qwr[e][s4 * 4 + 3] = v.w;
      }
      mr[e] = -1e30f; sr[e] = 0.f;
    }
    for (int c = 0; c < T_ / 64; ++c) {
      int j = c * 64 + jl;
      const float* kp = kw_g + ((size_t)(b * T_ + j) * H_ + h) * S_;
      float4 k0 = *(const float4*)(kp);
      float4 k1 = *(const float4*)(kp + 4);
      float4 k2 = *(const float4*)(kp + 8);
      float4 k3 = *(const float4*)(kp + 12);
#pragma unroll
      for (int e = 0; e < 2; ++e) {
        float d = qwr[e][0] * k0.x + qwr[e][1] * k0.y + qwr[e][2] * k0.z + qwr[e][3] * k0.w +
                  qwr[e][4] * k1.x + qwr[e][5] * k1.y + qwr[e][6] * k1.z + qwr[e][7] * k1.w +
                  qwr[e][8] * k2.x + qwr[e][9] * k2.y + qwr[e][10] * k2.z + qwr[e][11] * k2.w +
                  qwr[e][12] * k3.x + qwr[e][13] * k3.y + qwr[e][14] * k3.z + qwr[e][15] * k3.w;
        float mn = fmaxf(mr[e], d);
        sr[e] = sr[e] * __expf(mr[e] - mn) + __expf(d - mn);
        mr[e] = mn;
      }
    }
#pragma unroll
    for (int o = 4; o < 64; o <<= 1) {
#pragma unroll
      for (int e = 0; e < 2; ++e) {
        float m2 = __shfl_xor(mr[e], o);
        float s2 = __shfl_xor(sr[e], o);
        float mn = fmaxf(mr[e], m2);
        sr[e] = sr[e] * __expf(mr[e] - mn) + s2 * __expf(m2 - mn);
        mr[e] = mn;
      }
    }
    int wv = t >> 6;
    if ((t & 63) < 4) {
      sm.red[wv][rp][0][0] = mr[0]; sm.red[wv][rp][0][1] = sr[0];
      sm.red[wv][rp][1][0] = mr[1]; sm.red[wv][rp][1][1] = sr[1];
    }
    __syncthreads();
    if (t < ITS) {
      int rpp = t >> 1, e = t & 1;
      float mf = sm.red[0][rpp][e][0], sf = sm.red[0][rpp][e][1];
#pragma unroll
      for (int w = 1; w < 4; ++w) {
        float m2 = sm.red[w][rpp][e][0], s2 = sm.red[w][rpp][e][1];
        float mn = fmaxf(mf, m2);
        sf = sf * __expf(mf - mn) + s2 * __expf(m2 - mn);
        mf = mn;
      }
      size_t o = (size_t)(b * H_ + h) * T_ + i0 + t;
      m_g[o] = mf;
      is_g[o] = 1.f / sf;
    }
  } else {
    const int id = g;  // 0..511
    const int jc = id & 15;
    const int h = (id >> 4) & 7;
    const int b = id >> 7;
    const int j0 = jc * 64;
    {
      int jj = t >> 2, dqg = t & 3;
      const float* vp = qkv + (size_t)(b * T_ + j0 + jj) * 1536 + 1024 + h * 64 + dqg * 16;
#pragma unroll
      for (int q = 0; q < 4; ++q) {
        float4 v = *(const float4*)(vp + q * 4);
        *(float4*)&sm.Vl[jj][dqg * 16 + q * 4] = v;
      }
    }
    __syncthreads();
    {
      int d = t >> 2, jg = t & 3;
      ushort4 hs[4], ls[4];
#pragma unroll
      for (int q = 0; q < 4; ++q) {
        float f0 = sm.Vl[jg * 16 + q * 4 + 0][d];
        float f1 = sm.Vl[jg * 16 + q * 4 + 1][d];
        float f2 = sm.Vl[jg * 16 + q * 4 + 2][d];
        float f3 = sm.Vl[jg * 16 + q * 4 + 3][d];
        hs[q].x = f2bf(f0); ls[q].x = f2bf(f0 - bf2f(hs[q].x));
        hs[q].y = f2bf(f1); ls[q].y = f2bf(f1 - bf2f(hs[q].y));
        hs[q].z = f2bf(f2); ls[q].z = f2bf(f2 - bf2f(hs[q].z));
        hs[q].w = f2bf(f3); ls[q].w = f2bf(f3 - bf2f(hs[q].w));
      }
      size_t off = ((size_t)(b * H_ + h) * 64 + d) * 1024 + j0 + jg * 16;
#pragma unroll
      for (int q = 0; q < 4; ++q) {
        *(ushort4*)(vth + off + q * 4) = hs[q];
        *(ushort4*)(vtl + off + q * 4) = ls[q];
      }
    }
  }
}

// ---------------- attn writer (v1 body, jt-split 16: one subtile per WG) ----------------
__global__ __launch_bounds__(256, 4) void k_attnw(const float* __restrict__ qw_g,
                                                  const float* __restrict__ kw_g,
                                                  const float* __restrict__ m_g,
                                                  const float* __restrict__ is_g,
                                                  float* __restrict__ attn) {
  const int x = blockIdx.x;
  const int jt = x & 15;
  const int it = (x >> 4) & 127;
  const int b = x >> 11;
  const int i0 = it * ITW;
  const int j0 = jt * 64;
  const int tid = threadIdx.x;

  __shared__ float qw_l[ITW][H_ * S_];     // 4 KB
  __shared__ float msl[ITW][H_];
  __shared__ float isl[ITW][H_];
  __shared__ float tile[ITW][H_][68];      // 17.4 KB

  {
    int f = tid * 4;
    int r = f >> 7, c = f & 127;
    *(float4*)&qw_l[r][c] = *(const float4*)(qw_g + ((size_t)(b * T_ + i0 + r) * 128 + c));
  }
  if (tid < 64) {
    int r = tid >> 3, hh = tid & 7;
    size_t o = (size_t)(b * H_ + hh) * T_ + i0 + r;
    msl[r][hh] = m_g[o];
    isl[r][hh] = is_g[o];
  }
  __syncthreads();

  const int h = tid >> 5;
  const int jq = tid & 31;
  const float* kw_b = kw_g + (size_t)b * T_ * (H_ * S_);
  float* attn_b = attn + (size_t)(b * T_ + i0) * (T_ * H_);

  const float* kp = kw_b + ((size_t)(j0 + jq * 2) * H_ + h) * S_;
  float4 ka[4], kb[4];
  ka[0] = *(const float4*)(kp);       ka[1] = *(const float4*)(kp + 4);
  ka[2] = *(const float4*)(kp + 8);   ka[3] = *(const float4*)(kp + 12);
  kb[0] = *(const float4*)(kp + 128); kb[1] = *(const float4*)(kp + 132);
  kb[2] = *(const float4*)(kp + 136); kb[3] = *(const float4*)(kp + 140);
#pragma unroll
  for (int r = 0; r < ITW; ++r) {
    float4 q4[4];
    q4[0] = *(const float4*)&qw_l[r][h * 16 + 0];
    q4[1] = *(const float4*)&qw_l[r][h * 16 + 4];
    q4[2] = *(const float4*)&qw_l[r][h * 16 + 8];
    q4[3] = *(const float4*)&qw_l[r][h * 16 + 12];
    float la = dot16(q4, ka);
    float lb = dot16(q4, kb);
    float mm = msl[r][h], ii = isl[r][h];
    *(float2*)&tile[r][h][jq * 2] =
        make_float2(__expf(la - mm) * ii, __expf(lb - mm) * ii);
  }
  __syncthreads();
#pragma unroll
  for (int l = 0; l < 4; ++l) {
    int f = (l * 256 + tid) * 4;
    int r = f >> 9;
    int rem = f & 511;
    int jl = rem >> 3;
    int h0 = rem & 7;  // 0 or 4
    float4 v;
    v.x = tile[r][h0 + 0][jl];
    v.y = tile[r][h0 + 1][jl];
    v.z = tile[r][h0 + 2][jl];
    v.w = tile[r][h0 + 3][jl];
    *(float4*)(attn_b + (size_t)r * (T_ * H_) + (size_t)(j0 + jl) * H_ + h0) = v;
  }
}

// ---------------- PV via MFMA (v6): Vt chunk staged in swizzled LDS ----------------
// Round-17 phase-2 issued 8 scattered 16B global loads/lane/chunk (2KB row
// stride; I=0/I=1 waves read identical data -> 2x redundant). v6 stages the
// 16KB Vt hi/lo chunk cooperatively (coalesced 128B rows) with the same XOR
// 16B-slot swizzle proven conflict-free in gemm_mfma. Merge scratch aliases
// the V buffers (used only after the post-loop barrier). LDS 20.7 KB.
__global__ __launch_bounds__(256, 4) void k_pv(const float* __restrict__ qw_g,
                                               const float* __restrict__ kw_g,
                                               const float* __restrict__ m_g,
                                               const float* __restrict__ is_g,
                                               const unsigned short* __restrict__ vth,
                                               const unsigned short* __restrict__ vtl,
                                               unsigned short* __restrict__ oph,
                                               unsigned short* __restrict__ opl) {
  const int bid = blockIdx.x;
  const int xcd = bid & 7;
  const int qq = bid >> 3;             // 0..127
  const int p = xcd * 4 + (qq & 3);    // panel 0..31
  const int ib = qq >> 2;              // 0..31
  const int b = p >> 3;
  const int h = p & 7;
  const int i0 = ib * PVI;
  const int t = threadIdx.x;
  const int lane = t & 63;
  const int w = t >> 6;
  const int I = w >> 1;                // i-frag
  const int S = w & 1;                 // k-step (32-j half of chunk)
  const int lr = lane & 15;
  const int kg = lane >> 4;

  union Sm {
    struct {
      unsigned short Vsh[64][64];   // 8 KB
      unsigned short Vsl[64][64];   // 8 KB
    } v;
    float mgs[128][17];             // 8.7 KB merge scratch (post-loop only)
  };
  __shared__ Sm sm;
  __shared__ float kw_sw[PVJ][16];  // 4 KB; s4-block ^= (j>>3)&3

  const int irow = I * 16 + lr;
  float qwr[16];
  {
    const float* qp = qw_g + (((size_t)(b * T_ + i0 + irow) * H_ + h) * S_);
#pragma unroll
    for (int s4 = 0; s4 < 4; ++s4) {
      float4 v = *(const float4*)(qp + s4 * 4);
      qwr[s4 * 4 + 0] = v.x; qwr[s4 * 4 + 1] = v.y;
      qwr[s4 * 4 + 2] = v.z; qwr[s4 * 4 + 3] = v.w;
    }
  }
  float mr = m_g[(size_t)(b * H_ + h) * T_ + i0 + irow];
  float isr = is_g[(size_t)(b * H_ + h) * T_ + i0 + irow];
#pragma unroll
  for (int s = 0; s < 16; ++s) asm volatile("" : "+v"(qwr[s]));
  asm volatile("" : "+v"(mr));
  asm volatile("" : "+v"(isr));

  const unsigned short* vhp = vth + ((size_t)(b * H_ + h) * 64) * 1024;
  const unsigned short* vlp = vtl + ((size_t)(b * H_ + h) * 64) * 1024;

  f32x4m acc[4];
#pragma unroll
  for (int f = 0; f < 4; ++f) { f32x4m z = {0.f, 0.f, 0.f, 0.f}; acc[f] = z; }

  for (int jc = 0; jc < T_ / PVJ; ++jc) {
    const int j0 = jc * PVJ;
    __syncthreads();  // prior chunk's readers done
    // stage kw (swizzled)
    {
      int j = t >> 2, s4g = t & 3;
      float4 v = *(const float4*)(kw_g + (((size_t)(b * T_ + j0 + j) * H_ + h) * S_ + s4g * 4));
      int blk = s4g ^ ((j >> 3) & 3);
      *(float4*)&kw_sw[j][blk * 4] = v;
    }
    // stage Vt hi/lo chunk: 64 d-rows x 64 j, coalesced 128B rows, 16B-slot swizzle
#pragma unroll
    for (int u2 = 0; u2 < 2; ++u2) {
      int u = t + u2 * 256;           // 0..511
      int row = u >> 3, c8 = u & 7;
      int c8s = c8 ^ (row & 7);
      float4 vh = *(const float4*)(vhp + (size_t)row * 1024 + j0 + c8 * 8);
      float4 vl = *(const float4*)(vlp + (size_t)row * 1024 + j0 + c8 * 8);
      *(float4*)&sm.v.Vsh[row][c8s * 8] = vh;
      *(float4*)&sm.v.Vsl[row][c8s * 8] = vl;
    }
    __syncthreads();
    // ---- phase 1: logits -> P A-frag (hi/lo bf16) in registers ----
    union UA { unsigned short s[8]; bf16x8 v; } AH, AL;
#pragma unroll
    for (int u = 0; u < 8; ++u) {
      int jr = S * 32 + kg * 8 + u;
      int g = (jr >> 3) & 3;
      float d = 0.f;
#pragma unroll
      for (int s4 = 0; s4 < 4; ++s4) {
        float4 kv = *(const float4*)&kw_sw[jr][(s4 ^ g) * 4];
        d += qwr[s4 * 4 + 0] * kv.x + qwr[s4 * 4 + 1] * kv.y +
             qwr[s4 * 4 + 2] * kv.z + qwr[s4 * 4 + 3] * kv.w;
      }
      float pv = __expf(d - mr) * isr;
      unsigned short hh = f2bf(pv);
      AH.s[u] = hh;
      AL.s[u] = f2bf(pv - bf2f(hh));
    }
    // ---- phase 2: B-frags from swizzled LDS, 3 MFMA each ----
#pragma unroll
    for (int f = 0; f < 4; ++f) {
      int row = f * 16 + lr;
      int sl = (S * 4 + kg) ^ (row & 7);
      bf16x8 BHv = *(const bf16x8*)&sm.v.Vsh[row][sl * 8];
      bf16x8 BLv = *(const bf16x8*)&sm.v.Vsl[row][sl * 8];
      acc[f] = __builtin_amdgcn_mfma_f32_16x16x32_bf16(AL.v, BHv, acc[f], 0, 0, 0);
      acc[f] = __builtin_amdgcn_mfma_f32_16x16x32_bf16(AH.v, BLv, acc[f], 0, 0, 0);
      acc[f] = __builtin_amdgcn_mfma_f32_16x16x32_bf16(AH.v, BHv, acc[f], 0, 0, 0);
    }
  }
  // ---- merge S=0 + S=1 partials (scratch aliases V buffers), store bf16 hi/lo ----
  __syncthreads();
  if (S == 1) {
    float* dst = &sm.mgs[I * 64 + lane][0];
#pragma unroll
    for (int f = 0; f < 4; ++f)
#pragma unroll
      for (int r = 0; r < 4; ++r) dst[f * 4 + r] = acc[f][r];
  }
  __syncthreads();
  if (S == 0) {
    const float* src = &sm.mgs[I * 64 + lane][0];
#pragma unroll
    for (int f = 0; f < 4; ++f) {
#pragma unroll
      for (int r = 0; r < 4; ++r) {
        float o = acc[f][r] + src[f * 4 + r];
        unsigned short hh = f2bf(o);
        unsigned short ll = f2bf(o - bf2f(hh));
        size_t idx = (size_t)(b * T_ + i0 + I * 16 + kg * 4 + r) * D_ + h * HD_ + f * 16 + lr;
        oph[idx] = hh;
        opl[idx] = ll;
      }
    }
  }
}

extern "C" void kernel_launch(void* const* d_in, const int* in_sizes, int n_in,
                              void* d_out, int out_size, void* d_ws, size_t ws_size,
                              hipStream_t stream) {
  const float* x = (const float*)d_in[0];
  const float* qkv_w = (const float*)d_in[1];
  const float* out_w = (const float*)d_in[2];
  const float* base_c = (const float*)d_in[3];
  const float* deltas = (const float*)d_in[4];
  const float* log_sc = (const float*)d_in[5];
  const float* log_am = (const float*)d_in[6];
  const float* move_p = (const float*)d_in[7];
  const float* temp = (const float*)d_in[8];

  float* out = (float*)d_out;                    // B*T*D
  float* attn = out + (size_t)B_ * T_ * D_;      // B*T*T*H

  float* ws = (float*)d_ws;
  float* qkv = ws;                                          // 6,291,456 f
  float* qw = qkv + 6291456;                                // 524,288
  float* kw = qw + 524288;                                  // 524,288
  float* centers = kw + 524288;                             // 8,192
  float* inv_var = centers + 8192;                          // 128
  float* eff_amps = inv_var + 128;                          // 128
  float* inv_temp = eff_amps + 128;                         // 4
  float* m_g = inv_temp + 4;                                // 32,768
  float* is_g = m_g + 32768;                                // 32,768
  unsigned short* xh = (unsigned short*)(is_g + 32768);     // 2,097,152 us
  unsigned short* xl = xh + 2097152;                        // 2,097,152
  unsigned short* wh = xl + 2097152;                        // 786,432
  unsigned short* wl = wh + 786432;                         // 786,432
  unsigned short* owh = wl + 786432;                        // 262,144
  unsigned short* owl = owh + 262144;                       // 262,144
  unsigned short* oph = owl + 262144;                       // 2,097,152
  unsigned short* opl = oph + 2097152;                      // 2,097,152
  unsigned short* vth = opl + 2097152;                      // 2,097,152
  unsigned short* vtl = vth + 2097152;                      // 2,097,152

  k_prep<<<3104, 256, 0, stream>>>(x, qkv_w, out_w, base_c, deltas, log_sc, log_am,
                                   move_p, temp, xh, xl, wh, wl, owh, owl,
                                   centers, inv_var, eff_amps, inv_temp);

  dim3 g1(1536 / 64, 4096 / 128);   // 24 x 32 = 768 WGs
  gemm_mfma<64><<<g1, 256, 0, stream>>>(xh, xl, wh, wl, qkv, B_ * T_, 3 * D_, D_);

  k_gauss<<<(B_ * T_ * H_ * 8) / 256, 256, 0, stream>>>(qkv, centers, inv_var,
                                                        eff_amps, inv_temp, qw, kw);
  k_sv<<<4608, 256, 0, stream>>>(qw, kw, qkv, m_g, is_g, vth, vtl);
  k_attnw<<<B_ * (T_ / ITW) * 16, 256, 0, stream>>>(qw, kw, m_g, is_g, attn);
  k_pv<<<B_ * H_ * (T_ / PVI), 256, 0, stream>>>(qw, kw, m_g, is_g, vth, vtl, oph, opl);

  dim3 g2(512 / 32, 4096 / 64);     // 16 x 64 = 1024 WGs
  gemm_mfma2<32><<<g2, 128, 0, stream>>>(oph, opl, owh, owl, out, B_ * T_, D_, D_);
}

// Round 19
// 245.324 us; speedup vs baseline: 1.3138x; 1.0299x over previous
//
#include <hip/hip_runtime.h>
#include <hip/hip_bf16.h>

#define B_ 4
#define T_ 1024
#define D_ 512
#define H_ 8
#define S_ 16
#define HD_ 64
#define ITS 8    // i-rows per WG (stats)
#define ITW 8    // i-rows per WG (attnw)
#define PVI 32   // i-rows per WG (pv)
#define PVJ 64   // j-chunk (pv)

typedef short bf16x8 __attribute__((ext_vector_type(8)));
typedef float f32x4m __attribute__((ext_vector_type(4)));

__device__ __forceinline__ unsigned short f2bf(float f) {
  unsigned u = __float_as_uint(f);
  unsigned r = (u + 0x7FFFu + ((u >> 16) & 1u)) >> 16;  // RNE
  return (unsigned short)r;
}
__device__ __forceinline__ float bf2f(unsigned short h) {
  return __uint_as_float((unsigned)h << 16);
}

__device__ __forceinline__ void split4(const float4 v, ushort4& h, ushort4& l) {
  h.x = f2bf(v.x); l.x = f2bf(v.x - bf2f(h.x));
  h.y = f2bf(v.y); l.y = f2bf(v.y - bf2f(h.y));
  h.z = f2bf(v.z); l.z = f2bf(v.z - bf2f(h.z));
  h.w = f2bf(v.w); l.w = f2bf(v.w - bf2f(h.w));
}

// ---------------- prep: params + 3 fp32->bf16hi/lo splits, fused ----------------
__global__ __launch_bounds__(256) void k_prep(const float* __restrict__ x,
                                              const float* __restrict__ qkv_w,
                                              const float* __restrict__ out_w,
                                              const float* __restrict__ base_centers,
                                              const float* __restrict__ center_deltas,
                                              const float* __restrict__ log_scales,
                                              const float* __restrict__ log_amps,
                                              const float* __restrict__ movement_param,
                                              const float* __restrict__ temperature,
                                              unsigned short* __restrict__ xh,
                                              unsigned short* __restrict__ xl,
                                              unsigned short* __restrict__ wh,
                                              unsigned short* __restrict__ wl,
                                              unsigned short* __restrict__ owh,
                                              unsigned short* __restrict__ owl,
                                              float* __restrict__ centers,
                                              float* __restrict__ inv_var,
                                              float* __restrict__ eff_amps,
                                              float* __restrict__ inv_temp) {
  const int bid = blockIdx.x;
  const int t = threadIdx.x;
  if (bid < 2048) {
    int i = bid * 256 + t;
    float4 v = ((const float4*)x)[i];
    ushort4 h, l; split4(v, h, l);
    ((ushort4*)xh)[i] = h; ((ushort4*)xl)[i] = l;
  } else if (bid < 2816) {
    int i = (bid - 2048) * 256 + t;
    float4 v = ((const float4*)qkv_w)[i];
    ushort4 h, l; split4(v, h, l);
    ((ushort4*)wh)[i] = h; ((ushort4*)wl)[i] = l;
  } else if (bid < 3072) {
    int i = (bid - 2816) * 256 + t;
    float4 v = ((const float4*)out_w)[i];
    ushort4 h, l; split4(v, h, l);
    ((ushort4*)owh)[i] = h; ((ushort4*)owl)[i] = l;
  } else {
    int tid = (bid - 3072) * 256 + t;  // 0..8191
    float move = (1.f / (1.f + __expf(-movement_param[0]))) * 0.2f;
    centers[tid] = base_centers[tid] + center_deltas[tid] * move;
    if (tid < H_ * S_) {
      float sc = __expf(log_scales[tid]);
      sc = fminf(fmaxf(sc, 1e-4f), 5.f);
      float am = __expf(log_amps[tid]);
      am = fminf(fmaxf(am, 1e-6f), 10.f);
      inv_var[tid] = 1.f / (sc * sc + 1e-8f);
      eff_amps[tid] = (am > 0.001f) ? am : 0.f;
    }
    if (tid == 0) {
      float tt = fminf(fmaxf(temperature[0], 0.01f), 10.f);
      inv_temp[0] = 1.f / tt;
    }
  }
}

// ---------------- split-bf16 MFMA GEMM, A AND B staged in swizzled LDS ----------------
// Round-16 B-staging won 36us (removed 4x-redundant scattered gathers). A has
// the same pathology (16-line scatter per frag load, 24x cross-block re-read):
// stage it too. LDS 48KB -> 3 WG/CU (= grid/CU). All LDS patterns 2-way max.
template <int BN>
__global__ __launch_bounds__(256) void gemm_mfma(const unsigned short* __restrict__ Ah,
                                                 const unsigned short* __restrict__ Al,
                                                 const unsigned short* __restrict__ Bh,
                                                 const unsigned short* __restrict__ Bl,
                                                 float* __restrict__ C,
                                                 int M, int N, int K) {
  static_assert(BN == 64, "staging sized for BN=64");
  constexpr int NF = BN / 16;
  const int t = threadIdx.x;
  const int lane = t & 63;
  const int wv = t >> 6;
  const int mBase = blockIdx.y * 128;
  const int n0 = blockIdx.x * BN;
  const int lr = lane & 15;
  const int kg = lane >> 4;

  __shared__ unsigned short Ash[128][64];  // 16 KB
  __shared__ unsigned short Asl[128][64];  // 16 KB
  __shared__ unsigned short Bsh[64][64];   // 8 KB
  __shared__ unsigned short Bsl[64][64];   // 8 KB

  f32x4m acc[2][NF];
#pragma unroll
  for (int i = 0; i < 2; ++i)
#pragma unroll
    for (int f = 0; f < NF; ++f) {
      f32x4m z = {0.f, 0.f, 0.f, 0.f};
      acc[i][f] = z;
    }

  for (int k0 = 0; k0 < K; k0 += 64) {
    if (k0) __syncthreads();  // previous chunk's readers done
    // stage B: 64 rows x 64 k
#pragma unroll
    for (int r2 = 0; r2 < 2; ++r2) {
      int idx = t + r2 * 256;
      int row = idx >> 3, c8 = idx & 7;
      int c8s = c8 ^ (row & 7);
      float4 vh = *(const float4*)(Bh + (size_t)(n0 + row) * K + k0 + c8 * 8);
      float4 vl = *(const float4*)(Bl + (size_t)(n0 + row) * K + k0 + c8 * 8);
      *(float4*)&Bsh[row][c8s * 8] = vh;
      *(float4*)&Bsl[row][c8s * 8] = vl;
    }
    // stage A: 128 rows x 64 k
#pragma unroll
    for (int r4 = 0; r4 < 4; ++r4) {
      int idx = t + r4 * 256;            // 0..1023
      int row = idx >> 3, c8 = idx & 7;
      int c8s = c8 ^ (row & 7);
      float4 vh = *(const float4*)(Ah + (size_t)(mBase + row) * K + k0 + c8 * 8);
      float4 vl = *(const float4*)(Al + (size_t)(mBase + row) * K + k0 + c8 * 8);
      *(float4*)&Ash[row][c8s * 8] = vh;
      *(float4*)&Asl[row][c8s * 8] = vl;
    }
    __syncthreads();
#pragma unroll
    for (int S2 = 0; S2 < 2; ++S2) {
      int rowA0 = wv * 32 + lr;
      int rowA1 = rowA0 + 16;
      int slA = (S2 * 4 + kg) ^ (lr & 7);  // rowA&7 == lr&7 for both frags
      bf16x8 ah0 = *(const bf16x8*)&Ash[rowA0][slA * 8];
      bf16x8 ah1 = *(const bf16x8*)&Ash[rowA1][slA * 8];
      bf16x8 al0 = *(const bf16x8*)&Asl[rowA0][slA * 8];
      bf16x8 al1 = *(const bf16x8*)&Asl[rowA1][slA * 8];
#pragma unroll
      for (int f = 0; f < NF; ++f) {
        int row = f * 16 + lr;
        int sl = (S2 * 4 + kg) ^ (row & 7);
        bf16x8 vbh = *(const bf16x8*)&Bsh[row][sl * 8];
        bf16x8 vbl = *(const bf16x8*)&Bsl[row][sl * 8];
        acc[0][f] = __builtin_amdgcn_mfma_f32_16x16x32_bf16(al0, vbh, acc[0][f], 0, 0, 0);
        acc[0][f] = __builtin_amdgcn_mfma_f32_16x16x32_bf16(ah0, vbl, acc[0][f], 0, 0, 0);
        acc[0][f] = __builtin_amdgcn_mfma_f32_16x16x32_bf16(ah0, vbh, acc[0][f], 0, 0, 0);
        acc[1][f] = __builtin_amdgcn_mfma_f32_16x16x32_bf16(al1, vbh, acc[1][f], 0, 0, 0);
        acc[1][f] = __builtin_amdgcn_mfma_f32_16x16x32_bf16(ah1, vbl, acc[1][f], 0, 0, 0);
        acc[1][f] = __builtin_amdgcn_mfma_f32_16x16x32_bf16(ah1, vbh, acc[1][f], 0, 0, 0);
      }
    }
  }
  const int m0 = mBase + wv * 32;
#pragma unroll
  for (int i = 0; i < 2; ++i)
#pragma unroll
    for (int f = 0; f < NF; ++f)
#pragma unroll
      for (int r = 0; r < 4; ++r)
        C[(size_t)(m0 + i * 16 + kg * 4 + r) * N + n0 + f * 16 + lr] = acc[i][f][r];
}

// ---------------- 2-wave out-proj GEMM, A AND B staged in swizzled LDS ----------------
template <int BN>
__global__ __launch_bounds__(128) void gemm_mfma2(const unsigned short* __restrict__ Ah,
                                                  const unsigned short* __restrict__ Al,
                                                  const unsigned short* __restrict__ Bh,
                                                  const unsigned short* __restrict__ Bl,
                                                  float* __restrict__ C,
                                                  int M, int N, int K) {
  static_assert(BN == 32, "staging sized for BN=32");
  constexpr int NF = BN / 16;
  const int t = threadIdx.x;
  const int lane = t & 63;
  const int wv = t >> 6;  // 0..1
  const int mBase = blockIdx.y * 64;
  const int n0 = blockIdx.x * BN;
  const int lr = lane & 15;
  const int kg = lane >> 4;

  __shared__ unsigned short Ash[64][64];  // 8 KB
  __shared__ unsigned short Asl[64][64];  // 8 KB
  __shared__ unsigned short Bsh[32][64];  // 4 KB
  __shared__ unsigned short Bsl[32][64];  // 4 KB

  f32x4m acc[2][NF];
#pragma unroll
  for (int i = 0; i < 2; ++i)
#pragma unroll
    for (int f = 0; f < NF; ++f) {
      f32x4m z = {0.f, 0.f, 0.f, 0.f};
      acc[i][f] = z;
    }

  for (int k0 = 0; k0 < K; k0 += 64) {
    if (k0) __syncthreads();
    // stage B: 32 rows x 64 k
#pragma unroll
    for (int r2 = 0; r2 < 2; ++r2) {
      int idx = t + r2 * 128;
      int row = idx >> 3, c8 = idx & 7;
      int c8s = c8 ^ (row & 7);
      float4 vh = *(const float4*)(Bh + (size_t)(n0 + row) * K + k0 + c8 * 8);
      float4 vl = *(const float4*)(Bl + (size_t)(n0 + row) * K + k0 + c8 * 8);
      *(float4*)&Bsh[row][c8s * 8] = vh;
      *(float4*)&Bsl[row][c8s * 8] = vl;
    }
    // stage A: 64 rows x 64 k
#pragma unroll
    for (int r4 = 0; r4 < 4; ++r4) {
      int idx = t + r4 * 128;            // 0..511
      int row = idx >> 3, c8 = idx & 7;
      int c8s = c8 ^ (row & 7);
      float4 vh = *(const float4*)(Ah + (size_t)(mBase + row) * K + k0 + c8 * 8);
      float4 vl = *(const float4*)(Al + (size_t)(mBase + row) * K + k0 + c8 * 8);
      *(float4*)&Ash[row][c8s * 8] = vh;
      *(float4*)&Asl[row][c8s * 8] = vl;
    }
    __syncthreads();
#pragma unroll
    for (int S2 = 0; S2 < 2; ++S2) {
      int rowA0 = wv * 32 + lr;
      int rowA1 = rowA0 + 16;
      int slA = (S2 * 4 + kg) ^ (lr & 7);
      bf16x8 ah0 = *(const bf16x8*)&Ash[rowA0][slA * 8];
      bf16x8 ah1 = *(const bf16x8*)&Ash[rowA1][slA * 8];
      bf16x8 al0 = *(const bf16x8*)&Asl[rowA0][slA * 8];
      bf16x8 al1 = *(const bf16x8*)&Asl[rowA1][slA * 8];
#pragma unroll
      for (int f = 0; f < NF; ++f) {
        int row = f * 16 + lr;
        int sl = (S2 * 4 + kg) ^ (row & 7);
        bf16x8 vbh = *(const bf16x8*)&Bsh[row][sl * 8];
        bf16x8 vbl = *(const bf16x8*)&Bsl[row][sl * 8];
        acc[0][f] = __builtin_amdgcn_mfma_f32_16x16x32_bf16(al0, vbh, acc[0][f], 0, 0, 0);
        acc[0][f] = __builtin_amdgcn_mfma_f32_16x16x32_bf16(ah0, vbl, acc[0][f], 0, 0, 0);
        acc[0][f] = __builtin_amdgcn_mfma_f32_16x16x32_bf16(ah0, vbh, acc[0][f], 0, 0, 0);
        acc[1][f] = __builtin_amdgcn_mfma_f32_16x16x32_bf16(al1, vbh, acc[1][f], 0, 0, 0);
        acc[1][f] = __builtin_amdgcn_mfma_f32_16x16x32_bf16(ah1, vbl, acc[1][f], 0, 0, 0);
        acc[1][f] = __builtin_amdgcn_mfma_f32_16x16x32_bf16(ah1, vbh, acc[1][f], 0, 0, 0);
      }
    }
  }
  const int m0 = mBase + wv * 32;
#pragma unroll
  for (int i = 0; i < 2; ++i)
#pragma unroll
    for (int f = 0; f < NF; ++f)
#pragma unroll
      for (int r = 0; r < 4; ++r)
        C[(size_t)(m0 + i * 16 + kg * 4 + r) * N + n0 + f * 16 + lr] = acc[i][f][r];
}

// ---------------- gaussian kernel weights v2: 2 s-values share q/k rows ----------------
__global__ __launch_bounds__(256) void k_gauss(const float* __restrict__ qkv,
                                               const float* __restrict__ centers,
                                               const float* __restrict__ inv_var,
                                               const float* __restrict__ eff_amps,
                                               const float* __restrict__ inv_temp,
                                               float* __restrict__ qw,
                                               float* __restrict__ kw) {
  int gid = blockIdx.x * blockDim.x + threadIdx.x;  // 0..B*T*H*8-1
  int s = gid & 7;
  int h = (gid >> 3) & 7;
  int bt = gid >> 6;
  const float* qrow = qkv + (size_t)bt * 1536 + h * 64;
  const float* krow = qrow + 512;
  const float* c0 = centers + (h * 16 + s) * 64;
  const float* c1 = c0 + 8 * 64;  // s+8
  float qd0 = 0.f, kd0 = 0.f, qd1 = 0.f, kd1 = 0.f;
#pragma unroll
  for (int d = 0; d < 64; d += 4) {
    float4 qv = *(const float4*)(qrow + d);
    float4 kv = *(const float4*)(krow + d);
    float4 ca = *(const float4*)(c0 + d);
    float4 cb = *(const float4*)(c1 + d);
    float t;
    t = qv.x - ca.x; qd0 += t * t;  t = qv.y - ca.y; qd0 += t * t;
    t = qv.z - ca.z; qd0 += t * t;  t = qv.w - ca.w; qd0 += t * t;
    t = kv.x - ca.x; kd0 += t * t;  t = kv.y - ca.y; kd0 += t * t;
    t = kv.z - ca.z; kd0 += t * t;  t = kv.w - ca.w; kd0 += t * t;
    t = qv.x - cb.x; qd1 += t * t;  t = qv.y - cb.y; qd1 += t * t;
    t = qv.z - cb.z; qd1 += t * t;  t = qv.w - cb.w; qd1 += t * t;
    t = kv.x - cb.x; kd1 += t * t;  t = kv.y - cb.y; kd1 += t * t;
    t = kv.z - cb.z; kd1 += t * t;  t = kv.w - cb.w; kd1 += t * t;
  }
  qd0 = fminf(qd0, 100.f); kd0 = fminf(kd0, 100.f);
  qd1 = fminf(qd1, 100.f); kd1 = fminf(kd1, 100.f);
  float it = inv_temp[0];
  float iv0 = inv_var[h * 16 + s],     ea0 = eff_amps[h * 16 + s];
  float iv1 = inv_var[h * 16 + s + 8], ea1 = eff_amps[h * 16 + s + 8];
  size_t base = (size_t)(bt * H_ + h) * S_ + s;
  qw[base]     = __expf(-0.5f * qd0 * iv0) * ea0 * it;
  kw[base]     = __expf(-0.5f * kd0 * iv0) * ea0;
  qw[base + 8] = __expf(-0.5f * qd1 * iv1) * ea1 * it;
  kw[base + 8] = __expf(-0.5f * kd1 * iv1) * ea1;
}

__device__ __forceinline__ float dot16(const float4 q[4], const float4 k[4]) {
  return q[0].x * k[0].x + q[0].y * k[0].y + q[0].z * k[0].z + q[0].w * k[0].w +
         q[1].x * k[1].x + q[1].y * k[1].y + q[1].z * k[1].z + q[1].w * k[1].w +
         q[2].x * k[2].x + q[2].y * k[2].y + q[2].z * k[2].z + q[2].w * k[2].w +
         q[3].x * k[3].x + q[3].y * k[3].y + q[3].z * k[3].z + q[3].w * k[3].w;
}

// ---------------- fused stats + vtr (8:1 WG interleave) ----------------
__global__ __launch_bounds__(256, 4) void k_sv(const float* __restrict__ qw_g,
                                               const float* __restrict__ kw_g,
                                               const float* __restrict__ qkv,
                                               float* __restrict__ m_g,
                                               float* __restrict__ is_g,
                                               unsigned short* __restrict__ vth,
                                               unsigned short* __restrict__ vtl) {
  union Sm {
    float red[4][4][2][2];
    float Vl[64][68];
  };
  __shared__ Sm sm;
  const int bid = blockIdx.x;
  const int g = bid / 9;
  const int r = bid - g * 9;
  const int t = threadIdx.x;

  if (r < 8) {
    const int x = g * 8 + r;  // 0..4095
    const int ic = x & 127;
    const int h = (x >> 7) & 7;
    const int b = x >> 10;
    const int i0 = ic * ITS;
    const int rp = t & 3;
    const int jl = t >> 2;

    float qwr[2][16], mr[2], sr[2];
#pragma unroll
    for (int e = 0; e < 2; ++e) {
      const float* qp = qw_g + (((size_t)(b * T_ + i0 + rp * 2 + e) * H_ + h) * S_);
#pragma unroll
      for (int s4 = 0; s4 < 4; ++s4) {
        float4 v = *(const float4*)(qp + s4 * 4);
        qwr[e][s4 * 4 + 0] = v.x; qwr[e][s4 * 4 + 1] = v.y;
        qwr[e][s4 * 4 + 2] = v.z; qwr[e][s4 * 4 + 3] = v.w;
      }
      mr[e] = -1e30f; sr[e] = 0.f;
    }
    for (int c = 0; c < T_ / 64; ++c) {
      int j = c * 64 + jl;
      const float* kp = kw_g + ((size_t)(b * T_ + j) * H_ + h) * S_;
      float4 k0 = *(const float4*)(kp);
      float4 k1 = *(const float4*)(kp + 4);
      float4 k2 = *(const float4*)(kp + 8);
      float4 k3 = *(const float4*)(kp + 12);
#pragma unroll
      for (int e = 0; e < 2; ++e) {
        float d = qwr[e][0] * k0.x + qwr[e][1] * k0.y + qwr[e][2] * k0.z + qwr[e][3] * k0.w +
                  qwr[e][4] * k1.x + qwr[e][5] * k1.y + qwr[e][6] * k1.z + qwr[e][7] * k1.w +
                  qwr[e][8] * k2.x + qwr[e][9] * k2.y + qwr[e][10] * k2.z + qwr[e][11] * k2.w +
                  qwr[e][12] * k3.x + qwr[e][13] * k3.y + qwr[e][14] * k3.z + qwr[e][15] * k3.w;
        float mn = fmaxf(mr[e], d);
        sr[e] = sr[e] * __expf(mr[e] - mn) + __expf(d - mn);
        mr[e] = mn;
      }
    }
#pragma unroll
    for (int o = 4; o < 64; o <<= 1) {
#pragma unroll
      for (int e = 0; e < 2; ++e) {
        float m2 = __shfl_xor(mr[e], o);
        float s2 = __shfl_xor(sr[e], o);
        float mn = fmaxf(mr[e], m2);
        sr[e] = sr[e] * __expf(mr[e] - mn) + s2 * __expf(m2 - mn);
        mr[e] = mn;
      }
    }
    int wv = t >> 6;
    if ((t & 63) < 4) {
      sm.red[wv][rp][0][0] = mr[0]; sm.red[wv][rp][0][1] = sr[0];
      sm.red[wv][rp][1][0] = mr[1]; sm.red[wv][rp][1][1] = sr[1];
    }
    __syncthreads();
    if (t < ITS) {
      int rpp = t >> 1, e = t & 1;
      float mf = sm.red[0][rpp][e][0], sf = sm.red[0][rpp][e][1];
#pragma unroll
      for (int w = 1; w < 4; ++w) {
        float m2 = sm.red[w][rpp][e][0], s2 = sm.red[w][rpp][e][1];
        float mn = fmaxf(mf, m2);
        sf = sf * __expf(mf - mn) + s2 * __expf(m2 - mn);
        mf = mn;
      }
      size_t o = (size_t)(b * H_ + h) * T_ + i0 + t;
      m_g[o] = mf;
      is_g[o] = 1.f / sf;
    }
  } else {
    const int id = g;  // 0..511
    const int jc = id & 15;
    const int h = (id >> 4) & 7;
    const int b = id >> 7;
    const int j0 = jc * 64;
    {
      int jj = t >> 2, dqg = t & 3;
      const float* vp = qkv + (size_t)(b * T_ + j0 + jj) * 1536 + 1024 + h * 64 + dqg * 16;
#pragma unroll
      for (int q = 0; q < 4; ++q) {
        float4 v = *(const float4*)(vp + q * 4);
        *(float4*)&sm.Vl[jj][dqg * 16 + q * 4] = v;
      }
    }
    __syncthreads();
    {
      int d = t >> 2, jg = t & 3;
      ushort4 hs[4], ls[4];
#pragma unroll
      for (int q = 0; q < 4; ++q) {
        float f0 = sm.Vl[jg * 16 + q * 4 + 0][d];
        float f1 = sm.Vl[jg * 16 + q * 4 + 1][d];
        float f2 = sm.Vl[jg * 16 + q * 4 + 2][d];
        float f3 = sm.Vl[jg * 16 + q * 4 + 3][d];
        hs[q].x = f2bf(f0); ls[q].x = f2bf(f0 - bf2f(hs[q].x));
        hs[q].y = f2bf(f1); ls[q].y = f2bf(f1 - bf2f(hs[q].y));
        hs[q].z = f2bf(f2); ls[q].z = f2bf(f2 - bf2f(hs[q].z));
        hs[q].w = f2bf(f3); ls[q].w = f2bf(f3 - bf2f(hs[q].w));
      }
      size_t off = ((size_t)(b * H_ + h) * 64 + d) * 1024 + j0 + jg * 16;
#pragma unroll
      for (int q = 0; q < 4; ++q) {
        *(ushort4*)(vth + off + q * 4) = hs[q];
        *(ushort4*)(vtl + off + q * 4) = ls[q];
      }
    }
  }
}

// ---------------- attn writer (v1 body, jt-split 16: one subtile per WG) ----------------
__global__ __launch_bounds__(256, 4) void k_attnw(const float* __restrict__ qw_g,
                                                  const float* __restrict__ kw_g,
                                                  const float* __restrict__ m_g,
                                                  const float* __restrict__ is_g,
                                                  float* __restrict__ attn) {
  const int x = blockIdx.x;
  const int jt = x & 15;
  const int it = (x >> 4) & 127;
  const int b = x >> 11;
  const int i0 = it * ITW;
  const int j0 = jt * 64;
  const int tid = threadIdx.x;

  __shared__ float qw_l[ITW][H_ * S_];     // 4 KB
  __shared__ float msl[ITW][H_];
  __shared__ float isl[ITW][H_];
  __shared__ float tile[ITW][H_][68];      // 17.4 KB

  {
    int f = tid * 4;
    int r = f >> 7, c = f & 127;
    *(float4*)&qw_l[r][c] = *(const float4*)(qw_g + ((size_t)(b * T_ + i0 + r) * 128 + c));
  }
  if (tid < 64) {
    int r = tid >> 3, hh = tid & 7;
    size_t o = (size_t)(b * H_ + hh) * T_ + i0 + r;
    msl[r][hh] = m_g[o];
    isl[r][hh] = is_g[o];
  }
  __syncthreads();

  const int h = tid >> 5;
  const int jq = tid & 31;
  const float* kw_b = kw_g + (size_t)b * T_ * (H_ * S_);
  float* attn_b = attn + (size_t)(b * T_ + i0) * (T_ * H_);

  const float* kp = kw_b + ((size_t)(j0 + jq * 2) * H_ + h) * S_;
  float4 ka[4], kb[4];
  ka[0] = *(const float4*)(kp);       ka[1] = *(const float4*)(kp + 4);
  ka[2] = *(const float4*)(kp + 8);   ka[3] = *(const float4*)(kp + 12);
  kb[0] = *(const float4*)(kp + 128); kb[1] = *(const float4*)(kp + 132);
  kb[2] = *(const float4*)(kp + 136); kb[3] = *(const float4*)(kp + 140);
#pragma unroll
  for (int r = 0; r < ITW; ++r) {
    float4 q4[4];
    q4[0] = *(const float4*)&qw_l[r][h * 16 + 0];
    q4[1] = *(const float4*)&qw_l[r][h * 16 + 4];
    q4[2] = *(const float4*)&qw_l[r][h * 16 + 8];
    q4[3] = *(const float4*)&qw_l[r][h * 16 + 12];
    float la = dot16(q4, ka);
    float lb = dot16(q4, kb);
    float mm = msl[r][h], ii = isl[r][h];
    *(float2*)&tile[r][h][jq * 2] =
        make_float2(__expf(la - mm) * ii, __expf(lb - mm) * ii);
  }
  __syncthreads();
#pragma unroll
  for (int l = 0; l < 4; ++l) {
    int f = (l * 256 + tid) * 4;
    int r = f >> 9;
    int rem = f & 511;
    int jl = rem >> 3;
    int h0 = rem & 7;  // 0 or 4
    float4 v;
    v.x = tile[r][h0 + 0][jl];
    v.y = tile[r][h0 + 1][jl];
    v.z = tile[r][h0 + 2][jl];
    v.w = tile[r][h0 + 3][jl];
    *(float4*)(attn_b + (size_t)r * (T_ * H_) + (size_t)(j0 + jl) * H_ + h0) = v;
  }
}

// ---------------- PV via MFMA (v6): Vt chunk staged in swizzled LDS ----------------
__global__ __launch_bounds__(256, 4) void k_pv(const float* __restrict__ qw_g,
                                               const float* __restrict__ kw_g,
                                               const float* __restrict__ m_g,
                                               const float* __restrict__ is_g,
                                               const unsigned short* __restrict__ vth,
                                               const unsigned short* __restrict__ vtl,
                                               unsigned short* __restrict__ oph,
                                               unsigned short* __restrict__ opl) {
  const int bid = blockIdx.x;
  const int xcd = bid & 7;
  const int qq = bid >> 3;             // 0..127
  const int p = xcd * 4 + (qq & 3);    // panel 0..31
  const int ib = qq >> 2;              // 0..31
  const int b = p >> 3;
  const int h = p & 7;
  const int i0 = ib * PVI;
  const int t = threadIdx.x;
  const int lane = t & 63;
  const int w = t >> 6;
  const int I = w >> 1;                // i-frag
  const int S = w & 1;                 // k-step (32-j half of chunk)
  const int lr = lane & 15;
  const int kg = lane >> 4;

  union Sm {
    struct {
      unsigned short Vsh[64][64];   // 8 KB
      unsigned short Vsl[64][64];   // 8 KB
    } v;
    float mgs[128][17];             // 8.7 KB merge scratch (post-loop only)
  };
  __shared__ Sm sm;
  __shared__ float kw_sw[PVJ][16];  // 4 KB; s4-block ^= (j>>3)&3

  const int irow = I * 16 + lr;
  float qwr[16];
  {
    const float* qp = qw_g + (((size_t)(b * T_ + i0 + irow) * H_ + h) * S_);
#pragma unroll
    for (int s4 = 0; s4 < 4; ++s4) {
      float4 v = *(const float4*)(qp + s4 * 4);
      qwr[s4 * 4 + 0] = v.x; qwr[s4 * 4 + 1] = v.y;
      qwr[s4 * 4 + 2] = v.z; qwr[s4 * 4 + 3] = v.w;
    }
  }
  float mr = m_g[(size_t)(b * H_ + h) * T_ + i0 + irow];
  float isr = is_g[(size_t)(b * H_ + h) * T_ + i0 + irow];
#pragma unroll
  for (int s = 0; s < 16; ++s) asm volatile("" : "+v"(qwr[s]));
  asm volatile("" : "+v"(mr));
  asm volatile("" : "+v"(isr));

  const unsigned short* vhp = vth + ((size_t)(b * H_ + h) * 64) * 1024;
  const unsigned short* vlp = vtl + ((size_t)(b * H_ + h) * 64) * 1024;

  f32x4m acc[4];
#pragma unroll
  for (int f = 0; f < 4; ++f) { f32x4m z = {0.f, 0.f, 0.f, 0.f}; acc[f] = z; }

  for (int jc = 0; jc < T_ / PVJ; ++jc) {
    const int j0 = jc * PVJ;
    __syncthreads();  // prior chunk's readers done
    // stage kw (swizzled)
    {
      int j = t >> 2, s4g = t & 3;
      float4 v = *(const float4*)(kw_g + (((size_t)(b * T_ + j0 + j) * H_ + h) * S_ + s4g * 4));
      int blk = s4g ^ ((j >> 3) & 3);
      *(float4*)&kw_sw[j][blk * 4] = v;
    }
    // stage Vt hi/lo chunk: 64 d-rows x 64 j, coalesced 128B rows, 16B-slot swizzle
#pragma unroll
    for (int u2 = 0; u2 < 2; ++u2) {
      int u = t + u2 * 256;           // 0..511
      int row = u >> 3, c8 = u & 7;
      int c8s = c8 ^ (row & 7);
      float4 vh = *(const float4*)(vhp + (size_t)row * 1024 + j0 + c8 * 8);
      float4 vl = *(const float4*)(vlp + (size_t)row * 1024 + j0 + c8 * 8);
      *(float4*)&sm.v.Vsh[row][c8s * 8] = vh;
      *(float4*)&sm.v.Vsl[row][c8s * 8] = vl;
    }
    __syncthreads();
    // ---- phase 1: logits -> P A-frag (hi/lo bf16) in registers ----
    union UA { unsigned short s[8]; bf16x8 v; } AH, AL;
#pragma unroll
    for (int u = 0; u < 8; ++u) {
      int jr = S * 32 + kg * 8 + u;
      int g = (jr >> 3) & 3;
      float d = 0.f;
#pragma unroll
      for (int s4 = 0; s4 < 4; ++s4) {
        float4 kv = *(const float4*)&kw_sw[jr][(s4 ^ g) * 4];
        d += qwr[s4 * 4 + 0] * kv.x + qwr[s4 * 4 + 1] * kv.y +
             qwr[s4 * 4 + 2] * kv.z + qwr[s4 * 4 + 3] * kv.w;
      }
      float pv = __expf(d - mr) * isr;
      unsigned short hh = f2bf(pv);
      AH.s[u] = hh;
      AL.s[u] = f2bf(pv - bf2f(hh));
    }
    // ---- phase 2: B-frags from swizzled LDS, 3 MFMA each ----
#pragma unroll
    for (int f = 0; f < 4; ++f) {
      int row = f * 16 + lr;
      int sl = (S * 4 + kg) ^ (row & 7);
      bf16x8 BHv = *(const bf16x8*)&sm.v.Vsh[row][sl * 8];
      bf16x8 BLv = *(const bf16x8*)&sm.v.Vsl[row][sl * 8];
      acc[f] = __builtin_amdgcn_mfma_f32_16x16x32_bf16(AL.v, BHv, acc[f], 0, 0, 0);
      acc[f] = __builtin_amdgcn_mfma_f32_16x16x32_bf16(AH.v, BLv, acc[f], 0, 0, 0);
      acc[f] = __builtin_amdgcn_mfma_f32_16x16x32_bf16(AH.v, BHv, acc[f], 0, 0, 0);
    }
  }
  // ---- merge S=0 + S=1 partials (scratch aliases V buffers), store bf16 hi/lo ----
  __syncthreads();
  if (S == 1) {
    float* dst = &sm.mgs[I * 64 + lane][0];
#pragma unroll
    for (int f = 0; f < 4; ++f)
#pragma unroll
      for (int r = 0; r < 4; ++r) dst[f * 4 + r] = acc[f][r];
  }
  __syncthreads();
  if (S == 0) {
    const float* src = &sm.mgs[I * 64 + lane][0];
#pragma unroll
    for (int f = 0; f < 4; ++f) {
#pragma unroll
      for (int r = 0; r < 4; ++r) {
        float o = acc[f][r] + src[f * 4 + r];
        unsigned short hh = f2bf(o);
        unsigned short ll = f2bf(o - bf2f(hh));
        size_t idx = (size_t)(b * T_ + i0 + I * 16 + kg * 4 + r) * D_ + h * HD_ + f * 16 + lr;
        oph[idx] = hh;
        opl[idx] = ll;
      }
    }
  }
}

extern "C" void kernel_launch(void* const* d_in, const int* in_sizes, int n_in,
                              void* d_out, int out_size, void* d_ws, size_t ws_size,
                              hipStream_t stream) {
  const float* x = (const float*)d_in[0];
  const float* qkv_w = (const float*)d_in[1];
  const float* out_w = (const float*)d_in[2];
  const float* base_c = (const float*)d_in[3];
  const float* deltas = (const float*)d_in[4];
  const float* log_sc = (const float*)d_in[5];
  const float* log_am = (const float*)d_in[6];
  const float* move_p = (const float*)d_in[7];
  const float* temp = (const float*)d_in[8];

  float* out = (float*)d_out;                    // B*T*D
  float* attn = out + (size_t)B_ * T_ * D_;      // B*T*T*H

  float* ws = (float*)d_ws;
  float* qkv = ws;                                          // 6,291,456 f
  float* qw = qkv + 6291456;                                // 524,288
  float* kw = qw + 524288;                                  // 524,288
  float* centers = kw + 524288;                             // 8,192
  float* inv_var = centers + 8192;                          // 128
  float* eff_amps = inv_var + 128;                          // 128
  float* inv_temp = eff_amps + 128;                         // 4
  float* m_g = inv_temp + 4;                                // 32,768
  float* is_g = m_g + 32768;                                // 32,768
  unsigned short* xh = (unsigned short*)(is_g + 32768);     // 2,097,152 us
  unsigned short* xl = xh + 2097152;                        // 2,097,152
  unsigned short* wh = xl + 2097152;                        // 786,432
  unsigned short* wl = wh + 786432;                         // 786,432
  unsigned short* owh = wl + 786432;                        // 262,144
  unsigned short* owl = owh + 262144;                       // 262,144
  unsigned short* oph = owl + 262144;                       // 2,097,152
  unsigned short* opl = oph + 2097152;                      // 2,097,152
  unsigned short* vth = opl + 2097152;                      // 2,097,152
  unsigned short* vtl = vth + 2097152;                      // 2,097,152

  k_prep<<<3104, 256, 0, stream>>>(x, qkv_w, out_w, base_c, deltas, log_sc, log_am,
                                   move_p, temp, xh, xl, wh, wl, owh, owl,
                                   centers, inv_var, eff_amps, inv_temp);

  dim3 g1(1536 / 64, 4096 / 128);   // 24 x 32 = 768 WGs
  gemm_mfma<64><<<g1, 256, 0, stream>>>(xh, xl, wh, wl, qkv, B_ * T_, 3 * D_, D_);

  k_gauss<<<(B_ * T_ * H_ * 8) / 256, 256, 0, stream>>>(qkv, centers, inv_var,
                                                        eff_amps, inv_temp, qw, kw);
  k_sv<<<4608, 256, 0, stream>>>(qw, kw, qkv, m_g, is_g, vth, vtl);
  k_attnw<<<B_ * (T_ / ITW) * 16, 256, 0, stream>>>(qw, kw, m_g, is_g, attn);
  k_pv<<<B_ * H_ * (T_ / PVI), 256, 0, stream>>>(qw, kw, m_g, is_g, vth, vtl, oph, opl);

  dim3 g2(512 / 32, 4096 / 64);     // 16 x 64 = 1024 WGs
  gemm_mfma2<32><<<g2, 128, 0, stream>>>(oph, opl, owh, owl, out, B_ * T_, D_, D_);
}

// Round 20
// 243.706 us; speedup vs baseline: 1.3225x; 1.0066x over previous
//
#include <hip/hip_runtime.h>
#include <hip/hip_bf16.h>

#define B_ 4
#define T_ 1024
#define D_ 512
#define H_ 8
#define S_ 16
#define HD_ 64
#define ITS 8    // i-rows per WG (stats)
#define ITW 8    // i-rows per WG (attnw)
#define PVI 32   // i-rows per WG (pv)
#define PVJ 64   // j-chunk (pv)

typedef short bf16x8 __attribute__((ext_vector_type(8)));
typedef float f32x4m __attribute__((ext_vector_type(4)));

__device__ __forceinline__ unsigned short f2bf(float f) {
  unsigned u = __float_as_uint(f);
  unsigned r = (u + 0x7FFFu + ((u >> 16) & 1u)) >> 16;  // RNE
  return (unsigned short)r;
}
__device__ __forceinline__ float bf2f(unsigned short h) {
  return __uint_as_float((unsigned)h << 16);
}

__device__ __forceinline__ void split4(const float4 v, ushort4& h, ushort4& l) {
  h.x = f2bf(v.x); l.x = f2bf(v.x - bf2f(h.x));
  h.y = f2bf(v.y); l.y = f2bf(v.y - bf2f(h.y));
  h.z = f2bf(v.z); l.z = f2bf(v.z - bf2f(h.z));
  h.w = f2bf(v.w); l.w = f2bf(v.w - bf2f(h.w));
}

// ---------------- params only (splits now fused into the GEMM staging) ----------------
__global__ void k_params(const float* __restrict__ base_centers,
                         const float* __restrict__ center_deltas,
                         const float* __restrict__ log_scales,
                         const float* __restrict__ log_amps,
                         const float* __restrict__ movement_param,
                         const float* __restrict__ temperature,
                         float* __restrict__ centers,
                         float* __restrict__ inv_var,
                         float* __restrict__ eff_amps,
                         float* __restrict__ inv_temp) {
  int tid = blockIdx.x * blockDim.x + threadIdx.x;
  float move = (1.f / (1.f + __expf(-movement_param[0]))) * 0.2f;
  if (tid < H_ * S_ * HD_)
    centers[tid] = base_centers[tid] + center_deltas[tid] * move;
  if (tid < H_ * S_) {
    float sc = __expf(log_scales[tid]);
    sc = fminf(fmaxf(sc, 1e-4f), 5.f);
    float am = __expf(log_amps[tid]);
    am = fminf(fmaxf(am, 1e-6f), 10.f);
    inv_var[tid] = 1.f / (sc * sc + 1e-8f);
    eff_amps[tid] = (am > 0.001f) ? am : 0.f;
  }
  if (tid == 0) {
    float t = fminf(fmaxf(temperature[0], 0.01f), 10.f);
    inv_temp[0] = 1.f / t;
  }
}

// ---------------- split-bf16 MFMA GEMM from fp32 inputs, A+B staged in LDS ----------------
// fp32 and bf16-hi/lo are both 4B/elem: staging fp32 directly and splitting
// in-register during the stage costs identical global bytes and removes the
// separate split pre-pass + 22MB ws round-trip. Split VALU hides under MFMA.
template <int BN>
__global__ __launch_bounds__(256) void gemm_mfma(const float* __restrict__ A,
                                                 const float* __restrict__ Bw,
                                                 float* __restrict__ C,
                                                 int M, int N, int K) {
  static_assert(BN == 64, "staging sized for BN=64");
  constexpr int NF = BN / 16;
  const int t = threadIdx.x;
  const int lane = t & 63;
  const int wv = t >> 6;
  const int mBase = blockIdx.y * 128;
  const int n0 = blockIdx.x * BN;
  const int lr = lane & 15;
  const int kg = lane >> 4;

  __shared__ unsigned short Ash[128][64];  // 16 KB
  __shared__ unsigned short Asl[128][64];  // 16 KB
  __shared__ unsigned short Bsh[64][64];   // 8 KB
  __shared__ unsigned short Bsl[64][64];   // 8 KB

  f32x4m acc[2][NF];
#pragma unroll
  for (int i = 0; i < 2; ++i)
#pragma unroll
    for (int f = 0; f < NF; ++f) {
      f32x4m z = {0.f, 0.f, 0.f, 0.f};
      acc[i][f] = z;
    }

  for (int k0 = 0; k0 < K; k0 += 64) {
    if (k0) __syncthreads();  // previous chunk's readers done
    // stage B: 64 rows x 64 k (fp32 -> hi/lo split in-register)
#pragma unroll
    for (int r2 = 0; r2 < 2; ++r2) {
      int idx = t + r2 * 256;
      int row = idx >> 3, c8 = idx & 7;
      int c8s = c8 ^ (row & 7);
      const float* src = Bw + (size_t)(n0 + row) * K + k0 + c8 * 8;
      float4 v0 = *(const float4*)(src);
      float4 v1 = *(const float4*)(src + 4);
      ushort4 h0, l0, h1, l1;
      split4(v0, h0, l0); split4(v1, h1, l1);
      *(ushort4*)&Bsh[row][c8s * 8]     = h0;
      *(ushort4*)&Bsh[row][c8s * 8 + 4] = h1;
      *(ushort4*)&Bsl[row][c8s * 8]     = l0;
      *(ushort4*)&Bsl[row][c8s * 8 + 4] = l1;
    }
    // stage A: 128 rows x 64 k
#pragma unroll
    for (int r4 = 0; r4 < 4; ++r4) {
      int idx = t + r4 * 256;            // 0..1023
      int row = idx >> 3, c8 = idx & 7;
      int c8s = c8 ^ (row & 7);
      const float* src = A + (size_t)(mBase + row) * K + k0 + c8 * 8;
      float4 v0 = *(const float4*)(src);
      float4 v1 = *(const float4*)(src + 4);
      ushort4 h0, l0, h1, l1;
      split4(v0, h0, l0); split4(v1, h1, l1);
      *(ushort4*)&Ash[row][c8s * 8]     = h0;
      *(ushort4*)&Ash[row][c8s * 8 + 4] = h1;
      *(ushort4*)&Asl[row][c8s * 8]     = l0;
      *(ushort4*)&Asl[row][c8s * 8 + 4] = l1;
    }
    __syncthreads();
#pragma unroll
    for (int S2 = 0; S2 < 2; ++S2) {
      int rowA0 = wv * 32 + lr;
      int rowA1 = rowA0 + 16;
      int slA = (S2 * 4 + kg) ^ (lr & 7);  // rowA&7 == lr&7 for both frags
      bf16x8 ah0 = *(const bf16x8*)&Ash[rowA0][slA * 8];
      bf16x8 ah1 = *(const bf16x8*)&Ash[rowA1][slA * 8];
      bf16x8 al0 = *(const bf16x8*)&Asl[rowA0][slA * 8];
      bf16x8 al1 = *(const bf16x8*)&Asl[rowA1][slA * 8];
#pragma unroll
      for (int f = 0; f < NF; ++f) {
        int row = f * 16 + lr;
        int sl = (S2 * 4 + kg) ^ (row & 7);
        bf16x8 vbh = *(const bf16x8*)&Bsh[row][sl * 8];
        bf16x8 vbl = *(const bf16x8*)&Bsl[row][sl * 8];
        acc[0][f] = __builtin_amdgcn_mfma_f32_16x16x32_bf16(al0, vbh, acc[0][f], 0, 0, 0);
        acc[0][f] = __builtin_amdgcn_mfma_f32_16x16x32_bf16(ah0, vbl, acc[0][f], 0, 0, 0);
        acc[0][f] = __builtin_amdgcn_mfma_f32_16x16x32_bf16(ah0, vbh, acc[0][f], 0, 0, 0);
        acc[1][f] = __builtin_amdgcn_mfma_f32_16x16x32_bf16(al1, vbh, acc[1][f], 0, 0, 0);
        acc[1][f] = __builtin_amdgcn_mfma_f32_16x16x32_bf16(ah1, vbl, acc[1][f], 0, 0, 0);
        acc[1][f] = __builtin_amdgcn_mfma_f32_16x16x32_bf16(ah1, vbh, acc[1][f], 0, 0, 0);
      }
    }
  }
  const int m0 = mBase + wv * 32;
#pragma unroll
  for (int i = 0; i < 2; ++i)
#pragma unroll
    for (int f = 0; f < NF; ++f)
#pragma unroll
      for (int r = 0; r < 4; ++r)
        C[(size_t)(m0 + i * 16 + kg * 4 + r) * N + n0 + f * 16 + lr] = acc[i][f][r];
}

// ---------------- 2-wave out-proj GEMM: A = bf16 hi/lo pair, B = fp32 (split in stage) ----------------
template <int BN>
__global__ __launch_bounds__(128) void gemm_mfma2(const unsigned short* __restrict__ Ah,
                                                  const unsigned short* __restrict__ Al,
                                                  const float* __restrict__ Bw,
                                                  float* __restrict__ C,
                                                  int M, int N, int K) {
  static_assert(BN == 32, "staging sized for BN=32");
  constexpr int NF = BN / 16;
  const int t = threadIdx.x;
  const int lane = t & 63;
  const int wv = t >> 6;  // 0..1
  const int mBase = blockIdx.y * 64;
  const int n0 = blockIdx.x * BN;
  const int lr = lane & 15;
  const int kg = lane >> 4;

  __shared__ unsigned short Ash[64][64];  // 8 KB
  __shared__ unsigned short Asl[64][64];  // 8 KB
  __shared__ unsigned short Bsh[32][64];  // 4 KB
  __shared__ unsigned short Bsl[32][64];  // 4 KB

  f32x4m acc[2][NF];
#pragma unroll
  for (int i = 0; i < 2; ++i)
#pragma unroll
    for (int f = 0; f < NF; ++f) {
      f32x4m z = {0.f, 0.f, 0.f, 0.f};
      acc[i][f] = z;
    }

  for (int k0 = 0; k0 < K; k0 += 64) {
    if (k0) __syncthreads();
    // stage B: 32 rows x 64 k (fp32 -> split)
#pragma unroll
    for (int r2 = 0; r2 < 2; ++r2) {
      int idx = t + r2 * 128;
      int row = idx >> 3, c8 = idx & 7;
      int c8s = c8 ^ (row & 7);
      const float* src = Bw + (size_t)(n0 + row) * K + k0 + c8 * 8;
      float4 v0 = *(const float4*)(src);
      float4 v1 = *(const float4*)(src + 4);
      ushort4 h0, l0, h1, l1;
      split4(v0, h0, l0); split4(v1, h1, l1);
      *(ushort4*)&Bsh[row][c8s * 8]     = h0;
      *(ushort4*)&Bsh[row][c8s * 8 + 4] = h1;
      *(ushort4*)&Bsl[row][c8s * 8]     = l0;
      *(ushort4*)&Bsl[row][c8s * 8 + 4] = l1;
    }
    // stage A: 64 rows x 64 k (pre-split bf16 from k_pv)
#pragma unroll
    for (int r4 = 0; r4 < 4; ++r4) {
      int idx = t + r4 * 128;            // 0..511
      int row = idx >> 3, c8 = idx & 7;
      int c8s = c8 ^ (row & 7);
      float4 vh = *(const float4*)(Ah + (size_t)(mBase + row) * K + k0 + c8 * 8);
      float4 vl = *(const float4*)(Al + (size_t)(mBase + row) * K + k0 + c8 * 8);
      *(float4*)&Ash[row][c8s * 8] = vh;
      *(float4*)&Asl[row][c8s * 8] = vl;
    }
    __syncthreads();
#pragma unroll
    for (int S2 = 0; S2 < 2; ++S2) {
      int rowA0 = wv * 32 + lr;
      int rowA1 = rowA0 + 16;
      int slA = (S2 * 4 + kg) ^ (lr & 7);
      bf16x8 ah0 = *(const bf16x8*)&Ash[rowA0][slA * 8];
      bf16x8 ah1 = *(const bf16x8*)&Ash[rowA1][slA * 8];
      bf16x8 al0 = *(const bf16x8*)&Asl[rowA0][slA * 8];
      bf16x8 al1 = *(const bf16x8*)&Asl[rowA1][slA * 8];
#pragma unroll
      for (int f = 0; f < NF; ++f) {
        int row = f * 16 + lr;
        int sl = (S2 * 4 + kg) ^ (row & 7);
        bf16x8 vbh = *(const bf16x8*)&Bsh[row][sl * 8];
        bf16x8 vbl = *(const bf16x8*)&Bsl[row][sl * 8];
        acc[0][f] = __builtin_amdgcn_mfma_f32_16x16x32_bf16(al0, vbh, acc[0][f], 0, 0, 0);
        acc[0][f] = __builtin_amdgcn_mfma_f32_16x16x32_bf16(ah0, vbl, acc[0][f], 0, 0, 0);
        acc[0][f] = __builtin_amdgcn_mfma_f32_16x16x32_bf16(ah0, vbh, acc[0][f], 0, 0, 0);
        acc[1][f] = __builtin_amdgcn_mfma_f32_16x16x32_bf16(al1, vbh, acc[1][f], 0, 0, 0);
        acc[1][f] = __builtin_amdgcn_mfma_f32_16x16x32_bf16(ah1, vbl, acc[1][f], 0, 0, 0);
        acc[1][f] = __builtin_amdgcn_mfma_f32_16x16x32_bf16(ah1, vbh, acc[1][f], 0, 0, 0);
      }
    }
  }
  const int m0 = mBase + wv * 32;
#pragma unroll
  for (int i = 0; i < 2; ++i)
#pragma unroll
    for (int f = 0; f < NF; ++f)
#pragma unroll
      for (int r = 0; r < 4; ++r)
        C[(size_t)(m0 + i * 16 + kg * 4 + r) * N + n0 + f * 16 + lr] = acc[i][f][r];
}

// ---------------- gaussian kernel weights v2: 2 s-values share q/k rows ----------------
__global__ __launch_bounds__(256) void k_gauss(const float* __restrict__ qkv,
                                               const float* __restrict__ centers,
                                               const float* __restrict__ inv_var,
                                               const float* __restrict__ eff_amps,
                                               const float* __restrict__ inv_temp,
                                               float* __restrict__ qw,
                                               float* __restrict__ kw) {
  int gid = blockIdx.x * blockDim.x + threadIdx.x;  // 0..B*T*H*8-1
  int s = gid & 7;
  int h = (gid >> 3) & 7;
  int bt = gid >> 6;
  const float* qrow = qkv + (size_t)bt * 1536 + h * 64;
  const float* krow = qrow + 512;
  const float* c0 = centers + (h * 16 + s) * 64;
  const float* c1 = c0 + 8 * 64;  // s+8
  float qd0 = 0.f, kd0 = 0.f, qd1 = 0.f, kd1 = 0.f;
#pragma unroll
  for (int d = 0; d < 64; d += 4) {
    float4 qv = *(const float4*)(qrow + d);
    float4 kv = *(const float4*)(krow + d);
    float4 ca = *(const float4*)(c0 + d);
    float4 cb = *(const float4*)(c1 + d);
    float t;
    t = qv.x - ca.x; qd0 += t * t;  t = qv.y - ca.y; qd0 += t * t;
    t = qv.z - ca.z; qd0 += t * t;  t = qv.w - ca.w; qd0 += t * t;
    t = kv.x - ca.x; kd0 += t * t;  t = kv.y - ca.y; kd0 += t * t;
    t = kv.z - ca.z; kd0 += t * t;  t = kv.w - ca.w; kd0 += t * t;
    t = qv.x - cb.x; qd1 += t * t;  t = qv.y - cb.y; qd1 += t * t;
    t = qv.z - cb.z; qd1 += t * t;  t = qv.w - cb.w; qd1 += t * t;
    t = kv.x - cb.x; kd1 += t * t;  t = kv.y - cb.y; kd1 += t * t;
    t = kv.z - cb.z; kd1 += t * t;  t = kv.w - cb.w; kd1 += t * t;
  }
  qd0 = fminf(qd0, 100.f); kd0 = fminf(kd0, 100.f);
  qd1 = fminf(qd1, 100.f); kd1 = fminf(kd1, 100.f);
  float it = inv_temp[0];
  float iv0 = inv_var[h * 16 + s],     ea0 = eff_amps[h * 16 + s];
  float iv1 = inv_var[h * 16 + s + 8], ea1 = eff_amps[h * 16 + s + 8];
  size_t base = (size_t)(bt * H_ + h) * S_ + s;
  qw[base]     = __expf(-0.5f * qd0 * iv0) * ea0 * it;
  kw[base]     = __expf(-0.5f * kd0 * iv0) * ea0;
  qw[base + 8] = __expf(-0.5f * qd1 * iv1) * ea1 * it;
  kw[base + 8] = __expf(-0.5f * kd1 * iv1) * ea1;
}

__device__ __forceinline__ float dot16(const float4 q[4], const float4 k[4]) {
  return q[0].x * k[0].x + q[0].y * k[0].y + q[0].z * k[0].z + q[0].w * k[0].w +
         q[1].x * k[1].x + q[1].y * k[1].y + q[1].z * k[1].z + q[1].w * k[1].w +
         q[2].x * k[2].x + q[2].y * k[2].y + q[2].z * k[2].z + q[2].w * k[2].w +
         q[3].x * k[3].x + q[3].y * k[3].y + q[3].z * k[3].z + q[3].w * k[3].w;
}

// ---------------- fused stats + vtr (8:1 WG interleave) ----------------
__global__ __launch_bounds__(256, 4) void k_sv(const float* __restrict__ qw_g,
                                               const float* __restrict__ kw_g,
                                               const float* __restrict__ qkv,
                                               float* __restrict__ m_g,
                                               float* __restrict__ is_g,
                                               unsigned short* __restrict__ vth,
                                               unsigned short* __restrict__ vtl) {
  union Sm {
    float red[4][4][2][2];
    float Vl[64][68];
  };
  __shared__ Sm sm;
  const int bid = blockIdx.x;
  const int g = bid / 9;
  const int r = bid - g * 9;
  const int t = threadIdx.x;

  if (r < 8) {
    const int x = g * 8 + r;  // 0..4095
    const int ic = x & 127;
    const int h = (x >> 7) & 7;
    const int b = x >> 10;
    const int i0 = ic * ITS;
    const int rp = t & 3;
    const int jl = t >> 2;

    float qwr[2][16], mr[2], sr[2];
#pragma unroll
    for (int e = 0; e < 2; ++e) {
      const float* qp = qw_g + (((size_t)(b * T_ + i0 + rp * 2 + e) * H_ + h) * S_);
#pragma unroll
      for (int s4 = 0; s4 < 4; ++s4) {
        float4 v = *(const float4*)(qp + s4 * 4);
        qwr[e][s4 * 4 + 0] = v.x; qwr[e][s4 * 4 + 1] = v.y;
        qwr[e][s4 * 4 + 2] = v.z; qwr[e][s4 * 4 + 3] = v.w;
      }
      mr[e] = -1e30f; sr[e] = 0.f;
    }
    for (int c = 0; c < T_ / 64; ++c) {
      int j = c * 64 + jl;
      const float* kp = kw_g + ((size_t)(b * T_ + j) * H_ + h) * S_;
      float4 k0 = *(const float4*)(kp);
      float4 k1 = *(const float4*)(kp + 4);
      float4 k2 = *(const float4*)(kp + 8);
      float4 k3 = *(const float4*)(kp + 12);
#pragma unroll
      for (int e = 0; e < 2; ++e) {
        float d = qwr[e][0] * k0.x + qwr[e][1] * k0.y + qwr[e][2] * k0.z + qwr[e][3] * k0.w +
                  qwr[e][4] * k1.x + qwr[e][5] * k1.y + qwr[e][6] * k1.z + qwr[e][7] * k1.w +
                  qwr[e][8] * k2.x + qwr[e][9] * k2.y + qwr[e][10] * k2.z + qwr[e][11] * k2.w +
                  qwr[e][12] * k3.x + qwr[e][13] * k3.y + qwr[e][14] * k3.z + qwr[e][15] * k3.w;
        float mn = fmaxf(mr[e], d);
        sr[e] = sr[e] * __expf(mr[e] - mn) + __expf(d - mn);
        mr[e] = mn;
      }
    }
#pragma unroll
    for (int o = 4; o < 64; o <<= 1) {
#pragma unroll
      for (int e = 0; e < 2; ++e) {
        float m2 = __shfl_xor(mr[e], o);
        float s2 = __shfl_xor(sr[e], o);
        float mn = fmaxf(mr[e], m2);
        sr[e] = sr[e] * __expf(mr[e] - mn) + s2 * __expf(m2 - mn);
        mr[e] = mn;
      }
    }
    int wv = t >> 6;
    if ((t & 63) < 4) {
      sm.red[wv][rp][0][0] = mr[0]; sm.red[wv][rp][0][1] = sr[0];
      sm.red[wv][rp][1][0] = mr[1]; sm.red[wv][rp][1][1] = sr[1];
    }
    __syncthreads();
    if (t < ITS) {
      int rpp = t >> 1, e = t & 1;
      float mf = sm.red[0][rpp][e][0], sf = sm.red[0][rpp][e][1];
#pragma unroll
      for (int w = 1; w < 4; ++w) {
        float m2 = sm.red[w][rpp][e][0], s2 = sm.red[w][rpp][e][1];
        float mn = fmaxf(mf, m2);
        sf = sf * __expf(mf - mn) + s2 * __expf(m2 - mn);
        mf = mn;
      }
      size_t o = (size_t)(b * H_ + h) * T_ + i0 + t;
      m_g[o] = mf;
      is_g[o] = 1.f / sf;
    }
  } else {
    const int id = g;  // 0..511
    const int jc = id & 15;
    const int h = (id >> 4) & 7;
    const int b = id >> 7;
    const int j0 = jc * 64;
    {
      int jj = t >> 2, dqg = t & 3;
      const float* vp = qkv + (size_t)(b * T_ + j0 + jj) * 1536 + 1024 + h * 64 + dqg * 16;
#pragma unroll
      for (int q = 0; q < 4; ++q) {
        float4 v = *(const float4*)(vp + q * 4);
        *(float4*)&sm.Vl[jj][dqg * 16 + q * 4] = v;
      }
    }
    __syncthreads();
    {
      int d = t >> 2, jg = t & 3;
      ushort4 hs[4], ls[4];
#pragma unroll
      for (int q = 0; q < 4; ++q) {
        float f0 = sm.Vl[jg * 16 + q * 4 + 0][d];
        float f1 = sm.Vl[jg * 16 + q * 4 + 1][d];
        float f2 = sm.Vl[jg * 16 + q * 4 + 2][d];
        float f3 = sm.Vl[jg * 16 + q * 4 + 3][d];
        hs[q].x = f2bf(f0); ls[q].x = f2bf(f0 - bf2f(hs[q].x));
        hs[q].y = f2bf(f1); ls[q].y = f2bf(f1 - bf2f(hs[q].y));
        hs[q].z = f2bf(f2); ls[q].z = f2bf(f2 - bf2f(hs[q].z));
        hs[q].w = f2bf(f3); ls[q].w = f2bf(f3 - bf2f(hs[q].w));
      }
      size_t off = ((size_t)(b * H_ + h) * 64 + d) * 1024 + j0 + jg * 16;
#pragma unroll
      for (int q = 0; q < 4; ++q) {
        *(ushort4*)(vth + off + q * 4) = hs[q];
        *(ushort4*)(vtl + off + q * 4) = ls[q];
      }
    }
  }
}

// ---------------- attn writer (v1 body, jt-split 16: one subtile per WG) ----------------
__global__ __launch_bounds__(256, 4) void k_attnw(const float* __restrict__ qw_g,
                                                  const float* __restrict__ kw_g,
                                                  const float* __restrict__ m_g,
                                                  const float* __restrict__ is_g,
                                                  float* __restrict__ attn) {
  const int x = blockIdx.x;
  const int jt = x & 15;
  const int it = (x >> 4) & 127;
  const int b = x >> 11;
  const int i0 = it * ITW;
  const int j0 = jt * 64;
  const int tid = threadIdx.x;

  __shared__ float qw_l[ITW][H_ * S_];     // 4 KB
  __shared__ float msl[ITW][H_];
  __shared__ float isl[ITW][H_];
  __shared__ float tile[ITW][H_][68];      // 17.4 KB

  {
    int f = tid * 4;
    int r = f >> 7, c = f & 127;
    *(float4*)&qw_l[r][c] = *(const float4*)(qw_g + ((size_t)(b * T_ + i0 + r) * 128 + c));
  }
  if (tid < 64) {
    int r = tid >> 3, hh = tid & 7;
    size_t o = (size_t)(b * H_ + hh) * T_ + i0 + r;
    msl[r][hh] = m_g[o];
    isl[r][hh] = is_g[o];
  }
  __syncthreads();

  const int h = tid >> 5;
  const int jq = tid & 31;
  const float* kw_b = kw_g + (size_t)b * T_ * (H_ * S_);
  float* attn_b = attn + (size_t)(b * T_ + i0) * (T_ * H_);

  const float* kp = kw_b + ((size_t)(j0 + jq * 2) * H_ + h) * S_;
  float4 ka[4], kb[4];
  ka[0] = *(const float4*)(kp);       ka[1] = *(const float4*)(kp + 4);
  ka[2] = *(const float4*)(kp + 8);   ka[3] = *(const float4*)(kp + 12);
  kb[0] = *(const float4*)(kp + 128); kb[1] = *(const float4*)(kp + 132);
  kb[2] = *(const float4*)(kp + 136); kb[3] = *(const float4*)(kp + 140);
#pragma unroll
  for (int r = 0; r < ITW; ++r) {
    float4 q4[4];
    q4[0] = *(const float4*)&qw_l[r][h * 16 + 0];
    q4[1] = *(const float4*)&qw_l[r][h * 16 + 4];
    q4[2] = *(const float4*)&qw_l[r][h * 16 + 8];
    q4[3] = *(const float4*)&qw_l[r][h * 16 + 12];
    float la = dot16(q4, ka);
    float lb = dot16(q4, kb);
    float mm = msl[r][h], ii = isl[r][h];
    *(float2*)&tile[r][h][jq * 2] =
        make_float2(__expf(la - mm) * ii, __expf(lb - mm) * ii);
  }
  __syncthreads();
#pragma unroll
  for (int l = 0; l < 4; ++l) {
    int f = (l * 256 + tid) * 4;
    int r = f >> 9;
    int rem = f & 511;
    int jl = rem >> 3;
    int h0 = rem & 7;  // 0 or 4
    float4 v;
    v.x = tile[r][h0 + 0][jl];
    v.y = tile[r][h0 + 1][jl];
    v.z = tile[r][h0 + 2][jl];
    v.w = tile[r][h0 + 3][jl];
    *(float4*)(attn_b + (size_t)r * (T_ * H_) + (size_t)(j0 + jl) * H_ + h0) = v;
  }
}

// ---------------- PV via MFMA (v6): Vt chunk staged in swizzled LDS ----------------
__global__ __launch_bounds__(256, 4) void k_pv(const float* __restrict__ qw_g,
                                               const float* __restrict__ kw_g,
                                               const float* __restrict__ m_g,
                                               const float* __restrict__ is_g,
                                               const unsigned short* __restrict__ vth,
                                               const unsigned short* __restrict__ vtl,
                                               unsigned short* __restrict__ oph,
                                               unsigned short* __restrict__ opl) {
  const int bid = blockIdx.x;
  const int xcd = bid & 7;
  const int qq = bid >> 3;             // 0..127
  const int p = xcd * 4 + (qq & 3);    // panel 0..31
  const int ib = qq >> 2;              // 0..31
  const int b = p >> 3;
  const int h = p & 7;
  const int i0 = ib * PVI;
  const int t = threadIdx.x;
  const int lane = t & 63;
  const int w = t >> 6;
  const int I = w >> 1;                // i-frag
  const int S = w & 1;                 // k-step (32-j half of chunk)
  const int lr = lane & 15;
  const int kg = lane >> 4;

  union Sm {
    struct {
      unsigned short Vsh[64][64];   // 8 KB
      unsigned short Vsl[64][64];   // 8 KB
    } v;
    float mgs[128][17];             // 8.7 KB merge scratch (post-loop only)
  };
  __shared__ Sm sm;
  __shared__ float kw_sw[PVJ][16];  // 4 KB; s4-block ^= (j>>3)&3

  const int irow = I * 16 + lr;
  float qwr[16];
  {
    const float* qp = qw_g + (((size_t)(b * T_ + i0 + irow) * H_ + h) * S_);
#pragma unroll
    for (int s4 = 0; s4 < 4; ++s4) {
      float4 v = *(const float4*)(qp + s4 * 4);
      qwr[s4 * 4 + 0] = v.x; qwr[s4 * 4 + 1] = v.y;
      qwr[s4 * 4 + 2] = v.z; qwr[s4 * 4 + 3] = v.w;
    }
  }
  float mr = m_g[(size_t)(b * H_ + h) * T_ + i0 + irow];
  float isr = is_g[(size_t)(b * H_ + h) * T_ + i0 + irow];
#pragma unroll
  for (int s = 0; s < 16; ++s) asm volatile("" : "+v"(qwr[s]));
  asm volatile("" : "+v"(mr));
  asm volatile("" : "+v"(isr));

  const unsigned short* vhp = vth + ((size_t)(b * H_ + h) * 64) * 1024;
  const unsigned short* vlp = vtl + ((size_t)(b * H_ + h) * 64) * 1024;

  f32x4m acc[4];
#pragma unroll
  for (int f = 0; f < 4; ++f) { f32x4m z = {0.f, 0.f, 0.f, 0.f}; acc[f] = z; }

  for (int jc = 0; jc < T_ / PVJ; ++jc) {
    const int j0 = jc * PVJ;
    __syncthreads();  // prior chunk's readers done
    // stage kw (swizzled)
    {
      int j = t >> 2, s4g = t & 3;
      float4 v = *(const float4*)(kw_g + (((size_t)(b * T_ + j0 + j) * H_ + h) * S_ + s4g * 4));
      int blk = s4g ^ ((j >> 3) & 3);
      *(float4*)&kw_sw[j][blk * 4] = v;
    }
    // stage Vt hi/lo chunk: 64 d-rows x 64 j, coalesced 128B rows, 16B-slot swizzle
#pragma unroll
    for (int u2 = 0; u2 < 2; ++u2) {
      int u = t + u2 * 256;           // 0..511
      int row = u >> 3, c8 = u & 7;
      int c8s = c8 ^ (row & 7);
      float4 vh = *(const float4*)(vhp + (size_t)row * 1024 + j0 + c8 * 8);
      float4 vl = *(const float4*)(vlp + (size_t)row * 1024 + j0 + c8 * 8);
      *(float4*)&sm.v.Vsh[row][c8s * 8] = vh;
      *(float4*)&sm.v.Vsl[row][c8s * 8] = vl;
    }
    __syncthreads();
    // ---- phase 1: logits -> P A-frag (hi/lo bf16) in registers ----
    union UA { unsigned short s[8]; bf16x8 v; } AH, AL;
#pragma unroll
    for (int u = 0; u < 8; ++u) {
      int jr = S * 32 + kg * 8 + u;
      int g = (jr >> 3) & 3;
      float d = 0.f;
#pragma unroll
      for (int s4 = 0; s4 < 4; ++s4) {
        float4 kv = *(const float4*)&kw_sw[jr][(s4 ^ g) * 4];
        d += qwr[s4 * 4 + 0] * kv.x + qwr[s4 * 4 + 1] * kv.y +
             qwr[s4 * 4 + 2] * kv.z + qwr[s4 * 4 + 3] * kv.w;
      }
      float pv = __expf(d - mr) * isr;
      unsigned short hh = f2bf(pv);
      AH.s[u] = hh;
      AL.s[u] = f2bf(pv - bf2f(hh));
    }
    // ---- phase 2: B-frags from swizzled LDS, 3 MFMA each ----
#pragma unroll
    for (int f = 0; f < 4; ++f) {
      int row = f * 16 + lr;
      int sl = (S * 4 + kg) ^ (row & 7);
      bf16x8 BHv = *(const bf16x8*)&sm.v.Vsh[row][sl * 8];
      bf16x8 BLv = *(const bf16x8*)&sm.v.Vsl[row][sl * 8];
      acc[f] = __builtin_amdgcn_mfma_f32_16x16x32_bf16(AL.v, BHv, acc[f], 0, 0, 0);
      acc[f] = __builtin_amdgcn_mfma_f32_16x16x32_bf16(AH.v, BLv, acc[f], 0, 0, 0);
      acc[f] = __builtin_amdgcn_mfma_f32_16x16x32_bf16(AH.v, BHv, acc[f], 0, 0, 0);
    }
  }
  // ---- merge S=0 + S=1 partials (scratch aliases V buffers), store bf16 hi/lo ----
  __syncthreads();
  if (S == 1) {
    float* dst = &sm.mgs[I * 64 + lane][0];
#pragma unroll
    for (int f = 0; f < 4; ++f)
#pragma unroll
      for (int r = 0; r < 4; ++r) dst[f * 4 + r] = acc[f][r];
  }
  __syncthreads();
  if (S == 0) {
    const float* src = &sm.mgs[I * 64 + lane][0];
#pragma unroll
    for (int f = 0; f < 4; ++f) {
#pragma unroll
      for (int r = 0; r < 4; ++r) {
        float o = acc[f][r] + src[f * 4 + r];
        unsigned short hh = f2bf(o);
        unsigned short ll = f2bf(o - bf2f(hh));
        size_t idx = (size_t)(b * T_ + i0 + I * 16 + kg * 4 + r) * D_ + h * HD_ + f * 16 + lr;
        oph[idx] = hh;
        opl[idx] = ll;
      }
    }
  }
}

extern "C" void kernel_launch(void* const* d_in, const int* in_sizes, int n_in,
                              void* d_out, int out_size, void* d_ws, size_t ws_size,
                              hipStream_t stream) {
  const float* x = (const float*)d_in[0];
  const float* qkv_w = (const float*)d_in[1];
  const float* out_w = (const float*)d_in[2];
  const float* base_c = (const float*)d_in[3];
  const float* deltas = (const float*)d_in[4];
  const float* log_sc = (const float*)d_in[5];
  const float* log_am = (const float*)d_in[6];
  const float* move_p = (const float*)d_in[7];
  const float* temp = (const float*)d_in[8];

  float* out = (float*)d_out;                    // B*T*D
  float* attn = out + (size_t)B_ * T_ * D_;      // B*T*T*H

  float* ws = (float*)d_ws;
  float* qkv = ws;                                          // 6,291,456 f
  float* qw = qkv + 6291456;                                // 524,288
  float* kw = qw + 524288;                                  // 524,288
  float* centers = kw + 524288;                             // 8,192
  float* inv_var = centers + 8192;                          // 128
  float* eff_amps = inv_var + 128;                          // 128
  float* inv_temp = eff_amps + 128;                         // 4
  float* m_g = inv_temp + 4;                                // 32,768
  float* is_g = m_g + 32768;                                // 32,768
  unsigned short* oph = (unsigned short*)(is_g + 32768);    // 2,097,152 us
  unsigned short* opl = oph + 2097152;                      // 2,097,152
  unsigned short* vth = opl + 2097152;                      // 2,097,152
  unsigned short* vtl = vth + 2097152;                      // 2,097,152

  k_params<<<32, 256, 0, stream>>>(base_c, deltas, log_sc, log_am, move_p, temp,
                                   centers, inv_var, eff_amps, inv_temp);

  dim3 g1(1536 / 64, 4096 / 128);   // 24 x 32 = 768 WGs
  gemm_mfma<64><<<g1, 256, 0, stream>>>(x, qkv_w, qkv, B_ * T_, 3 * D_, D_);

  k_gauss<<<(B_ * T_ * H_ * 8) / 256, 256, 0, stream>>>(qkv, centers, inv_var,
                                                        eff_amps, inv_temp, qw, kw);
  k_sv<<<4608, 256, 0, stream>>>(qw, kw, qkv, m_g, is_g, vth, vtl);
  k_attnw<<<B_ * (T_ / ITW) * 16, 256, 0, stream>>>(qw, kw, m_g, is_g, attn);
  k_pv<<<B_ * H_ * (T_ / PVI), 256, 0, stream>>>(qw, kw, m_g, is_g, vth, vtl, oph, opl);

  dim3 g2(512 / 32, 4096 / 64);     // 16 x 64 = 1024 WGs
  gemm_mfma2<32><<<g2, 128, 0, stream>>>(oph, opl, out_w, out, B_ * T_, D_, D_);
}

// Round 21
// 239.658 us; speedup vs baseline: 1.3448x; 1.0169x over previous
//
#include <hip/hip_runtime.h>
#include <hip/hip_bf16.h>

#define B_ 4
#define T_ 1024
#define D_ 512
#define H_ 8
#define S_ 16
#define HD_ 64
#define ITS 8    // i-rows per WG (stats)
#define ITW 8    // i-rows per WG (attnw)
#define PVI 16   // i-rows per WG (pv v7)
#define PVJ 64   // j-chunk (pv)

typedef short bf16x8 __attribute__((ext_vector_type(8)));
typedef float f32x4m __attribute__((ext_vector_type(4)));

__device__ __forceinline__ unsigned short f2bf(float f) {
  unsigned u = __float_as_uint(f);
  unsigned r = (u + 0x7FFFu + ((u >> 16) & 1u)) >> 16;  // RNE
  return (unsigned short)r;
}
__device__ __forceinline__ float bf2f(unsigned short h) {
  return __uint_as_float((unsigned)h << 16);
}

__device__ __forceinline__ void split4(const float4 v, ushort4& h, ushort4& l) {
  h.x = f2bf(v.x); l.x = f2bf(v.x - bf2f(h.x));
  h.y = f2bf(v.y); l.y = f2bf(v.y - bf2f(h.y));
  h.z = f2bf(v.z); l.z = f2bf(v.z - bf2f(h.z));
  h.w = f2bf(v.w); l.w = f2bf(v.w - bf2f(h.w));
}

// ---------------- params only ----------------
__global__ void k_params(const float* __restrict__ base_centers,
                         const float* __restrict__ center_deltas,
                         const float* __restrict__ log_scales,
                         const float* __restrict__ log_amps,
                         const float* __restrict__ movement_param,
                         const float* __restrict__ temperature,
                         float* __restrict__ centers,
                         float* __restrict__ inv_var,
                         float* __restrict__ eff_amps,
                         float* __restrict__ inv_temp) {
  int tid = blockIdx.x * blockDim.x + threadIdx.x;
  float move = (1.f / (1.f + __expf(-movement_param[0]))) * 0.2f;
  if (tid < H_ * S_ * HD_)
    centers[tid] = base_centers[tid] + center_deltas[tid] * move;
  if (tid < H_ * S_) {
    float sc = __expf(log_scales[tid]);
    sc = fminf(fmaxf(sc, 1e-4f), 5.f);
    float am = __expf(log_amps[tid]);
    am = fminf(fmaxf(am, 1e-6f), 10.f);
    inv_var[tid] = 1.f / (sc * sc + 1e-8f);
    eff_amps[tid] = (am > 0.001f) ? am : 0.f;
  }
  if (tid == 0) {
    float t = fminf(fmaxf(temperature[0], 0.01f), 10.f);
    inv_temp[0] = 1.f / t;
  }
}

// ---------------- split-bf16 MFMA GEMM from fp32 inputs, A+B staged in LDS ----------------
template <int BN>
__global__ __launch_bounds__(256) void gemm_mfma(const float* __restrict__ A,
                                                 const float* __restrict__ Bw,
                                                 float* __restrict__ C,
                                                 int M, int N, int K) {
  static_assert(BN == 64, "staging sized for BN=64");
  constexpr int NF = BN / 16;
  const int t = threadIdx.x;
  const int lane = t & 63;
  const int wv = t >> 6;
  const int mBase = blockIdx.y * 128;
  const int n0 = blockIdx.x * BN;
  const int lr = lane & 15;
  const int kg = lane >> 4;

  __shared__ unsigned short Ash[128][64];  // 16 KB
  __shared__ unsigned short Asl[128][64];  // 16 KB
  __shared__ unsigned short Bsh[64][64];   // 8 KB
  __shared__ unsigned short Bsl[64][64];   // 8 KB

  f32x4m acc[2][NF];
#pragma unroll
  for (int i = 0; i < 2; ++i)
#pragma unroll
    for (int f = 0; f < NF; ++f) {
      f32x4m z = {0.f, 0.f, 0.f, 0.f};
      acc[i][f] = z;
    }

  for (int k0 = 0; k0 < K; k0 += 64) {
    if (k0) __syncthreads();  // previous chunk's readers done
    // stage B: 64 rows x 64 k (fp32 -> hi/lo split in-register)
#pragma unroll
    for (int r2 = 0; r2 < 2; ++r2) {
      int idx = t + r2 * 256;
      int row = idx >> 3, c8 = idx & 7;
      int c8s = c8 ^ (row & 7);
      const float* src = Bw + (size_t)(n0 + row) * K + k0 + c8 * 8;
      float4 v0 = *(const float4*)(src);
      float4 v1 = *(const float4*)(src + 4);
      ushort4 h0, l0, h1, l1;
      split4(v0, h0, l0); split4(v1, h1, l1);
      *(ushort4*)&Bsh[row][c8s * 8]     = h0;
      *(ushort4*)&Bsh[row][c8s * 8 + 4] = h1;
      *(ushort4*)&Bsl[row][c8s * 8]     = l0;
      *(ushort4*)&Bsl[row][c8s * 8 + 4] = l1;
    }
    // stage A: 128 rows x 64 k
#pragma unroll
    for (int r4 = 0; r4 < 4; ++r4) {
      int idx = t + r4 * 256;            // 0..1023
      int row = idx >> 3, c8 = idx & 7;
      int c8s = c8 ^ (row & 7);
      const float* src = A + (size_t)(mBase + row) * K + k0 + c8 * 8;
      float4 v0 = *(const float4*)(src);
      float4 v1 = *(const float4*)(src + 4);
      ushort4 h0, l0, h1, l1;
      split4(v0, h0, l0); split4(v1, h1, l1);
      *(ushort4*)&Ash[row][c8s * 8]     = h0;
      *(ushort4*)&Ash[row][c8s * 8 + 4] = h1;
      *(ushort4*)&Asl[row][c8s * 8]     = l0;
      *(ushort4*)&Asl[row][c8s * 8 + 4] = l1;
    }
    __syncthreads();
#pragma unroll
    for (int S2 = 0; S2 < 2; ++S2) {
      int rowA0 = wv * 32 + lr;
      int rowA1 = rowA0 + 16;
      int slA = (S2 * 4 + kg) ^ (lr & 7);  // rowA&7 == lr&7 for both frags
      bf16x8 ah0 = *(const bf16x8*)&Ash[rowA0][slA * 8];
      bf16x8 ah1 = *(const bf16x8*)&Ash[rowA1][slA * 8];
      bf16x8 al0 = *(const bf16x8*)&Asl[rowA0][slA * 8];
      bf16x8 al1 = *(const bf16x8*)&Asl[rowA1][slA * 8];
#pragma unroll
      for (int f = 0; f < NF; ++f) {
        int row = f * 16 + lr;
        int sl = (S2 * 4 + kg) ^ (row & 7);
        bf16x8 vbh = *(const bf16x8*)&Bsh[row][sl * 8];
        bf16x8 vbl = *(const bf16x8*)&Bsl[row][sl * 8];
        acc[0][f] = __builtin_amdgcn_mfma_f32_16x16x32_bf16(al0, vbh, acc[0][f], 0, 0, 0);
        acc[0][f] = __builtin_amdgcn_mfma_f32_16x16x32_bf16(ah0, vbl, acc[0][f], 0, 0, 0);
        acc[0][f] = __builtin_amdgcn_mfma_f32_16x16x32_bf16(ah0, vbh, acc[0][f], 0, 0, 0);
        acc[1][f] = __builtin_amdgcn_mfma_f32_16x16x32_bf16(al1, vbh, acc[1][f], 0, 0, 0);
        acc[1][f] = __builtin_amdgcn_mfma_f32_16x16x32_bf16(ah1, vbl, acc[1][f], 0, 0, 0);
        acc[1][f] = __builtin_amdgcn_mfma_f32_16x16x32_bf16(ah1, vbh, acc[1][f], 0, 0, 0);
      }
    }
  }
  const int m0 = mBase + wv * 32;
#pragma unroll
  for (int i = 0; i < 2; ++i)
#pragma unroll
    for (int f = 0; f < NF; ++f)
#pragma unroll
      for (int r = 0; r < 4; ++r)
        C[(size_t)(m0 + i * 16 + kg * 4 + r) * N + n0 + f * 16 + lr] = acc[i][f][r];
}

// ---------------- 2-wave out-proj GEMM: A = bf16 hi/lo pair, B = fp32 (split in stage) ----------------
template <int BN>
__global__ __launch_bounds__(128) void gemm_mfma2(const unsigned short* __restrict__ Ah,
                                                  const unsigned short* __restrict__ Al,
                                                  const float* __restrict__ Bw,
                                                  float* __restrict__ C,
                                                  int M, int N, int K) {
  static_assert(BN == 32, "staging sized for BN=32");
  constexpr int NF = BN / 16;
  const int t = threadIdx.x;
  const int lane = t & 63;
  const int wv = t >> 6;  // 0..1
  const int mBase = blockIdx.y * 64;
  const int n0 = blockIdx.x * BN;
  const int lr = lane & 15;
  const int kg = lane >> 4;

  __shared__ unsigned short Ash[64][64];  // 8 KB
  __shared__ unsigned short Asl[64][64];  // 8 KB
  __shared__ unsigned short Bsh[32][64];  // 4 KB
  __shared__ unsigned short Bsl[32][64];  // 4 KB

  f32x4m acc[2][NF];
#pragma unroll
  for (int i = 0; i < 2; ++i)
#pragma unroll
    for (int f = 0; f < NF; ++f) {
      f32x4m z = {0.f, 0.f, 0.f, 0.f};
      acc[i][f] = z;
    }

  for (int k0 = 0; k0 < K; k0 += 64) {
    if (k0) __syncthreads();
    // stage B: 32 rows x 64 k (fp32 -> split)
#pragma unroll
    for (int r2 = 0; r2 < 2; ++r2) {
      int idx = t + r2 * 128;
      int row = idx >> 3, c8 = idx & 7;
      int c8s = c8 ^ (row & 7);
      const float* src = Bw + (size_t)(n0 + row) * K + k0 + c8 * 8;
      float4 v0 = *(const float4*)(src);
      float4 v1 = *(const float4*)(src + 4);
      ushort4 h0, l0, h1, l1;
      split4(v0, h0, l0); split4(v1, h1, l1);
      *(ushort4*)&Bsh[row][c8s * 8]     = h0;
      *(ushort4*)&Bsh[row][c8s * 8 + 4] = h1;
      *(ushort4*)&Bsl[row][c8s * 8]     = l0;
      *(ushort4*)&Bsl[row][c8s * 8 + 4] = l1;
    }
    // stage A: 64 rows x 64 k (pre-split bf16 from k_pv)
#pragma unroll
    for (int r4 = 0; r4 < 4; ++r4) {
      int idx = t + r4 * 128;            // 0..511
      int row = idx >> 3, c8 = idx & 7;
      int c8s = c8 ^ (row & 7);
      float4 vh = *(const float4*)(Ah + (size_t)(mBase + row) * K + k0 + c8 * 8);
      float4 vl = *(const float4*)(Al + (size_t)(mBase + row) * K + k0 + c8 * 8);
      *(float4*)&Ash[row][c8s * 8] = vh;
      *(float4*)&Asl[row][c8s * 8] = vl;
    }
    __syncthreads();
#pragma unroll
    for (int S2 = 0; S2 < 2; ++S2) {
      int rowA0 = wv * 32 + lr;
      int rowA1 = rowA0 + 16;
      int slA = (S2 * 4 + kg) ^ (lr & 7);
      bf16x8 ah0 = *(const bf16x8*)&Ash[rowA0][slA * 8];
      bf16x8 ah1 = *(const bf16x8*)&Ash[rowA1][slA * 8];
      bf16x8 al0 = *(const bf16x8*)&Asl[rowA0][slA * 8];
      bf16x8 al1 = *(const bf16x8*)&Asl[rowA1][slA * 8];
#pragma unroll
      for (int f = 0; f < NF; ++f) {
        int row = f * 16 + lr;
        int sl = (S2 * 4 + kg) ^ (row & 7);
        bf16x8 vbh = *(const bf16x8*)&Bsh[row][sl * 8];
        bf16x8 vbl = *(const bf16x8*)&Bsl[row][sl * 8];
        acc[0][f] = __builtin_amdgcn_mfma_f32_16x16x32_bf16(al0, vbh, acc[0][f], 0, 0, 0);
        acc[0][f] = __builtin_amdgcn_mfma_f32_16x16x32_bf16(ah0, vbl, acc[0][f], 0, 0, 0);
        acc[0][f] = __builtin_amdgcn_mfma_f32_16x16x32_bf16(ah0, vbh, acc[0][f], 0, 0, 0);
        acc[1][f] = __builtin_amdgcn_mfma_f32_16x16x32_bf16(al1, vbh, acc[1][f], 0, 0, 0);
        acc[1][f] = __builtin_amdgcn_mfma_f32_16x16x32_bf16(ah1, vbl, acc[1][f], 0, 0, 0);
        acc[1][f] = __builtin_amdgcn_mfma_f32_16x16x32_bf16(ah1, vbh, acc[1][f], 0, 0, 0);
      }
    }
  }
  const int m0 = mBase + wv * 32;
#pragma unroll
  for (int i = 0; i < 2; ++i)
#pragma unroll
    for (int f = 0; f < NF; ++f)
#pragma unroll
      for (int r = 0; r < 4; ++r)
        C[(size_t)(m0 + i * 16 + kg * 4 + r) * N + n0 + f * 16 + lr] = acc[i][f][r];
}

// ---------------- gaussian kernel weights v2: 2 s-values share q/k rows ----------------
__global__ __launch_bounds__(256) void k_gauss(const float* __restrict__ qkv,
                                               const float* __restrict__ centers,
                                               const float* __restrict__ inv_var,
                                               const float* __restrict__ eff_amps,
                                               const float* __restrict__ inv_temp,
                                               float* __restrict__ qw,
                                               float* __restrict__ kw) {
  int gid = blockIdx.x * blockDim.x + threadIdx.x;  // 0..B*T*H*8-1
  int s = gid & 7;
  int h = (gid >> 3) & 7;
  int bt = gid >> 6;
  const float* qrow = qkv + (size_t)bt * 1536 + h * 64;
  const float* krow = qrow + 512;
  const float* c0 = centers + (h * 16 + s) * 64;
  const float* c1 = c0 + 8 * 64;  // s+8
  float qd0 = 0.f, kd0 = 0.f, qd1 = 0.f, kd1 = 0.f;
#pragma unroll
  for (int d = 0; d < 64; d += 4) {
    float4 qv = *(const float4*)(qrow + d);
    float4 kv = *(const float4*)(krow + d);
    float4 ca = *(const float4*)(c0 + d);
    float4 cb = *(const float4*)(c1 + d);
    float t;
    t = qv.x - ca.x; qd0 += t * t;  t = qv.y - ca.y; qd0 += t * t;
    t = qv.z - ca.z; qd0 += t * t;  t = qv.w - ca.w; qd0 += t * t;
    t = kv.x - ca.x; kd0 += t * t;  t = kv.y - ca.y; kd0 += t * t;
    t = kv.z - ca.z; kd0 += t * t;  t = kv.w - ca.w; kd0 += t * t;
    t = qv.x - cb.x; qd1 += t * t;  t = qv.y - cb.y; qd1 += t * t;
    t = qv.z - cb.z; qd1 += t * t;  t = qv.w - cb.w; qd1 += t * t;
    t = kv.x - cb.x; kd1 += t * t;  t = kv.y - cb.y; kd1 += t * t;
    t = kv.z - cb.z; kd1 += t * t;  t = kv.w - cb.w; kd1 += t * t;
  }
  qd0 = fminf(qd0, 100.f); kd0 = fminf(kd0, 100.f);
  qd1 = fminf(qd1, 100.f); kd1 = fminf(kd1, 100.f);
  float it = inv_temp[0];
  float iv0 = inv_var[h * 16 + s],     ea0 = eff_amps[h * 16 + s];
  float iv1 = inv_var[h * 16 + s + 8], ea1 = eff_amps[h * 16 + s + 8];
  size_t base = (size_t)(bt * H_ + h) * S_ + s;
  qw[base]     = __expf(-0.5f * qd0 * iv0) * ea0 * it;
  kw[base]     = __expf(-0.5f * kd0 * iv0) * ea0;
  qw[base + 8] = __expf(-0.5f * qd1 * iv1) * ea1 * it;
  kw[base + 8] = __expf(-0.5f * kd1 * iv1) * ea1;
}

__device__ __forceinline__ float dot16(const float4 q[4], const float4 k[4]) {
  return q[0].x * k[0].x + q[0].y * k[0].y + q[0].z * k[0].z + q[0].w * k[0].w +
         q[1].x * k[1].x + q[1].y * k[1].y + q[1].z * k[1].z + q[1].w * k[1].w +
         q[2].x * k[2].x + q[2].y * k[2].y + q[2].z * k[2].z + q[2].w * k[2].w +
         q[3].x * k[3].x + q[3].y * k[3].y + q[3].z * k[3].z + q[3].w * k[3].w;
}

// ---------------- fused stats + vtr (8:1 WG interleave) ----------------
__global__ __launch_bounds__(256, 4) void k_sv(const float* __restrict__ qw_g,
                                               const float* __restrict__ kw_g,
                                               const float* __restrict__ qkv,
                                               float* __restrict__ m_g,
                                               float* __restrict__ is_g,
                                               unsigned short* __restrict__ vth,
                                               unsigned short* __restrict__ vtl) {
  union Sm {
    float red[4][4][2][2];
    float Vl[64][68];
  };
  __shared__ Sm sm;
  const int bid = blockIdx.x;
  const int g = bid / 9;
  const int r = bid - g * 9;
  const int t = threadIdx.x;

  if (r < 8) {
    const int x = g * 8 + r;  // 0..4095
    const int ic = x & 127;
    const int h = (x >> 7) & 7;
    const int b = x >> 10;
    const int i0 = ic * ITS;
    const int rp = t & 3;
    const int jl = t >> 2;

    float qwr[2][16], mr[2], sr[2];
#pragma unroll
    for (int e = 0; e < 2; ++e) {
      const float* qp = qw_g + (((size_t)(b * T_ + i0 + rp * 2 + e) * H_ + h) * S_);
#pragma unroll
      for (int s4 = 0; s4 < 4; ++s4) {
        float4 v = *(const float4*)(qp + s4 * 4);
        qwr[e][s4 * 4 + 0] = v.x; qwr[e][s4 * 4 + 1] = v.y;
        qwr[e][s4 * 4 + 2] = v.z; qwr[e][s4 * 4 + 3] = v.w;
      }
      mr[e] = -1e30f; sr[e] = 0.f;
    }
    for (int c = 0; c < T_ / 64; ++c) {
      int j = c * 64 + jl;
      const float* kp = kw_g + ((size_t)(b * T_ + j) * H_ + h) * S_;
      float4 k0 = *(const float4*)(kp);
      float4 k1 = *(const float4*)(kp + 4);
      float4 k2 = *(const float4*)(kp + 8);
      float4 k3 = *(const float4*)(kp + 12);
#pragma unroll
      for (int e = 0; e < 2; ++e) {
        float d = qwr[e][0] * k0.x + qwr[e][1] * k0.y + qwr[e][2] * k0.z + qwr[e][3] * k0.w +
                  qwr[e][4] * k1.x + qwr[e][5] * k1.y + qwr[e][6] * k1.z + qwr[e][7] * k1.w +
                  qwr[e][8] * k2.x + qwr[e][9] * k2.y + qwr[e][10] * k2.z + qwr[e][11] * k2.w +
                  qwr[e][12] * k3.x + qwr[e][13] * k3.y + qwr[e][14] * k3.z + qwr[e][15] * k3.w;
        float mn = fmaxf(mr[e], d);
        sr[e] = sr[e] * __expf(mr[e] - mn) + __expf(d - mn);
        mr[e] = mn;
      }
    }
#pragma unroll
    for (int o = 4; o < 64; o <<= 1) {
#pragma unroll
      for (int e = 0; e < 2; ++e) {
        float m2 = __shfl_xor(mr[e], o);
        float s2 = __shfl_xor(sr[e], o);
        float mn = fmaxf(mr[e], m2);
        sr[e] = sr[e] * __expf(mr[e] - mn) + s2 * __expf(m2 - mn);
        mr[e] = mn;
      }
    }
    int wv = t >> 6;
    if ((t & 63) < 4) {
      sm.red[wv][rp][0][0] = mr[0]; sm.red[wv][rp][0][1] = sr[0];
      sm.red[wv][rp][1][0] = mr[1]; sm.red[wv][rp][1][1] = sr[1];
    }
    __syncthreads();
    if (t < ITS) {
      int rpp = t >> 1, e = t & 1;
      float mf = sm.red[0][rpp][e][0], sf = sm.red[0][rpp][e][1];
#pragma unroll
      for (int w = 1; w < 4; ++w) {
        float m2 = sm.red[w][rpp][e][0], s2 = sm.red[w][rpp][e][1];
        float mn = fmaxf(mf, m2);
        sf = sf * __expf(mf - mn) + s2 * __expf(m2 - mn);
        mf = mn;
      }
      size_t o = (size_t)(b * H_ + h) * T_ + i0 + t;
      m_g[o] = mf;
      is_g[o] = 1.f / sf;
    }
  } else {
    const int id = g;  // 0..511
    const int jc = id & 15;
    const int h = (id >> 4) & 7;
    const int b = id >> 7;
    const int j0 = jc * 64;
    {
      int jj = t >> 2, dqg = t & 3;
      const float* vp = qkv + (size_t)(b * T_ + j0 + jj) * 1536 + 1024 + h * 64 + dqg * 16;
#pragma unroll
      for (int q = 0; q < 4; ++q) {
        float4 v = *(const float4*)(vp + q * 4);
        *(float4*)&sm.Vl[jj][dqg * 16 + q * 4] = v;
      }
    }
    __syncthreads();
    {
      int d = t >> 2, jg = t & 3;
      ushort4 hs[4], ls[4];
#pragma unroll
      for (int q = 0; q < 4; ++q) {
        float f0 = sm.Vl[jg * 16 + q * 4 + 0][d];
        float f1 = sm.Vl[jg * 16 + q * 4 + 1][d];
        float f2 = sm.Vl[jg * 16 + q * 4 + 2][d];
        float f3 = sm.Vl[jg * 16 + q * 4 + 3][d];
        hs[q].x = f2bf(f0); ls[q].x = f2bf(f0 - bf2f(hs[q].x));
        hs[q].y = f2bf(f1); ls[q].y = f2bf(f1 - bf2f(hs[q].y));
        hs[q].z = f2bf(f2); ls[q].z = f2bf(f2 - bf2f(hs[q].z));
        hs[q].w = f2bf(f3); ls[q].w = f2bf(f3 - bf2f(hs[q].w));
      }
      size_t off = ((size_t)(b * H_ + h) * 64 + d) * 1024 + j0 + jg * 16;
#pragma unroll
      for (int q = 0; q < 4; ++q) {
        *(ushort4*)(vth + off + q * 4) = hs[q];
        *(ushort4*)(vtl + off + q * 4) = ls[q];
      }
    }
  }
}

// ---------------- attn writer (v1 body, jt-split 16: one subtile per WG) ----------------
__global__ __launch_bounds__(256, 4) void k_attnw(const float* __restrict__ qw_g,
                                                  const float* __restrict__ kw_g,
                                                  const float* __restrict__ m_g,
                                                  const float* __restrict__ is_g,
                                                  float* __restrict__ attn) {
  const int x = blockIdx.x;
  const int jt = x & 15;
  const int it = (x >> 4) & 127;
  const int b = x >> 11;
  const int i0 = it * ITW;
  const int j0 = jt * 64;
  const int tid = threadIdx.x;

  __shared__ float qw_l[ITW][H_ * S_];     // 4 KB
  __shared__ float msl[ITW][H_];
  __shared__ float isl[ITW][H_];
  __shared__ float tile[ITW][H_][68];      // 17.4 KB

  {
    int f = tid * 4;
    int r = f >> 7, c = f & 127;
    *(float4*)&qw_l[r][c] = *(const float4*)(qw_g + ((size_t)(b * T_ + i0 + r) * 128 + c));
  }
  if (tid < 64) {
    int r = tid >> 3, hh = tid & 7;
    size_t o = (size_t)(b * H_ + hh) * T_ + i0 + r;
    msl[r][hh] = m_g[o];
    isl[r][hh] = is_g[o];
  }
  __syncthreads();

  const int h = tid >> 5;
  const int jq = tid & 31;
  const float* kw_b = kw_g + (size_t)b * T_ * (H_ * S_);
  float* attn_b = attn + (size_t)(b * T_ + i0) * (T_ * H_);

  const float* kp = kw_b + ((size_t)(j0 + jq * 2) * H_ + h) * S_;
  float4 ka[4], kb[4];
  ka[0] = *(const float4*)(kp);       ka[1] = *(const float4*)(kp + 4);
  ka[2] = *(const float4*)(kp + 8);   ka[3] = *(const float4*)(kp + 12);
  kb[0] = *(const float4*)(kp + 128); kb[1] = *(const float4*)(kp + 132);
  kb[2] = *(const float4*)(kp + 136); kb[3] = *(const float4*)(kp + 140);
#pragma unroll
  for (int r = 0; r < ITW; ++r) {
    float4 q4[4];
    q4[0] = *(const float4*)&qw_l[r][h * 16 + 0];
    q4[1] = *(const float4*)&qw_l[r][h * 16 + 4];
    q4[2] = *(const float4*)&qw_l[r][h * 16 + 8];
    q4[3] = *(const float4*)&qw_l[r][h * 16 + 12];
    float la = dot16(q4, ka);
    float lb = dot16(q4, kb);
    float mm = msl[r][h], ii = isl[r][h];
    *(float2*)&tile[r][h][jq * 2] =
        make_float2(__expf(la - mm) * ii, __expf(lb - mm) * ii);
  }
  __syncthreads();
#pragma unroll
  for (int l = 0; l < 4; ++l) {
    int f = (l * 256 + tid) * 4;
    int r = f >> 9;
    int rem = f & 511;
    int jl = rem >> 3;
    int h0 = rem & 7;  // 0 or 4
    float4 v;
    v.x = tile[r][h0 + 0][jl];
    v.y = tile[r][h0 + 1][jl];
    v.z = tile[r][h0 + 2][jl];
    v.w = tile[r][h0 + 3][jl];
    *(float4*)(attn_b + (size_t)r * (T_ * H_) + (size_t)(j0 + jl) * H_ + h0) = v;
  }
}

// ---------------- PV via MFMA (v7): hi-LDS / lo-global hybrid, PVI=16, 2-wave WGs ----------------
// Round-20 counters: k_pv 81us, 18.9M LDS bank conflicts, 36% occupancy (grid-capped
// 4 WG/CU). v7: (a) stage only V-hi in LDS (2 of 3 MFMA products; WG dedup), read
// V-lo straight from global Vt (1 use, L2-resident, proven fine in v5) -> LDS
// traffic ~halves; (b) PVI 32->16 with 128-thr WGs -> grid 2048 = 8 independent
// WGs/CU, 2-wave barrier scopes. Arithmetic order identical (same S0+S1 merge).
__global__ __launch_bounds__(128, 4) void k_pv(const float* __restrict__ qw_g,
                                               const float* __restrict__ kw_g,
                                               const float* __restrict__ m_g,
                                               const float* __restrict__ is_g,
                                               const unsigned short* __restrict__ vth,
                                               const unsigned short* __restrict__ vtl,
                                               unsigned short* __restrict__ oph,
                                               unsigned short* __restrict__ opl) {
  const int bid = blockIdx.x;
  const int xcd = bid & 7;
  const int qq = bid >> 3;             // 0..255
  const int p = xcd * 4 + (qq & 3);    // panel 0..31
  const int ib = qq >> 2;              // 0..63
  const int b = p >> 3;
  const int h = p & 7;
  const int i0 = ib * PVI;
  const int t = threadIdx.x;           // 0..127
  const int lane = t & 63;
  const int S = t >> 6;                // k-step (32-j half of chunk)
  const int lr = lane & 15;
  const int kg = lane >> 4;

  __shared__ unsigned short Vsh[64][64];  // 8 KB (V-hi only)
  __shared__ float kw_sw[PVJ][16];        // 4 KB; s4-block ^= (j>>3)&3
  __shared__ float mgs[64][17];           // 4.4 KB merge scratch

  const int irow = lr;                 // 16 i-rows per WG
  float qwr[16];
  {
    const float* qp = qw_g + (((size_t)(b * T_ + i0 + irow) * H_ + h) * S_);
#pragma unroll
    for (int s4 = 0; s4 < 4; ++s4) {
      float4 v = *(const float4*)(qp + s4 * 4);
      qwr[s4 * 4 + 0] = v.x; qwr[s4 * 4 + 1] = v.y;
      qwr[s4 * 4 + 2] = v.z; qwr[s4 * 4 + 3] = v.w;
    }
  }
  float mr = m_g[(size_t)(b * H_ + h) * T_ + i0 + irow];
  float isr = is_g[(size_t)(b * H_ + h) * T_ + i0 + irow];
#pragma unroll
  for (int s = 0; s < 16; ++s) asm volatile("" : "+v"(qwr[s]));
  asm volatile("" : "+v"(mr));
  asm volatile("" : "+v"(isr));

  const unsigned short* vhp = vth + ((size_t)(b * H_ + h) * 64) * 1024;
  const unsigned short* vlp = vtl + ((size_t)(b * H_ + h) * 64) * 1024;

  f32x4m acc[4];
#pragma unroll
  for (int f = 0; f < 4; ++f) { f32x4m z = {0.f, 0.f, 0.f, 0.f}; acc[f] = z; }

  for (int jc = 0; jc < T_ / PVJ; ++jc) {
    const int j0 = jc * PVJ;
    __syncthreads();  // prior chunk's readers done
    // stage kw (swizzled): 128 threads x 2
#pragma unroll
    for (int it2 = 0; it2 < 2; ++it2) {
      int id2 = t + it2 * 128;          // 0..255
      int j = id2 >> 2, s4g = id2 & 3;
      float4 v = *(const float4*)(kw_g + (((size_t)(b * T_ + j0 + j) * H_ + h) * S_ + s4g * 4));
      int blk = s4g ^ ((j >> 3) & 3);
      *(float4*)&kw_sw[j][blk * 4] = v;
    }
    // stage V-hi chunk: 64 d-rows x 64 j, coalesced, 16B-slot swizzle
#pragma unroll
    for (int u2 = 0; u2 < 4; ++u2) {
      int u = t + u2 * 128;             // 0..511
      int row = u >> 3, c8 = u & 7;
      int c8s = c8 ^ (row & 7);
      float4 vh = *(const float4*)(vhp + (size_t)row * 1024 + j0 + c8 * 8);
      *(float4*)&Vsh[row][c8s * 8] = vh;
    }
    __syncthreads();
    // ---- phase 1: logits -> P A-frag (hi/lo bf16) in registers ----
    union UA { unsigned short s[8]; bf16x8 v; } AH, AL;
#pragma unroll
    for (int u = 0; u < 8; ++u) {
      int jr = S * 32 + kg * 8 + u;
      int g = (jr >> 3) & 3;
      float d = 0.f;
#pragma unroll
      for (int s4 = 0; s4 < 4; ++s4) {
        float4 kv = *(const float4*)&kw_sw[jr][(s4 ^ g) * 4];
        d += qwr[s4 * 4 + 0] * kv.x + qwr[s4 * 4 + 1] * kv.y +
             qwr[s4 * 4 + 2] * kv.z + qwr[s4 * 4 + 3] * kv.w;
      }
      float pv = __expf(d - mr) * isr;
      unsigned short hh = f2bf(pv);
      AH.s[u] = hh;
      AL.s[u] = f2bf(pv - bf2f(hh));
    }
    // ---- phase 2: V-hi from LDS (2 products), V-lo from global (1 product) ----
#pragma unroll
    for (int f = 0; f < 4; ++f) {
      int row = f * 16 + lr;
      int sl = (S * 4 + kg) ^ (row & 7);
      bf16x8 BHv = *(const bf16x8*)&Vsh[row][sl * 8];
      bf16x8 BLv = *(const bf16x8*)(vlp + (size_t)row * 1024 + j0 + S * 32 + kg * 8);
      acc[f] = __builtin_amdgcn_mfma_f32_16x16x32_bf16(AL.v, BHv, acc[f], 0, 0, 0);
      acc[f] = __builtin_amdgcn_mfma_f32_16x16x32_bf16(AH.v, BLv, acc[f], 0, 0, 0);
      acc[f] = __builtin_amdgcn_mfma_f32_16x16x32_bf16(AH.v, BHv, acc[f], 0, 0, 0);
    }
  }
  // ---- merge S=0 + S=1 partials, store bf16 hi/lo ----
  __syncthreads();
  if (S == 1) {
    float* dst = &mgs[lane][0];
#pragma unroll
    for (int f = 0; f < 4; ++f)
#pragma unroll
      for (int r = 0; r < 4; ++r) dst[f * 4 + r] = acc[f][r];
  }
  __syncthreads();
  if (S == 0) {
    const float* src = &mgs[lane][0];
#pragma unroll
    for (int f = 0; f < 4; ++f) {
#pragma unroll
      for (int r = 0; r < 4; ++r) {
        float o = acc[f][r] + src[f * 4 + r];
        unsigned short hh = f2bf(o);
        unsigned short ll = f2bf(o - bf2f(hh));
        size_t idx = (size_t)(b * T_ + i0 + kg * 4 + r) * D_ + h * HD_ + f * 16 + lr;
        oph[idx] = hh;
        opl[idx] = ll;
      }
    }
  }
}

extern "C" void kernel_launch(void* const* d_in, const int* in_sizes, int n_in,
                              void* d_out, int out_size, void* d_ws, size_t ws_size,
                              hipStream_t stream) {
  const float* x = (const float*)d_in[0];
  const float* qkv_w = (const float*)d_in[1];
  const float* out_w = (const float*)d_in[2];
  const float* base_c = (const float*)d_in[3];
  const float* deltas = (const float*)d_in[4];
  const float* log_sc = (const float*)d_in[5];
  const float* log_am = (const float*)d_in[6];
  const float* move_p = (const float*)d_in[7];
  const float* temp = (const float*)d_in[8];

  float* out = (float*)d_out;                    // B*T*D
  float* attn = out + (size_t)B_ * T_ * D_;      // B*T*T*H

  float* ws = (float*)d_ws;
  float* qkv = ws;                                          // 6,291,456 f
  float* qw = qkv + 6291456;                                // 524,288
  float* kw = qw + 524288;                                  // 524,288
  float* centers = kw + 524288;                             // 8,192
  float* inv_var = centers + 8192;                          // 128
  float* eff_amps = inv_var + 128;                          // 128
  float* inv_temp = eff_amps + 128;                         // 4
  float* m_g = inv_temp + 4;                                // 32,768
  float* is_g = m_g + 32768;                                // 32,768
  unsigned short* oph = (unsigned short*)(is_g + 32768);    // 2,097,152 us
  unsigned short* opl = oph + 2097152;                      // 2,097,152
  unsigned short* vth = opl + 2097152;                      // 2,097,152
  unsigned short* vtl = vth + 2097152;                      // 2,097,152

  k_params<<<32, 256, 0, stream>>>(base_c, deltas, log_sc, log_am, move_p, temp,
                                   centers, inv_var, eff_amps, inv_temp);

  dim3 g1(1536 / 64, 4096 / 128);   // 24 x 32 = 768 WGs
  gemm_mfma<64><<<g1, 256, 0, stream>>>(x, qkv_w, qkv, B_ * T_, 3 * D_, D_);

  k_gauss<<<(B_ * T_ * H_ * 8) / 256, 256, 0, stream>>>(qkv, centers, inv_var,
                                                        eff_amps, inv_temp, qw, kw);
  k_sv<<<4608, 256, 0, stream>>>(qw, kw, qkv, m_g, is_g, vth, vtl);
  k_attnw<<<B_ * (T_ / ITW) * 16, 256, 0, stream>>>(qw, kw, m_g, is_g, attn);
  k_pv<<<B_ * H_ * (T_ / PVI), 128, 0, stream>>>(qw, kw, m_g, is_g, vth, vtl, oph, opl);

  dim3 g2(512 / 32, 4096 / 64);     // 16 x 64 = 1024 WGs
  gemm_mfma2<32><<<g2, 128, 0, stream>>>(oph, opl, out_w, out, B_ * T_, D_, D_);
}